// Round 4
// baseline (416.235 us; speedup 1.0000x reference)
//
#include <hip/hip_runtime.h>

typedef __bf16 bf16x8 __attribute__((ext_vector_type(8)));
typedef float f32x4 __attribute__((ext_vector_type(4)));

__device__ __forceinline__ ushort f2b(float f){
  union { float f; unsigned u; } v; v.f = f;
  unsigned r = v.u + 0x7FFFu + ((v.u >> 16) & 1u);
  return (ushort)(r >> 16);
}
__device__ __forceinline__ float b2f(ushort b){
  union { unsigned u; float f; } v; v.u = ((unsigned)b) << 16; return v.f;
}

__device__ __forceinline__ void gload16(const ushort* g, ushort* lds){
  __builtin_amdgcn_global_load_lds(
      (const __attribute__((address_space(1))) unsigned int*)(g),
      (__attribute__((address_space(3))) unsigned int*)(lds), 16, 0, 0);
}

#define WAIT_LGKM do { asm volatile("s_waitcnt lgkmcnt(0)" ::: "memory"); __builtin_amdgcn_sched_barrier(0); } while(0)
#define VMW(n)    do { asm volatile("s_waitcnt vmcnt(" #n ")" ::: "memory"); __builtin_amdgcn_sched_barrier(0); } while(0)

// ---------------- converts ----------------
__global__ __launch_bounds__(256) void cvt_bf16_k(const float* __restrict__ in,
                                                  ushort* __restrict__ out, int n4){
  int i = blockIdx.x*256 + threadIdx.x;
  if (i < n4){
    f32x4 v = reinterpret_cast<const f32x4*>(in)[i];
    ushort4 o = make_ushort4(f2b(v.x), f2b(v.y), f2b(v.z), f2b(v.w));
    reinterpret_cast<ushort4*>(out)[i] = o;
  }
}

__global__ __launch_bounds__(256) void cvt_enc_k(const float* __restrict__ in,
                                                 ushort* __restrict__ out){
  int i = blockIdx.x*256 + threadIdx.x;
  if (i < 384*2048/4){
    f32x4 v = {0.f,0.f,0.f,0.f};
    if (i < 324*2048/4) v = reinterpret_cast<const f32x4*>(in)[i];
    ushort4 o = make_ushort4(f2b(v.x), f2b(v.y), f2b(v.z), f2b(v.w));
    reinterpret_cast<ushort4*>(out)[i] = o;
  }
}

// W[K][N] fp32 -> Wt[N][K] bf16
__global__ __launch_bounds__(256) void transpose_bf16_k(const float* __restrict__ W,
                                                        ushort* __restrict__ Wt, int K, int N){
  __shared__ float tile[32][33];
  int n0 = blockIdx.x*32, k0 = blockIdx.y*32;
  int tx = threadIdx.x & 31, ty = threadIdx.x >> 5;
  for (int i = ty; i < 32; i += 8) tile[i][tx] = W[(size_t)(k0+i)*N + n0+tx];
  __syncthreads();
  for (int i = ty; i < 32; i += 8) Wt[(size_t)(n0+i)*K + k0+tx] = f2b(tile[tx][i]);
}

// ---------------- 256x256 8-phase GEMM (T1+T2+T3+T4+T5): C = A[M][K] @ Bt[N][K]^T ----------
// 512 threads, 8 waves (interleaved 2x4), BK=64, 128KiB LDS (2 buf x 2 half x 128x64 x A,B).
// Half-tile pipeline: per phase read one A-half + one B-half, stage one half-tile,
// vmcnt(6) (=3 half-tiles in flight) at p2/p4. Swizzle: col ^= (row&7)<<3 (elements),
// applied on global source (gload_lds dest linear) and on ds_read.
template<int MODE>
__global__ __launch_bounds__(512, 2) void gemm256(
    const ushort* __restrict__ A, const ushort* __restrict__ Bt,
    int M, int N, int K, int lda, int ldb, int ldo,
    float* __restrict__ outF, ushort* __restrict__ outB,
    const float* __restrict__ bias, const float* __restrict__ resid)
{
  __shared__ ushort As[2][2][128][64];
  __shared__ ushort Bs[2][2][128][64];
  int ntiles = N >> 8;
  int nwg = gridDim.x;
  int bid = blockIdx.x;
  if ((nwg & 7) == 0){
    int cpx = nwg >> 3;
    bid = (bid & 7)*cpx + (bid >> 3);
  }
  int mt = bid / ntiles;
  int nt = bid - mt*ntiles;
  int t = threadIdx.x;
  int wid = t >> 6, l = t & 63;
  int wr = wid >> 2, wc = wid & 3;           // interleaved wave grid 2(M) x 4(N)
  int fr = l & 15, fq = l >> 4;
  int swz = (fr & 7) << 3;                   // element swizzle for ds_read

  // staging geometry: thread t covers (row = t>>3 [+64], col = (t&7)*8) of a 128x64 half
  int srow = t >> 3;
  int scol = ((t & 7) << 3) ^ ((srow & 7) << 3);
  const ushort* Asrc = A + (size_t)(mt*256 + srow)*lda + scol;
  const ushort* Bsrc = Bt + (size_t)(nt*256 + srow)*ldb + scol;

  auto stageA = [&](int h, int kt){
    int bufd = kt & 1;
    ushort* dst = &As[bufd][h][0][0] + t*8;
    const ushort* src = Asrc + (size_t)h*128*lda + (size_t)kt*64;
    gload16(src, dst);
    gload16(src + (size_t)64*lda, dst + 4096);
  };
  auto stageB = [&](int h, int kt){
    int bufd = kt & 1;
    ushort* dst = &Bs[bufd][h][0][0] + t*8;
    const ushort* src = Bsrc + (size_t)h*128*ldb + (size_t)kt*64;
    gload16(src, dst);
    gload16(src + (size_t)64*ldb, dst + 4096);
  };

  f32x4 acc[2][2][4][2];
  #pragma unroll
  for (int mq = 0; mq < 2; ++mq)
    #pragma unroll
    for (int nq = 0; nq < 2; ++nq)
      #pragma unroll
      for (int f = 0; f < 4; ++f)
        #pragma unroll
        for (int g = 0; g < 2; ++g) acc[mq][nq][f][g] = (f32x4){0.f,0.f,0.f,0.f};

  int nk = K >> 6;   // assumes nk >= 3

  // prologue: halves in steady-state global order
  stageB(0, 0); stageA(0, 0); stageA(1, 0); stageB(1, 0);
  stageB(0, 1); stageA(0, 1);
  VMW(6);
  __builtin_amdgcn_s_barrier();
  __builtin_amdgcn_sched_barrier(0);

#define PHASE(MQ, NQ, STAGES, TAILWAIT) { \
    bf16x8 af[2][4], bfr[2][2]; \
    _Pragma("unroll") \
    for (int f = 0; f < 4; ++f){ \
      int ar = wr*64 + f*16 + fr; \
      af[0][f] = *reinterpret_cast<const bf16x8*>(&As[buf][MQ][ar][(0*32 + fq*8) ^ swz]); \
      af[1][f] = *reinterpret_cast<const bf16x8*>(&As[buf][MQ][ar][(1*32 + fq*8) ^ swz]); \
    } \
    _Pragma("unroll") \
    for (int g = 0; g < 2; ++g){ \
      int br = wc*32 + g*16 + fr; \
      bfr[0][g] = *reinterpret_cast<const bf16x8*>(&Bs[buf][NQ][br][(0*32 + fq*8) ^ swz]); \
      bfr[1][g] = *reinterpret_cast<const bf16x8*>(&Bs[buf][NQ][br][(1*32 + fq*8) ^ swz]); \
    } \
    STAGES; \
    __builtin_amdgcn_s_barrier(); \
    WAIT_LGKM; \
    __builtin_amdgcn_s_setprio(1); \
    _Pragma("unroll") \
    for (int kk = 0; kk < 2; ++kk) \
      _Pragma("unroll") \
      for (int f = 0; f < 4; ++f) \
        _Pragma("unroll") \
        for (int g = 0; g < 2; ++g) \
          acc[MQ][NQ][f][g] = __builtin_amdgcn_mfma_f32_16x16x32_bf16(af[kk][f], bfr[kk][g], acc[MQ][NQ][f][g], 0, 0, 0); \
    __builtin_amdgcn_s_setprio(0); \
    __builtin_amdgcn_sched_barrier(0); \
    TAILWAIT; \
    __builtin_amdgcn_s_barrier(); \
    __builtin_amdgcn_sched_barrier(0); \
  }

  for (int T = 0; T < nk; ++T){
    int buf = T & 1;
    // p1: A0 x B0 ; stage A1(T+1)
    PHASE(0, 0, { if (T+1 < nk) stageA(1, T+1); }, {});
    // p2: A1 x B0 ; stage B1(T+1) ; mid vmcnt
    PHASE(1, 0, { if (T+1 < nk) stageB(1, T+1); },
               { if (T == nk-1) { VMW(0); } else { VMW(6); } });
    // p3: A0 x B1 ; stage B0(T+2)
    PHASE(0, 1, { if (T+2 < nk) stageB(0, T+2); }, {});
    // p4: A1 x B1 ; stage A0(T+2) ; boundary vmcnt
    PHASE(1, 1, { if (T+2 < nk) stageA(0, T+2); },
               { if (T < nk-1) { if (T+1 == nk-1) { VMW(0); } else { VMW(6); } } });
  }
#undef PHASE

  int fqb = fq << 2;
  #pragma unroll
  for (int mq = 0; mq < 2; ++mq){
    #pragma unroll
    for (int nq = 0; nq < 2; ++nq){
      #pragma unroll
      for (int f = 0; f < 4; ++f){
        #pragma unroll
        for (int g = 0; g < 2; ++g){
          #pragma unroll
          for (int r = 0; r < 4; ++r){
            int row = mt*256 + mq*128 + wr*64 + f*16 + fqb + r;
            int col = nt*256 + nq*128 + wc*32 + g*16 + fr;
            size_t oidx = (size_t)row*ldo + col;
            float v = acc[mq][nq][f][g][r];
            if (MODE == 0) outB[oidx] = f2b(v);
            else           outF[oidx] = v + bias[col] + resid[oidx];
          }
        }
      }
    }
  }
}

// ---------------- 128x128 GEMM, BK=64, double-buffered 2-phase, swizzled LDS ----------------
// (kept for the 384-row encoder projection)
template<int MODE>
__global__ __launch_bounds__(256) void gemm128(
    const ushort* __restrict__ A, const ushort* __restrict__ Bt,
    int M, int N, int K, int lda, int ldb, int ldo,
    float* __restrict__ outF, ushort* __restrict__ outB,
    const float* __restrict__ bias, const float* __restrict__ resid)
{
  __shared__ ushort As[2][128*64];
  __shared__ ushort Bs[2][128*64];
  int ntiles = N >> 7;
  int nwg = gridDim.x;
  int bid = blockIdx.x;
  if ((nwg & 7) == 0){
    int cpx = nwg >> 3;
    bid = (bid & 7)*cpx + (bid >> 3);
  }
  int mt = bid / ntiles;
  int nt = bid - mt*ntiles;
  int t = threadIdx.x;
  int w = t >> 6, l = t & 63;
  int wr = w >> 1, wc = w & 1;
  int fr = l & 15, fq = l >> 4;

  const char* Agb = (const char*)(A + (size_t)(mt*128)*lda);
  const char* Bgb = (const char*)(Bt + (size_t)(nt*128)*ldb);
  int srow = t >> 3;
  int sbyte = (t & 7) << 4;

  f32x4 acc[4][4];
  #pragma unroll
  for (int m = 0; m < 4; ++m)
    #pragma unroll
    for (int n = 0; n < 4; ++n) acc[m][n] = (f32x4){0.f,0.f,0.f,0.f};

  auto stage = [&](int buf, int kt){
    size_t kb = (size_t)(kt*64)*2;
    #pragma unroll
    for (int j = 0; j < 4; ++j){
      int r = srow + j*32;
      int bs = sbyte ^ ((r & 7) << 4);
      gload16((const ushort*)(Agb + (size_t)r*(lda*2) + kb + bs), &As[buf][0] + (t + j*256)*8);
      gload16((const ushort*)(Bgb + (size_t)r*(ldb*2) + kb + bs), &Bs[buf][0] + (t + j*256)*8);
    }
  };
  auto frag = [&](const ushort* lbuf, int row, int cb)->bf16x8{
    int b = cb ^ ((row & 7) << 4);
    return *reinterpret_cast<const bf16x8*>((const char*)lbuf + row*128 + b);
  };
  auto compute = [&](int buf){
    bf16x8 af[2][4], bf[2][4];
    #pragma unroll
    for (int kk = 0; kk < 2; ++kk){
      #pragma unroll
      for (int m = 0; m < 4; ++m) af[kk][m] = frag(&As[buf][0], wr*64 + m*16 + fr, kk*64 + fq*16);
      #pragma unroll
      for (int n = 0; n < 4; ++n) bf[kk][n] = frag(&Bs[buf][0], wc*64 + n*16 + fr, kk*64 + fq*16);
    }
    #pragma unroll
    for (int kk = 0; kk < 2; ++kk)
      #pragma unroll
      for (int m = 0; m < 4; ++m)
        #pragma unroll
        for (int n = 0; n < 4; ++n)
          acc[m][n] = __builtin_amdgcn_mfma_f32_16x16x32_bf16(af[kk][m], bf[kk][n], acc[m][n], 0, 0, 0);
  };

  int nk = K >> 6;
  stage(0, 0);
  __syncthreads();
  int cur = 0;
  for (int kt = 0; kt < nk - 1; ++kt){
    stage(cur ^ 1, kt + 1);
    compute(cur);
    __syncthreads();
    cur ^= 1;
  }
  compute(cur);

  int fqb = fq << 2;
  #pragma unroll
  for (int m = 0; m < 4; ++m){
    #pragma unroll
    for (int n = 0; n < 4; ++n){
      #pragma unroll
      for (int r = 0; r < 4; ++r){
        int row = mt*128 + wr*64 + m*16 + fqb + r;
        int col = nt*128 + wc*64 + n*16 + fr;
        size_t oidx = (size_t)row*ldo + col;
        float v = acc[m][n][r];
        if (MODE == 0) outB[oidx] = f2b(v);
        else           outF[oidx] = v + bias[col] + resid[oidx];
      }
    }
  }
}

// ---------------- 64x64 GEMM (batched, for logits) ----------------
__global__ __launch_bounds__(256) void gemm64(
    const ushort* __restrict__ A, const ushort* __restrict__ Bt,
    int M, int N, int K, int lda, int ldb, int ldo,
    long long sA, long long sB, long long sO, float* __restrict__ outF)
{
  __shared__ ushort As[64][40];
  __shared__ ushort Bs[64][40];
  int ntiles = N >> 6;
  int mt = blockIdx.x / ntiles;
  int nt = blockIdx.x - mt*ntiles;
  int z  = blockIdx.z;
  const ushort* Ab = A + (size_t)z*sA;
  const ushort* Bb = Bt + (size_t)z*sB;
  int t = threadIdx.x;
  int w = t >> 6, l = t & 63;
  int lr = t >> 2, lc = (t & 3) << 3;
  int fr = l & 15, fk = (l >> 4) << 3;
  f32x4 acc[4];
  #pragma unroll
  for (int n = 0; n < 4; ++n) acc[n] = (f32x4){0.f,0.f,0.f,0.f};

  const ushort* Aptr = Ab + (size_t)(mt*64 + lr)*lda + lc;
  const ushort* Bptr = Bb + (size_t)(nt*64 + lr)*ldb + lc;
  for (int k0 = 0; k0 < K; k0 += 32){
    uint4 av = *reinterpret_cast<const uint4*>(Aptr + k0);
    uint4 bv = *reinterpret_cast<const uint4*>(Bptr + k0);
    __syncthreads();
    *reinterpret_cast<uint4*>(&As[lr][lc]) = av;
    *reinterpret_cast<uint4*>(&Bs[lr][lc]) = bv;
    __syncthreads();
    bf16x8 af = *reinterpret_cast<const bf16x8*>(&As[w*16 + fr][fk]);
    #pragma unroll
    for (int n = 0; n < 4; ++n){
      bf16x8 bf = *reinterpret_cast<const bf16x8*>(&Bs[n*16 + fr][fk]);
      acc[n] = __builtin_amdgcn_mfma_f32_16x16x32_bf16(af, bf, acc[n], 0, 0, 0);
    }
  }
  int fq = l >> 4;
  #pragma unroll
  for (int n = 0; n < 4; ++n){
    #pragma unroll
    for (int r = 0; r < 4; ++r){
      int row = mt*64 + w*16 + fq*4 + r;
      int col = nt*64 + n*16 + fr;
      outF[(size_t)z*sO + (size_t)row*ldo + col] = acc[n][r];
    }
  }
}

// ---------------- T_ip[b][k][n] = 0.125 * sum_c text[b,k,c]*ip[b,n,c] ----------------
__global__ __launch_bounds__(64) void tip_k(const float* __restrict__ enc, float* __restrict__ tip){
  int k = blockIdx.x, n = blockIdx.y, b = blockIdx.z;
  const float* text = enc + ((size_t)b*81 + k)*2048;
  const float* ip   = enc + ((size_t)b*81 + 77 + n)*2048;
  int l = threadIdx.x;
  float acc = 0.f;
  for (int c = l; c < 2048; c += 64) acc += text[c]*ip[c];
  for (int off = 32; off > 0; off >>= 1) acc += __shfl_down(acc, off);
  if (l == 0) tip[((size_t)b*77 + k)*4 + n] = acc * 0.125f;
}

// ---------------- softmax over 77 logits + sem = p @ T_ip ----------------
__global__ __launch_bounds__(128) void semsm_k(const float* __restrict__ logits,
    const float* __restrict__ tip, float* __restrict__ sem)
{
  int row = blockIdx.x;
  int b = row >> 12;
  int t = threadIdx.x;
  __shared__ float ls[77];
  __shared__ float ps[77];
  if (t < 77) ls[t] = logits[(size_t)row*128 + t] * 0.125f;
  __syncthreads();
  float m = -1e30f;
  for (int k = 0; k < 77; ++k) m = fmaxf(m, ls[k]);
  float s = 0.f;
  for (int k = 0; k < 77; ++k) s += __expf(ls[k]-m);
  if (t < 77) ps[t] = __expf(ls[t]-m) / s;
  __syncthreads();
  if (t < 4){
    float acc = 0.f;
    const float* tp = tip + (size_t)b*77*4 + t;
    for (int k = 0; k < 77; ++k) acc += ps[k]*tp[k*4];
    sem[(size_t)row*4 + t] = acc;
  }
}

// ---------------- MFMA fused text+ip attention ----------------
__global__ __launch_bounds__(256) void attn_mfma_k(
    const ushort* __restrict__ qb, const ushort* __restrict__ pall,
    const float* __restrict__ sem, const float* __restrict__ mask,
    ushort* __restrict__ hmid)
{
  int qt = blockIdx.x;   // 0..63
  int h  = blockIdx.y;   // 0..19
  int b  = blockIdx.z;   // 0..3
  __shared__ ushort Qs[64][72];
  __shared__ ushort Ks[96][72];
  __shared__ ushort Vt[64][104];  // V^T: [d][k]
  __shared__ ushort Ps[64][104];
  int t = threadIdx.x;
  int w = t >> 6, l = t & 63;
  const ushort* pb = pall + (size_t)b*81*5120 + h*64;

  {
    int base = b*4096 + qt*64;
    #pragma unroll
    for (int it = 0; it < 2; ++it){
      int chunk = t + it*256;
      int r = chunk >> 3, dp = (chunk & 7) << 3;
      uint4 v = *reinterpret_cast<const uint4*>(qb + (size_t)(base + r)*1280 + h*64 + dp);
      *reinterpret_cast<uint4*>(&Qs[r][dp]) = v;
    }
  }
  #pragma unroll
  for (int it = 0; it < 6; ++it){
    int chunk = t + it*256;
    int k = chunk >> 4, dp = (chunk & 15) << 2;
    ushort4 v = make_ushort4(0,0,0,0);
    if (k < 77)      v = *reinterpret_cast<const ushort4*>(pb + (size_t)k*5120 + dp);
    else if (k < 81) v = *reinterpret_cast<const ushort4*>(pb + (size_t)k*5120 + 2560 + dp);
    *reinterpret_cast<ushort4*>(&Ks[k][dp]) = v;
  }
  #pragma unroll
  for (int it = 0; it < 24; ++it){
    int idx = t + it*256;
    int k = idx >> 6, d = idx & 63;
    ushort v = 0;
    if (k < 77)      v = pb[(size_t)k*5120 + 1280 + d];
    else if (k < 81) v = pb[(size_t)k*5120 + 3840 + d];
    Vt[d][k] = v;
  }
  __syncthreads();

  int fr = l & 15, fq = l >> 4, fkb = fq << 3;
  int c = fr;

  f32x4 s[6];
  #pragma unroll
  for (int n = 0; n < 6; ++n) s[n] = (f32x4){0.f,0.f,0.f,0.f};
  #pragma unroll
  for (int ks = 0; ks < 2; ++ks){
    bf16x8 aq = *reinterpret_cast<const bf16x8*>(&Qs[w*16 + fr][ks*32 + fkb]);
    #pragma unroll
    for (int n = 0; n < 6; ++n){
      bf16x8 bk = *reinterpret_cast<const bf16x8*>(&Ks[n*16 + fr][ks*32 + fkb]);
      s[n] = __builtin_amdgcn_mfma_f32_16x16x32_bf16(aq, bk, s[n], 0, 0, 0);
    }
  }

  int rowbase = qt*64 + w*16 + (fq << 2);
  #pragma unroll
  for (int r = 0; r < 4; ++r){
    float lg[6];
    #pragma unroll
    for (int n = 0; n < 6; ++n) lg[n] = s[n][r]*0.125f;

    float mt = fmaxf(fmaxf(lg[0],lg[1]), fmaxf(lg[2],lg[3]));
    if (c < 13) mt = fmaxf(mt, lg[4]);
    #pragma unroll
    for (int off = 1; off < 16; off <<= 1) mt = fmaxf(mt, __shfl_xor(mt, off));
    float st = __expf(lg[0]-mt) + __expf(lg[1]-mt) + __expf(lg[2]-mt) + __expf(lg[3]-mt);
    if (c < 13) st += __expf(lg[4]-mt);
    #pragma unroll
    for (int off = 1; off < 16; off <<= 1) st += __shfl_xor(st, off);
    float invst = 1.f/st;

    size_t qrow = (size_t)b*4096 + rowbase + r;
    float f4 = -1e30f, f5 = -1e30f;
    if (c >= 13) f4 = lg[4] + 0.5f*sem[qrow*4 + (c-13)];
    if (c == 0)  f5 = lg[5] + 0.5f*sem[qrow*4 + 3];
    float m2 = fmaxf(f4, f5);
    #pragma unroll
    for (int off = 1; off < 16; off <<= 1) m2 = fmaxf(m2, __shfl_xor(m2, off));
    float si = (c >= 13 ? __expf(f4-m2) : 0.f) + (c == 0 ? __expf(f5-m2) : 0.f);
    #pragma unroll
    for (int off = 1; off < 16; off <<= 1) si += __shfl_xor(si, off);
    float pmul = mask[rowbase + r] / si;

    int prow = w*16 + (fq << 2) + r;
    #pragma unroll
    for (int n = 0; n < 4; ++n) Ps[prow][n*16 + c] = f2b(__expf(lg[n]-mt)*invst);
    Ps[prow][64 + c] = f2b(c < 13 ? __expf(lg[4]-mt)*invst : __expf(f4-m2)*pmul);
    Ps[prow][80 + c] = f2b(c == 0 ? __expf(f5-m2)*pmul : 0.f);
  }
  __syncthreads();

  f32x4 o[4];
  #pragma unroll
  for (int df = 0; df < 4; ++df) o[df] = (f32x4){0.f,0.f,0.f,0.f};
  #pragma unroll
  for (int ks = 0; ks < 3; ++ks){
    bf16x8 ap = *reinterpret_cast<const bf16x8*>(&Ps[w*16 + fr][ks*32 + fkb]);
    #pragma unroll
    for (int df = 0; df < 4; ++df){
      bf16x8 bv = *reinterpret_cast<const bf16x8*>(&Vt[df*16 + fr][ks*32 + fkb]);
      o[df] = __builtin_amdgcn_mfma_f32_16x16x32_bf16(ap, bv, o[df], 0, 0, 0);
    }
  }
  #pragma unroll
  for (int df = 0; df < 4; ++df)
    #pragma unroll
    for (int r = 0; r < 4; ++r)
      hmid[((size_t)b*4096 + rowbase + r)*1280 + h*64 + df*16 + c] = f2b(o[df][r]);
}

extern "C" void kernel_launch(void* const* d_in, const int* in_sizes, int n_in,
                              void* d_out, int out_size, void* d_ws, size_t ws_size,
                              hipStream_t stream)
{
  (void)in_sizes; (void)n_in; (void)out_size; (void)ws_size;
  const float* hs   = (const float*)d_in[0];
  const float* enc  = (const float*)d_in[1];
  const float* mask = (const float*)d_in[2];
  const float* Wq   = (const float*)d_in[3];
  const float* Wk   = (const float*)d_in[4];
  const float* Wv   = (const float*)d_in[5];
  const float* Wkip = (const float*)d_in[6];
  const float* Wvip = (const float*)d_in[7];
  const float* Wout = (const float*)d_in[8];
  const float* bout = (const float*)d_in[9];
  float* out = (float*)d_out;
  char* ws = (char*)d_ws;

  size_t off = 0;
  auto alloc = [&](size_t bytes)->char*{
    char* p = ws + off; off += (bytes + 255) & ~(size_t)255; return p;
  };
  ushort* hs_bf   = (ushort*)alloc(16384ull*1280*2);   // reused as hmid
  ushort* q_bf    = (ushort*)alloc(16384ull*1280*2);
  ushort* enc_bf  = (ushort*)alloc(384ull*2048*2);
  ushort* wqt     = (ushort*)alloc(1280ull*1280*2);
  ushort* woutt   = (ushort*)alloc(1280ull*1280*2);
  ushort* wcat    = (ushort*)alloc(5120ull*2048*2);
  ushort* pall    = (ushort*)alloc(384ull*5120*2);
  float*  logits  = (float*)alloc(16384ull*128*4);
  float*  tip     = (float*)alloc(4ull*77*4*4);
  float*  semb    = (float*)alloc(16384ull*4*4);
  ushort* hmid_bf = hs_bf;

  cvt_bf16_k<<<20480, 256, 0, stream>>>(hs, hs_bf, 16384*1280/4);
  cvt_enc_k<<<768, 256, 0, stream>>>(enc, enc_bf);
  transpose_bf16_k<<<dim3(40,40), 256, 0, stream>>>(Wq,   wqt,   1280, 1280);
  transpose_bf16_k<<<dim3(40,40), 256, 0, stream>>>(Wout, woutt, 1280, 1280);
  transpose_bf16_k<<<dim3(40,64), 256, 0, stream>>>(Wk,   wcat + 0ull*1280*2048, 2048, 1280);
  transpose_bf16_k<<<dim3(40,64), 256, 0, stream>>>(Wv,   wcat + 1ull*1280*2048, 2048, 1280);
  transpose_bf16_k<<<dim3(40,64), 256, 0, stream>>>(Wkip, wcat + 2ull*1280*2048, 2048, 1280);
  transpose_bf16_k<<<dim3(40,64), 256, 0, stream>>>(Wvip, wcat + 3ull*1280*2048, 2048, 1280);

  // encoder projections: pall[384][5120] = enc_bf @ wcat^T  (bf16 out)
  gemm128<0><<<dim3((384/128)*(5120/128)), 256, 0, stream>>>(enc_bf, wcat, 384, 5120, 2048,
      2048, 2048, 5120, nullptr, pall, nullptr, nullptr);

  // q = hs @ Wq (bf16 out) — 256x256 8-phase
  gemm256<0><<<dim3((16384/256)*(1280/256)), 512, 0, stream>>>(hs_bf, wqt, 16384, 1280, 1280,
      1280, 1280, 1280, nullptr, q_bf, nullptr, nullptr);

  tip_k<<<dim3(77,4,4), 64, 0, stream>>>(enc, tip);

  // logits[b][4096][128] = q @ k_text^T  (batched; N padded to 128)
  gemm64<<<dim3((4096/64)*(128/64),1,4), 256, 0, stream>>>(q_bf, pall, 4096, 128, 1280,
      1280, 5120, 128, 4096ll*1280, 81ll*5120, 4096ll*128, logits);

  semsm_k<<<16384, 128, 0, stream>>>(logits, tip, semb);

  attn_mfma_k<<<dim3(64,20,4), 256, 0, stream>>>(q_bf, pall, semb, mask, hmid_bf);

  // out = hmid @ Wout + bout + residual — 256x256 8-phase
  gemm256<1><<<dim3((16384/256)*(1280/256)), 512, 0, stream>>>(hmid_bf, woutt, 16384, 1280, 1280,
      1280, 1280, 1280, out, nullptr, bout, hs);
}

// Round 5
// 402.374 us; speedup vs baseline: 1.0344x; 1.0344x over previous
//
#include <hip/hip_runtime.h>

typedef __bf16 bf16x8 __attribute__((ext_vector_type(8)));
typedef float f32x4 __attribute__((ext_vector_type(4)));

__device__ __forceinline__ ushort f2b(float f){
  union { float f; unsigned u; } v; v.f = f;
  unsigned r = v.u + 0x7FFFu + ((v.u >> 16) & 1u);
  return (ushort)(r >> 16);
}
__device__ __forceinline__ float b2f(ushort b){
  union { unsigned u; float f; } v; v.u = ((unsigned)b) << 16; return v.f;
}

__device__ __forceinline__ void gload16(const ushort* g, ushort* lds){
  __builtin_amdgcn_global_load_lds(
      (const __attribute__((address_space(1))) unsigned int*)(g),
      (__attribute__((address_space(3))) unsigned int*)(lds), 16, 0, 0);
}

#define WAIT_LGKM do { asm volatile("s_waitcnt lgkmcnt(0)" ::: "memory"); __builtin_amdgcn_sched_barrier(0); } while(0)
#define VMW(n)    do { asm volatile("s_waitcnt vmcnt(" #n ")" ::: "memory"); __builtin_amdgcn_sched_barrier(0); } while(0)
#define BARR      do { __builtin_amdgcn_s_barrier(); __builtin_amdgcn_sched_barrier(0); } while(0)

// ---------------- converts ----------------
__global__ __launch_bounds__(256) void cvt_bf16_k(const float* __restrict__ in,
                                                  ushort* __restrict__ out, int n4){
  int i = blockIdx.x*256 + threadIdx.x;
  if (i < n4){
    f32x4 v = reinterpret_cast<const f32x4*>(in)[i];
    ushort4 o = make_ushort4(f2b(v.x), f2b(v.y), f2b(v.z), f2b(v.w));
    reinterpret_cast<ushort4*>(out)[i] = o;
  }
}

__global__ __launch_bounds__(256) void cvt_enc_k(const float* __restrict__ in,
                                                 ushort* __restrict__ out){
  int i = blockIdx.x*256 + threadIdx.x;
  if (i < 384*2048/4){
    f32x4 v = {0.f,0.f,0.f,0.f};
    if (i < 324*2048/4) v = reinterpret_cast<const f32x4*>(in)[i];
    ushort4 o = make_ushort4(f2b(v.x), f2b(v.y), f2b(v.z), f2b(v.w));
    reinterpret_cast<ushort4*>(out)[i] = o;
  }
}

// W[K][N] fp32 -> Wt[N][K] bf16
__global__ __launch_bounds__(256) void transpose_bf16_k(const float* __restrict__ W,
                                                        ushort* __restrict__ Wt, int K, int N){
  __shared__ float tile[32][33];
  int n0 = blockIdx.x*32, k0 = blockIdx.y*32;
  int tx = threadIdx.x & 31, ty = threadIdx.x >> 5;
  for (int i = ty; i < 32; i += 8) tile[i][tx] = W[(size_t)(k0+i)*N + n0+tx];
  __syncthreads();
  for (int i = ty; i < 32; i += 8) Wt[(size_t)(n0+i)*K + k0+tx] = f2b(tile[tx][i]);
}

// ---------------- 256x256 8-phase GEMM, register-resident fragments ----------
// 512 threads / 8 waves (2Mx4N), BK=64, 128KiB LDS. Per K-tile: 4 phases,
// frags loaded ONCE (24 ds_read_b128/wave/K-tile) and reused across phases.
// vmcnt(6) (=3 half-tiles in flight) at p2/p4. Swizzle col ^= (row&7)<<3.
template<int MODE>
__global__ __launch_bounds__(512, 2) void gemm256(
    const ushort* __restrict__ A, const ushort* __restrict__ Bt,
    int M, int N, int K, int lda, int ldb, int ldo,
    float* __restrict__ outF, ushort* __restrict__ outB,
    const float* __restrict__ bias, const float* __restrict__ resid)
{
  __shared__ ushort As[2][2][128][64];
  __shared__ ushort Bs[2][2][128][64];
  int ntiles = N >> 8;
  int nwg = gridDim.x;
  int bid = blockIdx.x;
  if ((nwg & 7) == 0){
    int cpx = nwg >> 3;
    bid = (bid & 7)*cpx + (bid >> 3);
  }
  int mt = bid / ntiles;
  int nt = bid - mt*ntiles;
  int t = threadIdx.x;
  int wid = t >> 6, l = t & 63;
  int wr = wid >> 2, wc = wid & 3;           // wave grid 2(M) x 4(N)
  int fr = l & 15, fq = l >> 4;
  int swz = (fr & 7) << 3;

  int srow = t >> 3;
  int scol = ((t & 7) << 3) ^ ((srow & 7) << 3);
  const ushort* Asrc = A + (size_t)(mt*256 + srow)*lda + scol;
  const ushort* Bsrc = Bt + (size_t)(nt*256 + srow)*ldb + scol;

  auto stageA = [&](int h, int kt){
    int bufd = kt & 1;
    ushort* dst = &As[bufd][h][0][0] + t*8;
    const ushort* src = Asrc + (size_t)h*128*lda + (size_t)kt*64;
    gload16(src, dst);
    gload16(src + (size_t)64*lda, dst + 4096);
  };
  auto stageB = [&](int h, int kt){
    int bufd = kt & 1;
    ushort* dst = &Bs[bufd][h][0][0] + t*8;
    const ushort* src = Bsrc + (size_t)h*128*ldb + (size_t)kt*64;
    gload16(src, dst);
    gload16(src + (size_t)64*ldb, dst + 4096);
  };

  f32x4 acc[2][2][4][2];
  #pragma unroll
  for (int mq = 0; mq < 2; ++mq)
    #pragma unroll
    for (int nq = 0; nq < 2; ++nq)
      #pragma unroll
      for (int f = 0; f < 4; ++f)
        #pragma unroll
        for (int g = 0; g < 2; ++g) acc[mq][nq][f][g] = (f32x4){0.f,0.f,0.f,0.f};

  int nk = K >> 6;   // assumes nk >= 3

  // prologue: halves in steady-state global order
  stageB(0, 0); stageA(0, 0); stageA(1, 0); stageB(1, 0);
  stageB(0, 1); stageA(0, 1);
  VMW(6);
  BARR;

#define LOADA(dst, HALF) \
  _Pragma("unroll") for (int f = 0; f < 4; ++f){ \
    int ar = wr*64 + f*16 + fr; \
    dst[0][f] = *reinterpret_cast<const bf16x8*>(&As[buf][HALF][ar][(fq*8) ^ swz]); \
    dst[1][f] = *reinterpret_cast<const bf16x8*>(&As[buf][HALF][ar][(32 + fq*8) ^ swz]); \
  }
#define LOADB(dst, HALF) \
  _Pragma("unroll") for (int g = 0; g < 2; ++g){ \
    int br = wc*32 + g*16 + fr; \
    dst[0][g] = *reinterpret_cast<const bf16x8*>(&Bs[buf][HALF][br][(fq*8) ^ swz]); \
    dst[1][g] = *reinterpret_cast<const bf16x8*>(&Bs[buf][HALF][br][(32 + fq*8) ^ swz]); \
  }
#define MFMA_Q(MQ, NQ, AF, BF) do { \
  __builtin_amdgcn_s_setprio(1); \
  _Pragma("unroll") for (int kk = 0; kk < 2; ++kk) \
    _Pragma("unroll") for (int f = 0; f < 4; ++f) \
      _Pragma("unroll") for (int g = 0; g < 2; ++g) \
        acc[MQ][NQ][f][g] = __builtin_amdgcn_mfma_f32_16x16x32_bf16(AF[kk][f], BF[kk][g], acc[MQ][NQ][f][g], 0, 0, 0); \
  __builtin_amdgcn_s_setprio(0); \
  __builtin_amdgcn_sched_barrier(0); \
} while(0)

  for (int T = 0; T < nk; ++T){
    int buf = T & 1;
    bf16x8 af0[2][4], af1[2][4], bf0[2][2], bf1[2][2];
    // p1: load A0,B0; compute (0,0); stage A1(T+1)
    LOADA(af0, 0); LOADB(bf0, 0);
    if (T+1 < nk) stageA(1, T+1);
    BARR; WAIT_LGKM;
    MFMA_Q(0, 0, af0, bf0);
    BARR;
    // p2: load A1; compute (1,0); stage B1(T+1); mid vmcnt
    LOADA(af1, 1);
    if (T+1 < nk) stageB(1, T+1);
    BARR; WAIT_LGKM;
    MFMA_Q(1, 0, af1, bf0);
    if (T == nk-1) { VMW(0); } else { VMW(6); }
    BARR;
    // p3: load B1; compute (0,1); stage B0(T+2)
    LOADB(bf1, 1);
    if (T+2 < nk) stageB(0, T+2);
    BARR; WAIT_LGKM;
    MFMA_Q(0, 1, af0, bf1);
    BARR;
    // p4: compute (1,1); stage A0(T+2); boundary vmcnt
    if (T+2 < nk) stageA(0, T+2);
    BARR; WAIT_LGKM;
    MFMA_Q(1, 1, af1, bf1);
    if (T < nk-1){ if (T+1 == nk-1) { VMW(0); } else { VMW(6); } }
    BARR;
  }
#undef LOADA
#undef LOADB
#undef MFMA_Q

  int fqb = fq << 2;
  #pragma unroll
  for (int mq = 0; mq < 2; ++mq){
    #pragma unroll
    for (int nq = 0; nq < 2; ++nq){
      #pragma unroll
      for (int f = 0; f < 4; ++f){
        #pragma unroll
        for (int g = 0; g < 2; ++g){
          #pragma unroll
          for (int r = 0; r < 4; ++r){
            int row = mt*256 + mq*128 + wr*64 + f*16 + fqb + r;
            int col = nt*256 + nq*128 + wc*32 + g*16 + fr;
            size_t oidx = (size_t)row*ldo + col;
            float v = acc[mq][nq][f][g][r];
            if (MODE == 0) outB[oidx] = f2b(v);
            else           outF[oidx] = v + bias[col] + resid[oidx];
          }
        }
      }
    }
  }
}

// ---------------- 128x128 GEMM, BK=64, double-buffered 2-phase, swizzled LDS ----------------
// (kept for the 384-row encoder projection)
template<int MODE>
__global__ __launch_bounds__(256) void gemm128(
    const ushort* __restrict__ A, const ushort* __restrict__ Bt,
    int M, int N, int K, int lda, int ldb, int ldo,
    float* __restrict__ outF, ushort* __restrict__ outB,
    const float* __restrict__ bias, const float* __restrict__ resid)
{
  __shared__ ushort As[2][128*64];
  __shared__ ushort Bs[2][128*64];
  int ntiles = N >> 7;
  int nwg = gridDim.x;
  int bid = blockIdx.x;
  if ((nwg & 7) == 0){
    int cpx = nwg >> 3;
    bid = (bid & 7)*cpx + (bid >> 3);
  }
  int mt = bid / ntiles;
  int nt = bid - mt*ntiles;
  int t = threadIdx.x;
  int w = t >> 6, l = t & 63;
  int wr = w >> 1, wc = w & 1;
  int fr = l & 15, fq = l >> 4;

  const char* Agb = (const char*)(A + (size_t)(mt*128)*lda);
  const char* Bgb = (const char*)(Bt + (size_t)(nt*128)*ldb);
  int srow = t >> 3;
  int sbyte = (t & 7) << 4;

  f32x4 acc[4][4];
  #pragma unroll
  for (int m = 0; m < 4; ++m)
    #pragma unroll
    for (int n = 0; n < 4; ++n) acc[m][n] = (f32x4){0.f,0.f,0.f,0.f};

  auto stage = [&](int buf, int kt){
    size_t kb = (size_t)(kt*64)*2;
    #pragma unroll
    for (int j = 0; j < 4; ++j){
      int r = srow + j*32;
      int bs = sbyte ^ ((r & 7) << 4);
      gload16((const ushort*)(Agb + (size_t)r*(lda*2) + kb + bs), &As[buf][0] + (t + j*256)*8);
      gload16((const ushort*)(Bgb + (size_t)r*(ldb*2) + kb + bs), &Bs[buf][0] + (t + j*256)*8);
    }
  };
  auto frag = [&](const ushort* lbuf, int row, int cb)->bf16x8{
    int b = cb ^ ((row & 7) << 4);
    return *reinterpret_cast<const bf16x8*>((const char*)lbuf + row*128 + b);
  };
  auto compute = [&](int buf){
    bf16x8 af[2][4], bf[2][4];
    #pragma unroll
    for (int kk = 0; kk < 2; ++kk){
      #pragma unroll
      for (int m = 0; m < 4; ++m) af[kk][m] = frag(&As[buf][0], wr*64 + m*16 + fr, kk*64 + fq*16);
      #pragma unroll
      for (int n = 0; n < 4; ++n) bf[kk][n] = frag(&Bs[buf][0], wc*64 + n*16 + fr, kk*64 + fq*16);
    }
    #pragma unroll
    for (int kk = 0; kk < 2; ++kk)
      #pragma unroll
      for (int m = 0; m < 4; ++m)
        #pragma unroll
        for (int n = 0; n < 4; ++n)
          acc[m][n] = __builtin_amdgcn_mfma_f32_16x16x32_bf16(af[kk][m], bf[kk][n], acc[m][n], 0, 0, 0);
  };

  int nk = K >> 6;
  stage(0, 0);
  __syncthreads();
  int cur = 0;
  for (int kt = 0; kt < nk - 1; ++kt){
    stage(cur ^ 1, kt + 1);
    compute(cur);
    __syncthreads();
    cur ^= 1;
  }
  compute(cur);

  int fqb = fq << 2;
  #pragma unroll
  for (int m = 0; m < 4; ++m){
    #pragma unroll
    for (int n = 0; n < 4; ++n){
      #pragma unroll
      for (int r = 0; r < 4; ++r){
        int row = mt*128 + wr*64 + m*16 + fqb + r;
        int col = nt*128 + wc*64 + n*16 + fr;
        size_t oidx = (size_t)row*ldo + col;
        float v = acc[m][n][r];
        if (MODE == 0) outB[oidx] = f2b(v);
        else           outF[oidx] = v + bias[col] + resid[oidx];
      }
    }
  }
}

// ---------------- 64x64 GEMM (batched, for logits) ----------------
__global__ __launch_bounds__(256) void gemm64(
    const ushort* __restrict__ A, const ushort* __restrict__ Bt,
    int M, int N, int K, int lda, int ldb, int ldo,
    long long sA, long long sB, long long sO, float* __restrict__ outF)
{
  __shared__ ushort As[64][40];
  __shared__ ushort Bs[64][40];
  int ntiles = N >> 6;
  int mt = blockIdx.x / ntiles;
  int nt = blockIdx.x - mt*ntiles;
  int z  = blockIdx.z;
  const ushort* Ab = A + (size_t)z*sA;
  const ushort* Bb = Bt + (size_t)z*sB;
  int t = threadIdx.x;
  int w = t >> 6, l = t & 63;
  int lr = t >> 2, lc = (t & 3) << 3;
  int fr = l & 15, fk = (l >> 4) << 3;
  f32x4 acc[4];
  #pragma unroll
  for (int n = 0; n < 4; ++n) acc[n] = (f32x4){0.f,0.f,0.f,0.f};

  const ushort* Aptr = Ab + (size_t)(mt*64 + lr)*lda + lc;
  const ushort* Bptr = Bb + (size_t)(nt*64 + lr)*ldb + lc;
  for (int k0 = 0; k0 < K; k0 += 32){
    uint4 av = *reinterpret_cast<const uint4*>(Aptr + k0);
    uint4 bv = *reinterpret_cast<const uint4*>(Bptr + k0);
    __syncthreads();
    *reinterpret_cast<uint4*>(&As[lr][lc]) = av;
    *reinterpret_cast<uint4*>(&Bs[lr][lc]) = bv;
    __syncthreads();
    bf16x8 af = *reinterpret_cast<const bf16x8*>(&As[w*16 + fr][fk]);
    #pragma unroll
    for (int n = 0; n < 4; ++n){
      bf16x8 bf = *reinterpret_cast<const bf16x8*>(&Bs[n*16 + fr][fk]);
      acc[n] = __builtin_amdgcn_mfma_f32_16x16x32_bf16(af, bf, acc[n], 0, 0, 0);
    }
  }
  int fq = l >> 4;
  #pragma unroll
  for (int n = 0; n < 4; ++n){
    #pragma unroll
    for (int r = 0; r < 4; ++r){
      int row = mt*64 + w*16 + fq*4 + r;
      int col = nt*64 + n*16 + fr;
      outF[(size_t)z*sO + (size_t)row*ldo + col] = acc[n][r];
    }
  }
}

// ---------------- T_ip[b][k][n] = 0.125 * sum_c text[b,k,c]*ip[b,n,c] ----------------
__global__ __launch_bounds__(64) void tip_k(const float* __restrict__ enc, float* __restrict__ tip){
  int k = blockIdx.x, n = blockIdx.y, b = blockIdx.z;
  const float* text = enc + ((size_t)b*81 + k)*2048;
  const float* ip   = enc + ((size_t)b*81 + 77 + n)*2048;
  int l = threadIdx.x;
  float acc = 0.f;
  for (int c = l; c < 2048; c += 64) acc += text[c]*ip[c];
  for (int off = 32; off > 0; off >>= 1) acc += __shfl_down(acc, off);
  if (l == 0) tip[((size_t)b*77 + k)*4 + n] = acc * 0.125f;
}

// ---------------- softmax over 77 logits + sem = p @ T_ip ----------------
__global__ __launch_bounds__(128) void semsm_k(const float* __restrict__ logits,
    const float* __restrict__ tip, float* __restrict__ sem)
{
  int row = blockIdx.x;
  int b = row >> 12;
  int t = threadIdx.x;
  __shared__ float ls[77];
  __shared__ float ps[77];
  if (t < 77) ls[t] = logits[(size_t)row*128 + t] * 0.125f;
  __syncthreads();
  float m = -1e30f;
  for (int k = 0; k < 77; ++k) m = fmaxf(m, ls[k]);
  float s = 0.f;
  for (int k = 0; k < 77; ++k) s += __expf(ls[k]-m);
  if (t < 77) ps[t] = __expf(ls[t]-m) / s;
  __syncthreads();
  if (t < 4){
    float acc = 0.f;
    const float* tp = tip + (size_t)b*77*4 + t;
    for (int k = 0; k < 77; ++k) acc += ps[k]*tp[k*4];
    sem[(size_t)row*4 + t] = acc;
  }
}

// ---------------- MFMA fused text+ip attention ----------------
__global__ __launch_bounds__(256) void attn_mfma_k(
    const ushort* __restrict__ qb, const ushort* __restrict__ pall,
    const float* __restrict__ sem, const float* __restrict__ mask,
    ushort* __restrict__ hmid)
{
  int qt = blockIdx.x;   // 0..63
  int h  = blockIdx.y;   // 0..19
  int b  = blockIdx.z;   // 0..3
  __shared__ ushort Qs[64][72];
  __shared__ ushort Ks[96][72];
  __shared__ ushort Vt[64][104];  // V^T: [d][k]
  __shared__ ushort Ps[64][104];
  int t = threadIdx.x;
  int w = t >> 6, l = t & 63;
  const ushort* pb = pall + (size_t)b*81*5120 + h*64;

  {
    int base = b*4096 + qt*64;
    #pragma unroll
    for (int it = 0; it < 2; ++it){
      int chunk = t + it*256;
      int r = chunk >> 3, dp = (chunk & 7) << 3;
      uint4 v = *reinterpret_cast<const uint4*>(qb + (size_t)(base + r)*1280 + h*64 + dp);
      *reinterpret_cast<uint4*>(&Qs[r][dp]) = v;
    }
  }
  #pragma unroll
  for (int it = 0; it < 6; ++it){
    int chunk = t + it*256;
    int k = chunk >> 4, dp = (chunk & 15) << 2;
    ushort4 v = make_ushort4(0,0,0,0);
    if (k < 77)      v = *reinterpret_cast<const ushort4*>(pb + (size_t)k*5120 + dp);
    else if (k < 81) v = *reinterpret_cast<const ushort4*>(pb + (size_t)k*5120 + 2560 + dp);
    *reinterpret_cast<ushort4*>(&Ks[k][dp]) = v;
  }
  #pragma unroll
  for (int it = 0; it < 24; ++it){
    int idx = t + it*256;
    int k = idx >> 6, d = idx & 63;
    ushort v = 0;
    if (k < 77)      v = pb[(size_t)k*5120 + 1280 + d];
    else if (k < 81) v = pb[(size_t)k*5120 + 3840 + d];
    Vt[d][k] = v;
  }
  __syncthreads();

  int fr = l & 15, fq = l >> 4, fkb = fq << 3;
  int c = fr;

  f32x4 s[6];
  #pragma unroll
  for (int n = 0; n < 6; ++n) s[n] = (f32x4){0.f,0.f,0.f,0.f};
  #pragma unroll
  for (int ks = 0; ks < 2; ++ks){
    bf16x8 aq = *reinterpret_cast<const bf16x8*>(&Qs[w*16 + fr][ks*32 + fkb]);
    #pragma unroll
    for (int n = 0; n < 6; ++n){
      bf16x8 bk = *reinterpret_cast<const bf16x8*>(&Ks[n*16 + fr][ks*32 + fkb]);
      s[n] = __builtin_amdgcn_mfma_f32_16x16x32_bf16(aq, bk, s[n], 0, 0, 0);
    }
  }

  int rowbase = qt*64 + w*16 + (fq << 2);
  #pragma unroll
  for (int r = 0; r < 4; ++r){
    float lg[6];
    #pragma unroll
    for (int n = 0; n < 6; ++n) lg[n] = s[n][r]*0.125f;

    float mt = fmaxf(fmaxf(lg[0],lg[1]), fmaxf(lg[2],lg[3]));
    if (c < 13) mt = fmaxf(mt, lg[4]);
    #pragma unroll
    for (int off = 1; off < 16; off <<= 1) mt = fmaxf(mt, __shfl_xor(mt, off));
    float st = __expf(lg[0]-mt) + __expf(lg[1]-mt) + __expf(lg[2]-mt) + __expf(lg[3]-mt);
    if (c < 13) st += __expf(lg[4]-mt);
    #pragma unroll
    for (int off = 1; off < 16; off <<= 1) st += __shfl_xor(st, off);
    float invst = 1.f/st;

    size_t qrow = (size_t)b*4096 + rowbase + r;
    float f4 = -1e30f, f5 = -1e30f;
    if (c >= 13) f4 = lg[4] + 0.5f*sem[qrow*4 + (c-13)];
    if (c == 0)  f5 = lg[5] + 0.5f*sem[qrow*4 + 3];
    float m2 = fmaxf(f4, f5);
    #pragma unroll
    for (int off = 1; off < 16; off <<= 1) m2 = fmaxf(m2, __shfl_xor(m2, off));
    float si = (c >= 13 ? __expf(f4-m2) : 0.f) + (c == 0 ? __expf(f5-m2) : 0.f);
    #pragma unroll
    for (int off = 1; off < 16; off <<= 1) si += __shfl_xor(si, off);
    float pmul = mask[rowbase + r] / si;

    int prow = w*16 + (fq << 2) + r;
    #pragma unroll
    for (int n = 0; n < 4; ++n) Ps[prow][n*16 + c] = f2b(__expf(lg[n]-mt)*invst);
    Ps[prow][64 + c] = f2b(c < 13 ? __expf(lg[4]-mt)*invst : __expf(f4-m2)*pmul);
    Ps[prow][80 + c] = f2b(c == 0 ? __expf(f5-m2)*pmul : 0.f);
  }
  __syncthreads();

  f32x4 o[4];
  #pragma unroll
  for (int df = 0; df < 4; ++df) o[df] = (f32x4){0.f,0.f,0.f,0.f};
  #pragma unroll
  for (int ks = 0; ks < 3; ++ks){
    bf16x8 ap = *reinterpret_cast<const bf16x8*>(&Ps[w*16 + fr][ks*32 + fkb]);
    #pragma unroll
    for (int df = 0; df < 4; ++df){
      bf16x8 bv = *reinterpret_cast<const bf16x8*>(&Vt[df*16 + fr][ks*32 + fkb]);
      o[df] = __builtin_amdgcn_mfma_f32_16x16x32_bf16(ap, bv, o[df], 0, 0, 0);
    }
  }
  #pragma unroll
  for (int df = 0; df < 4; ++df)
    #pragma unroll
    for (int r = 0; r < 4; ++r)
      hmid[((size_t)b*4096 + rowbase + r)*1280 + h*64 + df*16 + c] = f2b(o[df][r]);
}

extern "C" void kernel_launch(void* const* d_in, const int* in_sizes, int n_in,
                              void* d_out, int out_size, void* d_ws, size_t ws_size,
                              hipStream_t stream)
{
  (void)in_sizes; (void)n_in; (void)out_size; (void)ws_size;
  const float* hs   = (const float*)d_in[0];
  const float* enc  = (const float*)d_in[1];
  const float* mask = (const float*)d_in[2];
  const float* Wq   = (const float*)d_in[3];
  const float* Wk   = (const float*)d_in[4];
  const float* Wv   = (const float*)d_in[5];
  const float* Wkip = (const float*)d_in[6];
  const float* Wvip = (const float*)d_in[7];
  const float* Wout = (const float*)d_in[8];
  const float* bout = (const float*)d_in[9];
  float* out = (float*)d_out;
  char* ws = (char*)d_ws;

  size_t off = 0;
  auto alloc = [&](size_t bytes)->char*{
    char* p = ws + off; off += (bytes + 255) & ~(size_t)255; return p;
  };
  ushort* hs_bf   = (ushort*)alloc(16384ull*1280*2);   // reused as hmid
  ushort* q_bf    = (ushort*)alloc(16384ull*1280*2);
  ushort* enc_bf  = (ushort*)alloc(384ull*2048*2);
  ushort* wqt     = (ushort*)alloc(1280ull*1280*2);
  ushort* woutt   = (ushort*)alloc(1280ull*1280*2);
  ushort* wcat    = (ushort*)alloc(5120ull*2048*2);
  ushort* pall    = (ushort*)alloc(384ull*5120*2);
  float*  logits  = (float*)alloc(16384ull*128*4);
  float*  tip     = (float*)alloc(4ull*77*4*4);
  float*  semb    = (float*)alloc(16384ull*4*4);
  ushort* hmid_bf = hs_bf;

  cvt_bf16_k<<<20480, 256, 0, stream>>>(hs, hs_bf, 16384*1280/4);
  cvt_enc_k<<<768, 256, 0, stream>>>(enc, enc_bf);
  transpose_bf16_k<<<dim3(40,40), 256, 0, stream>>>(Wq,   wqt,   1280, 1280);
  transpose_bf16_k<<<dim3(40,40), 256, 0, stream>>>(Wout, woutt, 1280, 1280);
  transpose_bf16_k<<<dim3(40,64), 256, 0, stream>>>(Wk,   wcat + 0ull*1280*2048, 2048, 1280);
  transpose_bf16_k<<<dim3(40,64), 256, 0, stream>>>(Wv,   wcat + 1ull*1280*2048, 2048, 1280);
  transpose_bf16_k<<<dim3(40,64), 256, 0, stream>>>(Wkip, wcat + 2ull*1280*2048, 2048, 1280);
  transpose_bf16_k<<<dim3(40,64), 256, 0, stream>>>(Wvip, wcat + 3ull*1280*2048, 2048, 1280);

  // encoder projections: pall[384][5120] = enc_bf @ wcat^T  (bf16 out)
  gemm128<0><<<dim3((384/128)*(5120/128)), 256, 0, stream>>>(enc_bf, wcat, 384, 5120, 2048,
      2048, 2048, 5120, nullptr, pall, nullptr, nullptr);

  // q = hs @ Wq (bf16 out) — 256x256 8-phase
  gemm256<0><<<dim3((16384/256)*(1280/256)), 512, 0, stream>>>(hs_bf, wqt, 16384, 1280, 1280,
      1280, 1280, 1280, nullptr, q_bf, nullptr, nullptr);

  tip_k<<<dim3(77,4,4), 64, 0, stream>>>(enc, tip);

  // logits[b][4096][128] = q @ k_text^T  (batched; N padded to 128)
  gemm64<<<dim3((4096/64)*(128/64),1,4), 256, 0, stream>>>(q_bf, pall, 4096, 128, 1280,
      1280, 5120, 128, 4096ll*1280, 81ll*5120, 4096ll*128, logits);

  semsm_k<<<16384, 128, 0, stream>>>(logits, tip, semb);

  attn_mfma_k<<<dim3(64,20,4), 256, 0, stream>>>(q_bf, pall, semb, mask, hmid_bf);

  // out = hmid @ Wout + bout + residual — 256x256 8-phase
  gemm256<1><<<dim3((16384/256)*(1280/256)), 512, 0, stream>>>(hmid_bf, woutt, 16384, 1280, 1280,
      1280, 1280, 1280, out, nullptr, bout, hs);
}

// Round 6
// 387.963 us; speedup vs baseline: 1.0729x; 1.0371x over previous
//
#include <hip/hip_runtime.h>

typedef __bf16 bf16x8 __attribute__((ext_vector_type(8)));
typedef float f32x4 __attribute__((ext_vector_type(4)));

__device__ __forceinline__ ushort f2b(float f){
  union { float f; unsigned u; } v; v.f = f;
  unsigned r = v.u + 0x7FFFu + ((v.u >> 16) & 1u);
  return (ushort)(r >> 16);
}
__device__ __forceinline__ float b2f(ushort b){
  union { unsigned u; float f; } v; v.u = ((unsigned)b) << 16; return v.f;
}

__device__ __forceinline__ void gload16(const ushort* g, ushort* lds){
  __builtin_amdgcn_global_load_lds(
      (const __attribute__((address_space(1))) unsigned int*)(g),
      (__attribute__((address_space(3))) unsigned int*)(lds), 16, 0, 0);
}

// ---------------- converts ----------------
__global__ __launch_bounds__(256) void cvt_bf16_k(const float* __restrict__ in,
                                                  ushort* __restrict__ out, int n4){
  int i = blockIdx.x*256 + threadIdx.x;
  if (i < n4){
    f32x4 v = reinterpret_cast<const f32x4*>(in)[i];
    ushort4 o = make_ushort4(f2b(v.x), f2b(v.y), f2b(v.z), f2b(v.w));
    reinterpret_cast<ushort4*>(out)[i] = o;
  }
}

__global__ __launch_bounds__(256) void cvt_enc_k(const float* __restrict__ in,
                                                 ushort* __restrict__ out){
  int i = blockIdx.x*256 + threadIdx.x;
  if (i < 384*2048/4){
    f32x4 v = {0.f,0.f,0.f,0.f};
    if (i < 324*2048/4) v = reinterpret_cast<const f32x4*>(in)[i];
    ushort4 o = make_ushort4(f2b(v.x), f2b(v.y), f2b(v.z), f2b(v.w));
    reinterpret_cast<ushort4*>(out)[i] = o;
  }
}

// W[K][N] fp32 -> Wt[N][K] bf16
__global__ __launch_bounds__(256) void transpose_bf16_k(const float* __restrict__ W,
                                                        ushort* __restrict__ Wt, int K, int N){
  __shared__ float tile[32][33];
  int n0 = blockIdx.x*32, k0 = blockIdx.y*32;
  int tx = threadIdx.x & 31, ty = threadIdx.x >> 5;
  for (int i = ty; i < 32; i += 8) tile[i][tx] = W[(size_t)(k0+i)*N + n0+tx];
  __syncthreads();
  for (int i = ty; i < 32; i += 8) Wt[(size_t)(n0+i)*K + k0+tx] = f2b(tile[tx][i]);
}

// ---------------- 128x128 GEMM, m97 structure: BK=32, 16KB LDS, single buffer ----------------
// 256 thr / 4 waves (2x2), 16 MFMA + 8 ds_read_b128 + 4 global_load_lds per K-step,
// 2 barriers per K-step (vmcnt drain at 2nd). ~3 blocks/CU gives implicit overlap (m97/m114).
// LDS slot swizzle: slot ^= (row>>1)&3 (2-way max conflict), applied on pre-swizzled
// global source (gload_lds dest linear, rule #21) and on ds_read address.
// MODE 0: bf16 store; MODE 1: fp32 + bias[col] + resid.
template<int MODE>
__global__ __launch_bounds__(256) void gemm128s(
    const ushort* __restrict__ A, const ushort* __restrict__ Bt,
    int M, int N, int K, int lda, int ldb, int ldo,
    float* __restrict__ outF, ushort* __restrict__ outB,
    const float* __restrict__ bias, const float* __restrict__ resid)
{
  __shared__ ushort As[128][32];
  __shared__ ushort Bs[128][32];
  int ntiles = N >> 7;
  int nwg = gridDim.x;
  int bid = blockIdx.x;
  if ((nwg & 7) == 0){
    int cpx = nwg >> 3;
    bid = (bid & 7)*cpx + (bid >> 3);
  }
  int mt = bid / ntiles;
  int nt = bid - mt*ntiles;
  int t = threadIdx.x;
  int w = t >> 6, l = t & 63;
  int wr = w >> 1, wc = w & 1;
  int fr = l & 15, fq = l >> 4;

  // staging: 512 chunks of 16B per matrix per K-step; thread t -> chunks t, t+256.
  // chunk c: row=c>>2, slot s=c&3; LDS dest linear = c*16B; global col pre-swizzled.
  int r0 = t >> 2, s0 = t & 3;
  int r1 = r0 + 64;
  int sc0 = ((s0 ^ ((r0 >> 1) & 3)) << 3);
  int sc1 = ((s0 ^ ((r1 >> 1) & 3)) << 3);
  const ushort* Ag0 = A  + (size_t)(mt*128 + r0)*lda + sc0;
  const ushort* Ag1 = A  + (size_t)(mt*128 + r1)*lda + sc1;
  const ushort* Bg0 = Bt + (size_t)(nt*128 + r0)*ldb + sc0;
  const ushort* Bg1 = Bt + (size_t)(nt*128 + r1)*ldb + sc1;
  ushort* Al0 = &As[0][0] + t*8;
  ushort* Al1 = &As[0][0] + (t+256)*8;
  ushort* Bl0 = &Bs[0][0] + t*8;
  ushort* Bl1 = &Bs[0][0] + (t+256)*8;

  f32x4 acc[4][4];
  #pragma unroll
  for (int m = 0; m < 4; ++m)
    #pragma unroll
    for (int n = 0; n < 4; ++n) acc[m][n] = (f32x4){0.f,0.f,0.f,0.f};

  for (int k0 = 0; k0 < K; k0 += 32){
    if (k0) __syncthreads();
    gload16(Ag0 + k0, Al0);
    gload16(Ag1 + k0, Al1);
    gload16(Bg0 + k0, Bl0);
    gload16(Bg1 + k0, Bl1);
    __syncthreads();
    bf16x8 af[4], bf[4];
    #pragma unroll
    for (int m = 0; m < 4; ++m){
      int row = wr*64 + m*16 + fr;
      af[m] = *reinterpret_cast<const bf16x8*>(&As[row][(fq ^ ((row >> 1) & 3)) << 3]);
    }
    #pragma unroll
    for (int n = 0; n < 4; ++n){
      int row = wc*64 + n*16 + fr;
      bf[n] = *reinterpret_cast<const bf16x8*>(&Bs[row][(fq ^ ((row >> 1) & 3)) << 3]);
    }
    #pragma unroll
    for (int m = 0; m < 4; ++m)
      #pragma unroll
      for (int n = 0; n < 4; ++n)
        acc[m][n] = __builtin_amdgcn_mfma_f32_16x16x32_bf16(af[m], bf[n], acc[m][n], 0, 0, 0);
  }

  int fqb = fq << 2;
  #pragma unroll
  for (int m = 0; m < 4; ++m){
    #pragma unroll
    for (int n = 0; n < 4; ++n){
      #pragma unroll
      for (int r = 0; r < 4; ++r){
        int row = mt*128 + wr*64 + m*16 + fqb + r;
        int col = nt*128 + wc*64 + n*16 + fr;
        size_t oidx = (size_t)row*ldo + col;
        float v = acc[m][n][r];
        if (MODE == 0) outB[oidx] = f2b(v);
        else           outF[oidx] = v + bias[col] + resid[oidx];
      }
    }
  }
}

// ---------------- 64x64 GEMM (batched, for logits) ----------------
__global__ __launch_bounds__(256) void gemm64(
    const ushort* __restrict__ A, const ushort* __restrict__ Bt,
    int M, int N, int K, int lda, int ldb, int ldo,
    long long sA, long long sB, long long sO, float* __restrict__ outF)
{
  __shared__ ushort As[64][40];
  __shared__ ushort Bs[64][40];
  int ntiles = N >> 6;
  int mt = blockIdx.x / ntiles;
  int nt = blockIdx.x - mt*ntiles;
  int z  = blockIdx.z;
  const ushort* Ab = A + (size_t)z*sA;
  const ushort* Bb = Bt + (size_t)z*sB;
  int t = threadIdx.x;
  int w = t >> 6, l = t & 63;
  int lr = t >> 2, lc = (t & 3) << 3;
  int fr = l & 15, fk = (l >> 4) << 3;
  f32x4 acc[4];
  #pragma unroll
  for (int n = 0; n < 4; ++n) acc[n] = (f32x4){0.f,0.f,0.f,0.f};

  const ushort* Aptr = Ab + (size_t)(mt*64 + lr)*lda + lc;
  const ushort* Bptr = Bb + (size_t)(nt*64 + lr)*ldb + lc;
  for (int k0 = 0; k0 < K; k0 += 32){
    uint4 av = *reinterpret_cast<const uint4*>(Aptr + k0);
    uint4 bv = *reinterpret_cast<const uint4*>(Bptr + k0);
    __syncthreads();
    *reinterpret_cast<uint4*>(&As[lr][lc]) = av;
    *reinterpret_cast<uint4*>(&Bs[lr][lc]) = bv;
    __syncthreads();
    bf16x8 af = *reinterpret_cast<const bf16x8*>(&As[w*16 + fr][fk]);
    #pragma unroll
    for (int n = 0; n < 4; ++n){
      bf16x8 bf = *reinterpret_cast<const bf16x8*>(&Bs[n*16 + fr][fk]);
      acc[n] = __builtin_amdgcn_mfma_f32_16x16x32_bf16(af, bf, acc[n], 0, 0, 0);
    }
  }
  int fq = l >> 4;
  #pragma unroll
  for (int n = 0; n < 4; ++n){
    #pragma unroll
    for (int r = 0; r < 4; ++r){
      int row = mt*64 + w*16 + fq*4 + r;
      int col = nt*64 + n*16 + fr;
      outF[(size_t)z*sO + (size_t)row*ldo + col] = acc[n][r];
    }
  }
}

// ---------------- T_ip[b][k][n] = 0.125 * sum_c text[b,k,c]*ip[b,n,c] ----------------
__global__ __launch_bounds__(64) void tip_k(const float* __restrict__ enc, float* __restrict__ tip){
  int k = blockIdx.x, n = blockIdx.y, b = blockIdx.z;
  const float* text = enc + ((size_t)b*81 + k)*2048;
  const float* ip   = enc + ((size_t)b*81 + 77 + n)*2048;
  int l = threadIdx.x;
  float acc = 0.f;
  for (int c = l; c < 2048; c += 64) acc += text[c]*ip[c];
  for (int off = 32; off > 0; off >>= 1) acc += __shfl_down(acc, off);
  if (l == 0) tip[((size_t)b*77 + k)*4 + n] = acc * 0.125f;
}

// ---------------- softmax over 77 logits + sem = p @ T_ip (wave per row) ----------------
__global__ __launch_bounds__(256) void semsm_k(const float* __restrict__ logits,
    const float* __restrict__ tip, float* __restrict__ sem)
{
  int w = threadIdx.x >> 6, l = threadIdx.x & 63;
  int row = blockIdx.x*4 + w;            // 0..16383
  int b = row >> 12;
  const float* lp = logits + (size_t)row*128;
  float v0 = (l < 77)      ? lp[l]      * 0.125f : -1e30f;
  float v1 = (l + 64 < 77) ? lp[l + 64] * 0.125f : -1e30f;
  float m = fmaxf(v0, v1);
  #pragma unroll
  for (int off = 32; off > 0; off >>= 1) m = fmaxf(m, __shfl_xor(m, off));
  float e0 = (l < 77)      ? __expf(v0 - m) : 0.f;
  float e1 = (l + 64 < 77) ? __expf(v1 - m) : 0.f;
  float s = e0 + e1;
  #pragma unroll
  for (int off = 32; off > 0; off >>= 1) s += __shfl_xor(s, off);
  float inv = 1.f / s;
  const float* tp = tip + (size_t)b*77*4;
  float a0 = 0.f, a1 = 0.f, a2 = 0.f, a3 = 0.f;
  if (l < 77){
    float p = e0 * inv;
    a0 = p*tp[l*4]; a1 = p*tp[l*4+1]; a2 = p*tp[l*4+2]; a3 = p*tp[l*4+3];
  }
  if (l + 64 < 77){
    float p = e1 * inv;
    int k = l + 64;
    a0 += p*tp[k*4]; a1 += p*tp[k*4+1]; a2 += p*tp[k*4+2]; a3 += p*tp[k*4+3];
  }
  #pragma unroll
  for (int off = 32; off > 0; off >>= 1){
    a0 += __shfl_xor(a0, off); a1 += __shfl_xor(a1, off);
    a2 += __shfl_xor(a2, off); a3 += __shfl_xor(a3, off);
  }
  if (l == 0){
    f32x4 o = {a0, a1, a2, a3};
    *reinterpret_cast<f32x4*>(&sem[(size_t)row*4]) = o;
  }
}

// ---------------- MFMA fused text+ip attention ----------------
__global__ __launch_bounds__(256) void attn_mfma_k(
    const ushort* __restrict__ qb, const ushort* __restrict__ pall,
    const float* __restrict__ sem, const float* __restrict__ mask,
    ushort* __restrict__ hmid)
{
  int qt = blockIdx.x;   // 0..63
  int h  = blockIdx.y;   // 0..19
  int b  = blockIdx.z;   // 0..3
  __shared__ ushort Qs[64][72];
  __shared__ ushort Ks[96][72];
  __shared__ ushort Vt[64][104];  // V^T: [d][k]
  __shared__ ushort Ps[64][104];
  int t = threadIdx.x;
  int w = t >> 6, l = t & 63;
  const ushort* pb = pall + (size_t)b*81*5120 + h*64;

  {
    int base = b*4096 + qt*64;
    #pragma unroll
    for (int it = 0; it < 2; ++it){
      int chunk = t + it*256;
      int r = chunk >> 3, dp = (chunk & 7) << 3;
      uint4 v = *reinterpret_cast<const uint4*>(qb + (size_t)(base + r)*1280 + h*64 + dp);
      *reinterpret_cast<uint4*>(&Qs[r][dp]) = v;
    }
  }
  #pragma unroll
  for (int it = 0; it < 6; ++it){
    int chunk = t + it*256;
    int k = chunk >> 4, dp = (chunk & 15) << 2;
    ushort4 v = make_ushort4(0,0,0,0);
    if (k < 77)      v = *reinterpret_cast<const ushort4*>(pb + (size_t)k*5120 + dp);
    else if (k < 81) v = *reinterpret_cast<const ushort4*>(pb + (size_t)k*5120 + 2560 + dp);
    *reinterpret_cast<ushort4*>(&Ks[k][dp]) = v;
  }
  #pragma unroll
  for (int it = 0; it < 24; ++it){
    int idx = t + it*256;
    int k = idx >> 6, d = idx & 63;
    ushort v = 0;
    if (k < 77)      v = pb[(size_t)k*5120 + 1280 + d];
    else if (k < 81) v = pb[(size_t)k*5120 + 3840 + d];
    Vt[d][k] = v;
  }
  __syncthreads();

  int fr = l & 15, fq = l >> 4, fkb = fq << 3;
  int c = fr;

  f32x4 s[6];
  #pragma unroll
  for (int n = 0; n < 6; ++n) s[n] = (f32x4){0.f,0.f,0.f,0.f};
  #pragma unroll
  for (int ks = 0; ks < 2; ++ks){
    bf16x8 aq = *reinterpret_cast<const bf16x8*>(&Qs[w*16 + fr][ks*32 + fkb]);
    #pragma unroll
    for (int n = 0; n < 6; ++n){
      bf16x8 bk = *reinterpret_cast<const bf16x8*>(&Ks[n*16 + fr][ks*32 + fkb]);
      s[n] = __builtin_amdgcn_mfma_f32_16x16x32_bf16(aq, bk, s[n], 0, 0, 0);
    }
  }

  int rowbase = qt*64 + w*16 + (fq << 2);
  #pragma unroll
  for (int r = 0; r < 4; ++r){
    float lg[6];
    #pragma unroll
    for (int n = 0; n < 6; ++n) lg[n] = s[n][r]*0.125f;

    float mt = fmaxf(fmaxf(lg[0],lg[1]), fmaxf(lg[2],lg[3]));
    if (c < 13) mt = fmaxf(mt, lg[4]);
    #pragma unroll
    for (int off = 1; off < 16; off <<= 1) mt = fmaxf(mt, __shfl_xor(mt, off));
    float st = __expf(lg[0]-mt) + __expf(lg[1]-mt) + __expf(lg[2]-mt) + __expf(lg[3]-mt);
    if (c < 13) st += __expf(lg[4]-mt);
    #pragma unroll
    for (int off = 1; off < 16; off <<= 1) st += __shfl_xor(st, off);
    float invst = 1.f/st;

    size_t qrow = (size_t)b*4096 + rowbase + r;
    float f4 = -1e30f, f5 = -1e30f;
    if (c >= 13) f4 = lg[4] + 0.5f*sem[qrow*4 + (c-13)];
    if (c == 0)  f5 = lg[5] + 0.5f*sem[qrow*4 + 3];
    float m2 = fmaxf(f4, f5);
    #pragma unroll
    for (int off = 1; off < 16; off <<= 1) m2 = fmaxf(m2, __shfl_xor(m2, off));
    float si = (c >= 13 ? __expf(f4-m2) : 0.f) + (c == 0 ? __expf(f5-m2) : 0.f);
    #pragma unroll
    for (int off = 1; off < 16; off <<= 1) si += __shfl_xor(si, off);
    float pmul = mask[rowbase + r] / si;

    int prow = w*16 + (fq << 2) + r;
    #pragma unroll
    for (int n = 0; n < 4; ++n) Ps[prow][n*16 + c] = f2b(__expf(lg[n]-mt)*invst);
    Ps[prow][64 + c] = f2b(c < 13 ? __expf(lg[4]-mt)*invst : __expf(f4-m2)*pmul);
    Ps[prow][80 + c] = f2b(c == 0 ? __expf(f5-m2)*pmul : 0.f);
  }
  __syncthreads();

  f32x4 o[4];
  #pragma unroll
  for (int df = 0; df < 4; ++df) o[df] = (f32x4){0.f,0.f,0.f,0.f};
  #pragma unroll
  for (int ks = 0; ks < 3; ++ks){
    bf16x8 ap = *reinterpret_cast<const bf16x8*>(&Ps[w*16 + fr][ks*32 + fkb]);
    #pragma unroll
    for (int df = 0; df < 4; ++df){
      bf16x8 bv = *reinterpret_cast<const bf16x8*>(&Vt[df*16 + fr][ks*32 + fkb]);
      o[df] = __builtin_amdgcn_mfma_f32_16x16x32_bf16(ap, bv, o[df], 0, 0, 0);
    }
  }
  #pragma unroll
  for (int df = 0; df < 4; ++df)
    #pragma unroll
    for (int r = 0; r < 4; ++r)
      hmid[((size_t)b*4096 + rowbase + r)*1280 + h*64 + df*16 + c] = f2b(o[df][r]);
}

extern "C" void kernel_launch(void* const* d_in, const int* in_sizes, int n_in,
                              void* d_out, int out_size, void* d_ws, size_t ws_size,
                              hipStream_t stream)
{
  (void)in_sizes; (void)n_in; (void)out_size; (void)ws_size;
  const float* hs   = (const float*)d_in[0];
  const float* enc  = (const float*)d_in[1];
  const float* mask = (const float*)d_in[2];
  const float* Wq   = (const float*)d_in[3];
  const float* Wk   = (const float*)d_in[4];
  const float* Wv   = (const float*)d_in[5];
  const float* Wkip = (const float*)d_in[6];
  const float* Wvip = (const float*)d_in[7];
  const float* Wout = (const float*)d_in[8];
  const float* bout = (const float*)d_in[9];
  float* out = (float*)d_out;
  char* ws = (char*)d_ws;

  size_t off = 0;
  auto alloc = [&](size_t bytes)->char*{
    char* p = ws + off; off += (bytes + 255) & ~(size_t)255; return p;
  };
  ushort* hs_bf   = (ushort*)alloc(16384ull*1280*2);   // reused as hmid
  ushort* q_bf    = (ushort*)alloc(16384ull*1280*2);
  ushort* enc_bf  = (ushort*)alloc(384ull*2048*2);
  ushort* wqt     = (ushort*)alloc(1280ull*1280*2);
  ushort* woutt   = (ushort*)alloc(1280ull*1280*2);
  ushort* wcat    = (ushort*)alloc(5120ull*2048*2);
  ushort* pall    = (ushort*)alloc(384ull*5120*2);
  float*  logits  = (float*)alloc(16384ull*128*4);
  float*  tip     = (float*)alloc(4ull*77*4*4);
  float*  semb    = (float*)alloc(16384ull*4*4);
  ushort* hmid_bf = hs_bf;

  cvt_bf16_k<<<20480, 256, 0, stream>>>(hs, hs_bf, 16384*1280/4);
  cvt_enc_k<<<768, 256, 0, stream>>>(enc, enc_bf);
  transpose_bf16_k<<<dim3(40,40), 256, 0, stream>>>(Wq,   wqt,   1280, 1280);
  transpose_bf16_k<<<dim3(40,40), 256, 0, stream>>>(Wout, woutt, 1280, 1280);
  transpose_bf16_k<<<dim3(40,64), 256, 0, stream>>>(Wk,   wcat + 0ull*1280*2048, 2048, 1280);
  transpose_bf16_k<<<dim3(40,64), 256, 0, stream>>>(Wv,   wcat + 1ull*1280*2048, 2048, 1280);
  transpose_bf16_k<<<dim3(40,64), 256, 0, stream>>>(Wkip, wcat + 2ull*1280*2048, 2048, 1280);
  transpose_bf16_k<<<dim3(40,64), 256, 0, stream>>>(Wvip, wcat + 3ull*1280*2048, 2048, 1280);

  // encoder projections: pall[384][5120] = enc_bf @ wcat^T  (bf16 out)
  gemm128s<0><<<dim3((384/128)*(5120/128)), 256, 0, stream>>>(enc_bf, wcat, 384, 5120, 2048,
      2048, 2048, 5120, nullptr, pall, nullptr, nullptr);

  // q = hs @ Wq (bf16 out)
  gemm128s<0><<<dim3((16384/128)*(1280/128)), 256, 0, stream>>>(hs_bf, wqt, 16384, 1280, 1280,
      1280, 1280, 1280, nullptr, q_bf, nullptr, nullptr);

  tip_k<<<dim3(77,4,4), 64, 0, stream>>>(enc, tip);

  // logits[b][4096][128] = q @ k_text^T  (batched; N padded to 128)
  gemm64<<<dim3((4096/64)*(128/64),1,4), 256, 0, stream>>>(q_bf, pall, 4096, 128, 1280,
      1280, 5120, 128, 4096ll*1280, 81ll*5120, 4096ll*128, logits);

  semsm_k<<<4096, 256, 0, stream>>>(logits, tip, semb);

  attn_mfma_k<<<dim3(64,20,4), 256, 0, stream>>>(q_bf, pall, semb, mask, hmid_bf);

  // out = hmid @ Wout + bout + residual
  gemm128s<1><<<dim3((16384/128)*(1280/128)), 256, 0, stream>>>(hmid_bf, woutt, 16384, 1280, 1280,
      1280, 1280, 1280, out, nullptr, bout, hs);
}

// Round 7
// 368.056 us; speedup vs baseline: 1.1309x; 1.0541x over previous
//
#include <hip/hip_runtime.h>

typedef __bf16 bf16x8 __attribute__((ext_vector_type(8)));
typedef float f32x4 __attribute__((ext_vector_type(4)));

__device__ __forceinline__ ushort f2b(float f){
  union { float f; unsigned u; } v; v.f = f;
  unsigned r = v.u + 0x7FFFu + ((v.u >> 16) & 1u);
  return (ushort)(r >> 16);
}
__device__ __forceinline__ float b2f(ushort b){
  union { unsigned u; float f; } v; v.u = ((unsigned)b) << 16; return v.f;
}

__device__ __forceinline__ void gload16(const ushort* g, ushort* lds){
  __builtin_amdgcn_global_load_lds(
      (const __attribute__((address_space(1))) unsigned int*)(g),
      (__attribute__((address_space(3))) unsigned int*)(lds), 16, 0, 0);
}

#define VMW(n)  do { asm volatile("s_waitcnt vmcnt(" #n ")" ::: "memory"); __builtin_amdgcn_sched_barrier(0); } while(0)
#define BARR    do { __builtin_amdgcn_s_barrier(); __builtin_amdgcn_sched_barrier(0); } while(0)

// ---------------- converts ----------------
__global__ __launch_bounds__(256) void cvt_bf16_k(const float* __restrict__ in,
                                                  ushort* __restrict__ out, int n4){
  int i = blockIdx.x*256 + threadIdx.x;
  if (i < n4){
    f32x4 v = reinterpret_cast<const f32x4*>(in)[i];
    ushort4 o = make_ushort4(f2b(v.x), f2b(v.y), f2b(v.z), f2b(v.w));
    reinterpret_cast<ushort4*>(out)[i] = o;
  }
}

__global__ __launch_bounds__(256) void cvt_enc_k(const float* __restrict__ in,
                                                 ushort* __restrict__ out){
  int i = blockIdx.x*256 + threadIdx.x;
  if (i < 384*2048/4){
    f32x4 v = {0.f,0.f,0.f,0.f};
    if (i < 324*2048/4) v = reinterpret_cast<const f32x4*>(in)[i];
    ushort4 o = make_ushort4(f2b(v.x), f2b(v.y), f2b(v.z), f2b(v.w));
    reinterpret_cast<ushort4*>(out)[i] = o;
  }
}

// W[K][N] fp32 -> Wt[N][K] bf16
__global__ __launch_bounds__(256) void transpose_bf16_k(const float* __restrict__ W,
                                                        ushort* __restrict__ Wt, int K, int N){
  __shared__ float tile[32][33];
  int n0 = blockIdx.x*32, k0 = blockIdx.y*32;
  int tx = threadIdx.x & 31, ty = threadIdx.x >> 5;
  for (int i = ty; i < 32; i += 8) tile[i][tx] = W[(size_t)(k0+i)*N + n0+tx];
  __syncthreads();
  for (int i = ty; i < 32; i += 8) Wt[(size_t)(n0+i)*K + k0+tx] = f2b(tile[tx][i]);
}

// ------- 128x128 GEMM, BK=32, 3-buffer counted-vmcnt pipeline (T4 idiom) -------
// 256 thr / 4 waves (2x2). Per K-step: VMW(4); s_barrier; stage(kt+2); ds_read; 16 MFMA/wave.
// Loads stay in flight across barriers (never drain until last tile). LDS 48KB -> 3 blocks/CU.
// LDS slot swizzle (2-way max, free per m136): slot ^= (row>>1)&3, applied on pre-swizzled
// global source (gload_lds dest linear, rule #21) and on ds_read address.
// MODE 0: bf16 store; MODE 1: fp32 + bias[col] + resid.
template<int MODE>
__global__ __launch_bounds__(256) void gemm128p(
    const ushort* __restrict__ A, const ushort* __restrict__ Bt,
    int M, int N, int K, int lda, int ldb, int ldo,
    float* __restrict__ outF, ushort* __restrict__ outB,
    const float* __restrict__ bias, const float* __restrict__ resid)
{
  __shared__ ushort As[3][128*32];
  __shared__ ushort Bs[3][128*32];
  int ntiles = N >> 7;
  int nwg = gridDim.x;
  int bid = blockIdx.x;
  if ((nwg & 7) == 0){
    int cpx = nwg >> 3;
    bid = (bid & 7)*cpx + (bid >> 3);
  }
  int mt = bid / ntiles;
  int nt = bid - mt*ntiles;
  int t = threadIdx.x;
  int w = t >> 6, l = t & 63;
  int wr = w >> 1, wc = w & 1;
  int fr = l & 15, fq = l >> 4;

  // staging: 512 chunks of 16B per matrix per K-step; thread t -> chunks t, t+256.
  // chunk c: row=c>>2, slot=c&3; LDS dest linear; global col pre-swizzled.
  int r0 = t >> 2, s0 = t & 3;
  int r1 = r0 + 64;
  int sc0 = ((s0 ^ ((r0 >> 1) & 3)) << 3);
  int sc1 = ((s0 ^ ((r1 >> 1) & 3)) << 3);
  const ushort* Ag0 = A  + (size_t)(mt*128 + r0)*lda + sc0;
  const ushort* Ag1 = A  + (size_t)(mt*128 + r1)*lda + sc1;
  const ushort* Bg0 = Bt + (size_t)(nt*128 + r0)*ldb + sc0;
  const ushort* Bg1 = Bt + (size_t)(nt*128 + r1)*ldb + sc1;

  f32x4 acc[4][4];
  #pragma unroll
  for (int m = 0; m < 4; ++m)
    #pragma unroll
    for (int n = 0; n < 4; ++n) acc[m][n] = (f32x4){0.f,0.f,0.f,0.f};

  auto stage = [&](int s, int kt){
    int ko = kt << 5;
    ushort* a = &As[s][0] + t*8;
    ushort* b = &Bs[s][0] + t*8;
    gload16(Ag0 + ko, a);
    gload16(Ag1 + ko, a + 2048);
    gload16(Bg0 + ko, b);
    gload16(Bg1 + ko, b + 2048);
  };
  auto compute = [&](int s){
    const ushort* Ab = &As[s][0];
    const ushort* Bb = &Bs[s][0];
    bf16x8 af[4], bf[4];
    #pragma unroll
    for (int m = 0; m < 4; ++m){
      int row = wr*64 + m*16 + fr;
      af[m] = *reinterpret_cast<const bf16x8*>(&Ab[row*32 + ((fq ^ ((row >> 1) & 3)) << 3)]);
    }
    #pragma unroll
    for (int n = 0; n < 4; ++n){
      int row = wc*64 + n*16 + fr;
      bf[n] = *reinterpret_cast<const bf16x8*>(&Bb[row*32 + ((fq ^ ((row >> 1) & 3)) << 3)]);
    }
    #pragma unroll
    for (int m = 0; m < 4; ++m)
      #pragma unroll
      for (int n = 0; n < 4; ++n)
        acc[m][n] = __builtin_amdgcn_mfma_f32_16x16x32_bf16(af[m], bf[n], acc[m][n], 0, 0, 0);
  };

  int nk = K >> 5;   // nk >= 2
  stage(0, 0);
  stage(1, 1);
  int kt = 0;
  for (; kt < nk - 1; ++kt){
    VMW(4);                 // tile kt landed (only stage(kt+1) may be in flight)
    BARR;
    if (kt + 2 < nk) stage((kt + 2) % 3, kt + 2);
    compute(kt % 3);
  }
  VMW(0);
  BARR;
  compute(kt % 3);

  int fqb = fq << 2;
  #pragma unroll
  for (int m = 0; m < 4; ++m){
    #pragma unroll
    for (int n = 0; n < 4; ++n){
      #pragma unroll
      for (int r = 0; r < 4; ++r){
        int row = mt*128 + wr*64 + m*16 + fqb + r;
        int col = nt*128 + wc*64 + n*16 + fr;
        size_t oidx = (size_t)row*ldo + col;
        float v = acc[m][n][r];
        if (MODE == 0) outB[oidx] = f2b(v);
        else           outF[oidx] = v + bias[col] + resid[oidx];
      }
    }
  }
}

// ---------------- 64x64 GEMM (batched, for logits) ----------------
__global__ __launch_bounds__(256) void gemm64(
    const ushort* __restrict__ A, const ushort* __restrict__ Bt,
    int M, int N, int K, int lda, int ldb, int ldo,
    long long sA, long long sB, long long sO, float* __restrict__ outF)
{
  __shared__ ushort As[64][40];
  __shared__ ushort Bs[64][40];
  int ntiles = N >> 6;
  int mt = blockIdx.x / ntiles;
  int nt = blockIdx.x - mt*ntiles;
  int z  = blockIdx.z;
  const ushort* Ab = A + (size_t)z*sA;
  const ushort* Bb = Bt + (size_t)z*sB;
  int t = threadIdx.x;
  int w = t >> 6, l = t & 63;
  int lr = t >> 2, lc = (t & 3) << 3;
  int fr = l & 15, fk = (l >> 4) << 3;
  f32x4 acc[4];
  #pragma unroll
  for (int n = 0; n < 4; ++n) acc[n] = (f32x4){0.f,0.f,0.f,0.f};

  const ushort* Aptr = Ab + (size_t)(mt*64 + lr)*lda + lc;
  const ushort* Bptr = Bb + (size_t)(nt*64 + lr)*ldb + lc;
  for (int k0 = 0; k0 < K; k0 += 32){
    uint4 av = *reinterpret_cast<const uint4*>(Aptr + k0);
    uint4 bv = *reinterpret_cast<const uint4*>(Bptr + k0);
    __syncthreads();
    *reinterpret_cast<uint4*>(&As[lr][lc]) = av;
    *reinterpret_cast<uint4*>(&Bs[lr][lc]) = bv;
    __syncthreads();
    bf16x8 af = *reinterpret_cast<const bf16x8*>(&As[w*16 + fr][fk]);
    #pragma unroll
    for (int n = 0; n < 4; ++n){
      bf16x8 bf = *reinterpret_cast<const bf16x8*>(&Bs[n*16 + fr][fk]);
      acc[n] = __builtin_amdgcn_mfma_f32_16x16x32_bf16(af, bf, acc[n], 0, 0, 0);
    }
  }
  int fq = l >> 4;
  #pragma unroll
  for (int n = 0; n < 4; ++n){
    #pragma unroll
    for (int r = 0; r < 4; ++r){
      int row = mt*64 + w*16 + fq*4 + r;
      int col = nt*64 + n*16 + fr;
      outF[(size_t)z*sO + (size_t)row*ldo + col] = acc[n][r];
    }
  }
}

// ---------------- T_ip[b][k][n] = 0.125 * sum_c text[b,k,c]*ip[b,n,c] ----------------
__global__ __launch_bounds__(64) void tip_k(const float* __restrict__ enc, float* __restrict__ tip){
  int k = blockIdx.x, n = blockIdx.y, b = blockIdx.z;
  const float* text = enc + ((size_t)b*81 + k)*2048;
  const float* ip   = enc + ((size_t)b*81 + 77 + n)*2048;
  int l = threadIdx.x;
  float acc = 0.f;
  for (int c = l; c < 2048; c += 64) acc += text[c]*ip[c];
  for (int off = 32; off > 0; off >>= 1) acc += __shfl_down(acc, off);
  if (l == 0) tip[((size_t)b*77 + k)*4 + n] = acc * 0.125f;
}

// ---------------- softmax over 77 logits + sem = p @ T_ip (wave per row) ----------------
__global__ __launch_bounds__(256) void semsm_k(const float* __restrict__ logits,
    const float* __restrict__ tip, float* __restrict__ sem)
{
  int w = threadIdx.x >> 6, l = threadIdx.x & 63;
  int row = blockIdx.x*4 + w;            // 0..16383
  int b = row >> 12;
  const float* lp = logits + (size_t)row*128;
  float v0 = (l < 77)      ? lp[l]      * 0.125f : -1e30f;
  float v1 = (l + 64 < 77) ? lp[l + 64] * 0.125f : -1e30f;
  float m = fmaxf(v0, v1);
  #pragma unroll
  for (int off = 32; off > 0; off >>= 1) m = fmaxf(m, __shfl_xor(m, off));
  float e0 = (l < 77)      ? __expf(v0 - m) : 0.f;
  float e1 = (l + 64 < 77) ? __expf(v1 - m) : 0.f;
  float s = e0 + e1;
  #pragma unroll
  for (int off = 32; off > 0; off >>= 1) s += __shfl_xor(s, off);
  float inv = 1.f / s;
  const float* tp = tip + (size_t)b*77*4;
  float a0 = 0.f, a1 = 0.f, a2 = 0.f, a3 = 0.f;
  if (l < 77){
    float p = e0 * inv;
    a0 = p*tp[l*4]; a1 = p*tp[l*4+1]; a2 = p*tp[l*4+2]; a3 = p*tp[l*4+3];
  }
  if (l + 64 < 77){
    float p = e1 * inv;
    int k = l + 64;
    a0 += p*tp[k*4]; a1 += p*tp[k*4+1]; a2 += p*tp[k*4+2]; a3 += p*tp[k*4+3];
  }
  #pragma unroll
  for (int off = 32; off > 0; off >>= 1){
    a0 += __shfl_xor(a0, off); a1 += __shfl_xor(a1, off);
    a2 += __shfl_xor(a2, off); a3 += __shfl_xor(a3, off);
  }
  if (l == 0){
    f32x4 o = {a0, a1, a2, a3};
    *reinterpret_cast<f32x4*>(&sem[(size_t)row*4]) = o;
  }
}

// ---------------- MFMA fused text+ip attention ----------------
__global__ __launch_bounds__(256) void attn_mfma_k(
    const ushort* __restrict__ qb, const ushort* __restrict__ pall,
    const float* __restrict__ sem, const float* __restrict__ mask,
    ushort* __restrict__ hmid)
{
  int qt = blockIdx.x;   // 0..63
  int h  = blockIdx.y;   // 0..19
  int b  = blockIdx.z;   // 0..3
  __shared__ ushort Qs[64][72];
  __shared__ ushort Ks[96][72];
  __shared__ ushort Vt[64][104];  // V^T: [d][k]
  __shared__ ushort Ps[64][104];
  int t = threadIdx.x;
  int w = t >> 6, l = t & 63;
  const ushort* pb = pall + (size_t)b*81*5120 + h*64;

  {
    int base = b*4096 + qt*64;
    #pragma unroll
    for (int it = 0; it < 2; ++it){
      int chunk = t + it*256;
      int r = chunk >> 3, dp = (chunk & 7) << 3;
      uint4 v = *reinterpret_cast<const uint4*>(qb + (size_t)(base + r)*1280 + h*64 + dp);
      *reinterpret_cast<uint4*>(&Qs[r][dp]) = v;
    }
  }
  #pragma unroll
  for (int it = 0; it < 6; ++it){
    int chunk = t + it*256;
    int k = chunk >> 4, dp = (chunk & 15) << 2;
    ushort4 v = make_ushort4(0,0,0,0);
    if (k < 77)      v = *reinterpret_cast<const ushort4*>(pb + (size_t)k*5120 + dp);
    else if (k < 81) v = *reinterpret_cast<const ushort4*>(pb + (size_t)k*5120 + 2560 + dp);
    *reinterpret_cast<ushort4*>(&Ks[k][dp]) = v;
  }
  #pragma unroll
  for (int it = 0; it < 24; ++it){
    int idx = t + it*256;
    int k = idx >> 6, d = idx & 63;
    ushort v = 0;
    if (k < 77)      v = pb[(size_t)k*5120 + 1280 + d];
    else if (k < 81) v = pb[(size_t)k*5120 + 3840 + d];
    Vt[d][k] = v;
  }
  __syncthreads();

  int fr = l & 15, fq = l >> 4, fkb = fq << 3;
  int c = fr;

  f32x4 s[6];
  #pragma unroll
  for (int n = 0; n < 6; ++n) s[n] = (f32x4){0.f,0.f,0.f,0.f};
  #pragma unroll
  for (int ks = 0; ks < 2; ++ks){
    bf16x8 aq = *reinterpret_cast<const bf16x8*>(&Qs[w*16 + fr][ks*32 + fkb]);
    #pragma unroll
    for (int n = 0; n < 6; ++n){
      bf16x8 bk = *reinterpret_cast<const bf16x8*>(&Ks[n*16 + fr][ks*32 + fkb]);
      s[n] = __builtin_amdgcn_mfma_f32_16x16x32_bf16(aq, bk, s[n], 0, 0, 0);
    }
  }

  int rowbase = qt*64 + w*16 + (fq << 2);
  #pragma unroll
  for (int r = 0; r < 4; ++r){
    float lg[6];
    #pragma unroll
    for (int n = 0; n < 6; ++n) lg[n] = s[n][r]*0.125f;

    float mt = fmaxf(fmaxf(lg[0],lg[1]), fmaxf(lg[2],lg[3]));
    if (c < 13) mt = fmaxf(mt, lg[4]);
    #pragma unroll
    for (int off = 1; off < 16; off <<= 1) mt = fmaxf(mt, __shfl_xor(mt, off));
    float st = __expf(lg[0]-mt) + __expf(lg[1]-mt) + __expf(lg[2]-mt) + __expf(lg[3]-mt);
    if (c < 13) st += __expf(lg[4]-mt);
    #pragma unroll
    for (int off = 1; off < 16; off <<= 1) st += __shfl_xor(st, off);
    float invst = 1.f/st;

    size_t qrow = (size_t)b*4096 + rowbase + r;
    float f4 = -1e30f, f5 = -1e30f;
    if (c >= 13) f4 = lg[4] + 0.5f*sem[qrow*4 + (c-13)];
    if (c == 0)  f5 = lg[5] + 0.5f*sem[qrow*4 + 3];
    float m2 = fmaxf(f4, f5);
    #pragma unroll
    for (int off = 1; off < 16; off <<= 1) m2 = fmaxf(m2, __shfl_xor(m2, off));
    float si = (c >= 13 ? __expf(f4-m2) : 0.f) + (c == 0 ? __expf(f5-m2) : 0.f);
    #pragma unroll
    for (int off = 1; off < 16; off <<= 1) si += __shfl_xor(si, off);
    float pmul = mask[rowbase + r] / si;

    int prow = w*16 + (fq << 2) + r;
    #pragma unroll
    for (int n = 0; n < 4; ++n) Ps[prow][n*16 + c] = f2b(__expf(lg[n]-mt)*invst);
    Ps[prow][64 + c] = f2b(c < 13 ? __expf(lg[4]-mt)*invst : __expf(f4-m2)*pmul);
    Ps[prow][80 + c] = f2b(c == 0 ? __expf(f5-m2)*pmul : 0.f);
  }
  __syncthreads();

  f32x4 o[4];
  #pragma unroll
  for (int df = 0; df < 4; ++df) o[df] = (f32x4){0.f,0.f,0.f,0.f};
  #pragma unroll
  for (int ks = 0; ks < 3; ++ks){
    bf16x8 ap = *reinterpret_cast<const bf16x8*>(&Ps[w*16 + fr][ks*32 + fkb]);
    #pragma unroll
    for (int df = 0; df < 4; ++df){
      bf16x8 bv = *reinterpret_cast<const bf16x8*>(&Vt[df*16 + fr][ks*32 + fkb]);
      o[df] = __builtin_amdgcn_mfma_f32_16x16x32_bf16(ap, bv, o[df], 0, 0, 0);
    }
  }
  #pragma unroll
  for (int df = 0; df < 4; ++df)
    #pragma unroll
    for (int r = 0; r < 4; ++r)
      hmid[((size_t)b*4096 + rowbase + r)*1280 + h*64 + df*16 + c] = f2b(o[df][r]);
}

extern "C" void kernel_launch(void* const* d_in, const int* in_sizes, int n_in,
                              void* d_out, int out_size, void* d_ws, size_t ws_size,
                              hipStream_t stream)
{
  (void)in_sizes; (void)n_in; (void)out_size; (void)ws_size;
  const float* hs   = (const float*)d_in[0];
  const float* enc  = (const float*)d_in[1];
  const float* mask = (const float*)d_in[2];
  const float* Wq   = (const float*)d_in[3];
  const float* Wk   = (const float*)d_in[4];
  const float* Wv   = (const float*)d_in[5];
  const float* Wkip = (const float*)d_in[6];
  const float* Wvip = (const float*)d_in[7];
  const float* Wout = (const float*)d_in[8];
  const float* bout = (const float*)d_in[9];
  float* out = (float*)d_out;
  char* ws = (char*)d_ws;

  size_t off = 0;
  auto alloc = [&](size_t bytes)->char*{
    char* p = ws + off; off += (bytes + 255) & ~(size_t)255; return p;
  };
  ushort* hs_bf   = (ushort*)alloc(16384ull*1280*2);   // reused as hmid
  ushort* q_bf    = (ushort*)alloc(16384ull*1280*2);
  ushort* enc_bf  = (ushort*)alloc(384ull*2048*2);
  ushort* wqt     = (ushort*)alloc(1280ull*1280*2);
  ushort* woutt   = (ushort*)alloc(1280ull*1280*2);
  ushort* wcat    = (ushort*)alloc(5120ull*2048*2);
  ushort* pall    = (ushort*)alloc(384ull*5120*2);
  float*  logits  = (float*)alloc(16384ull*128*4);
  float*  tip     = (float*)alloc(4ull*77*4*4);
  float*  semb    = (float*)alloc(16384ull*4*4);
  ushort* hmid_bf = hs_bf;

  cvt_bf16_k<<<20480, 256, 0, stream>>>(hs, hs_bf, 16384*1280/4);
  cvt_enc_k<<<768, 256, 0, stream>>>(enc, enc_bf);
  transpose_bf16_k<<<dim3(40,40), 256, 0, stream>>>(Wq,   wqt,   1280, 1280);
  transpose_bf16_k<<<dim3(40,40), 256, 0, stream>>>(Wout, woutt, 1280, 1280);
  transpose_bf16_k<<<dim3(40,64), 256, 0, stream>>>(Wk,   wcat + 0ull*1280*2048, 2048, 1280);
  transpose_bf16_k<<<dim3(40,64), 256, 0, stream>>>(Wv,   wcat + 1ull*1280*2048, 2048, 1280);
  transpose_bf16_k<<<dim3(40,64), 256, 0, stream>>>(Wkip, wcat + 2ull*1280*2048, 2048, 1280);
  transpose_bf16_k<<<dim3(40,64), 256, 0, stream>>>(Wvip, wcat + 3ull*1280*2048, 2048, 1280);

  // encoder projections: pall[384][5120] = enc_bf @ wcat^T  (bf16 out)
  gemm128p<0><<<dim3((384/128)*(5120/128)), 256, 0, stream>>>(enc_bf, wcat, 384, 5120, 2048,
      2048, 2048, 5120, nullptr, pall, nullptr, nullptr);

  // q = hs @ Wq (bf16 out)
  gemm128p<0><<<dim3((16384/128)*(1280/128)), 256, 0, stream>>>(hs_bf, wqt, 16384, 1280, 1280,
      1280, 1280, 1280, nullptr, q_bf, nullptr, nullptr);

  tip_k<<<dim3(77,4,4), 64, 0, stream>>>(enc, tip);

  // logits[b][4096][128] = q @ k_text^T  (batched; N padded to 128)
  gemm64<<<dim3((4096/64)*(128/64),1,4), 256, 0, stream>>>(q_bf, pall, 4096, 128, 1280,
      1280, 5120, 128, 4096ll*1280, 81ll*5120, 4096ll*128, logits);

  semsm_k<<<4096, 256, 0, stream>>>(logits, tip, semb);

  attn_mfma_k<<<dim3(64,20,4), 256, 0, stream>>>(q_bf, pall, semb, mask, hmid_bf);

  // out = hmid @ Wout + bout + residual
  gemm128p<1><<<dim3((16384/128)*(1280/128)), 256, 0, stream>>>(hmid_bf, woutt, 16384, 1280, 1280,
      1280, 1280, 1280, out, nullptr, bout, hs);
}

// Round 9
// 353.350 us; speedup vs baseline: 1.1780x; 1.0416x over previous
//
#include <hip/hip_runtime.h>

typedef __bf16 bf16x8 __attribute__((ext_vector_type(8)));
typedef float f32x4 __attribute__((ext_vector_type(4)));

__device__ __forceinline__ ushort f2b(float f){
  union { float f; unsigned u; } v; v.f = f;
  unsigned r = v.u + 0x7FFFu + ((v.u >> 16) & 1u);
  return (ushort)(r >> 16);
}
__device__ __forceinline__ float b2f(ushort b){
  union { unsigned u; float f; } v; v.u = ((unsigned)b) << 16; return v.f;
}

__device__ __forceinline__ void gload16(const ushort* g, ushort* lds){
  __builtin_amdgcn_global_load_lds(
      (const __attribute__((address_space(1))) unsigned int*)(g),
      (__attribute__((address_space(3))) unsigned int*)(lds), 16, 0, 0);
}

#define VMW(n)  do { asm volatile("s_waitcnt vmcnt(" #n ")" ::: "memory"); __builtin_amdgcn_sched_barrier(0); } while(0)
#define BARR    do { __builtin_amdgcn_s_barrier(); __builtin_amdgcn_sched_barrier(0); } while(0)

// ============ prep mega-kernel: hs cvt | enc cvt | 6 weight transposes | T_ip ============
__global__ __launch_bounds__(256) void prep_k(
    const float* __restrict__ hs, const float* __restrict__ enc,
    const float* __restrict__ Wq, const float* __restrict__ Wout,
    const float* __restrict__ Wk, const float* __restrict__ Wv,
    const float* __restrict__ Wkip, const float* __restrict__ Wvip,
    ushort* __restrict__ hs_bf, ushort* __restrict__ enc_bf,
    ushort* __restrict__ wqt, ushort* __restrict__ woutt, ushort* __restrict__ wcat,
    float* __restrict__ tip)
{
  __shared__ float tile[32][33];
  int bid = blockIdx.x;
  int t = threadIdx.x;

  if (bid < 20480){                       // hs f32 -> bf16
    int i = bid*256 + t;
    f32x4 v = reinterpret_cast<const f32x4*>(hs)[i];
    ushort4 o = make_ushort4(f2b(v.x), f2b(v.y), f2b(v.z), f2b(v.w));
    reinterpret_cast<ushort4*>(hs_bf)[i] = o;
    return;
  }
  bid -= 20480;
  if (bid < 768){                         // enc f32 -> bf16 (pad to 384 rows)
    int i = bid*256 + t;
    f32x4 v = {0.f,0.f,0.f,0.f};
    if (i < 324*2048/4) v = reinterpret_cast<const f32x4*>(enc)[i];
    ushort4 o = make_ushort4(f2b(v.x), f2b(v.y), f2b(v.z), f2b(v.w));
    reinterpret_cast<ushort4*>(enc_bf)[i] = o;
    return;
  }
  bid -= 768;
  if (bid < 13440){                       // weight transposes
    const float* Wsrc; ushort* Wdst; int K;
    if (bid < 1600)      { Wsrc = Wq;   Wdst = wqt;                    K = 1280; }
    else if (bid < 3200) { bid -= 1600; Wsrc = Wout; Wdst = woutt;     K = 1280; }
    else if (bid < 5760) { bid -= 3200; Wsrc = Wk;   Wdst = wcat;      K = 2048; }
    else if (bid < 8320) { bid -= 5760; Wsrc = Wv;   Wdst = wcat + 1ull*1280*2048; K = 2048; }
    else if (bid < 10880){ bid -= 8320; Wsrc = Wkip; Wdst = wcat + 2ull*1280*2048; K = 2048; }
    else                 { bid -= 10880; Wsrc = Wvip; Wdst = wcat + 3ull*1280*2048; K = 2048; }
    int n0 = (bid % 40)*32, k0 = (bid / 40)*32;
    int tx = t & 31, ty = t >> 5;
    for (int i = ty; i < 32; i += 8) tile[i][tx] = Wsrc[(size_t)(k0+i)*1280 + n0+tx];
    __syncthreads();
    for (int i = ty; i < 32; i += 8) Wdst[(size_t)(n0+i)*K + k0+tx] = f2b(tile[tx][i]);
    return;
  }
  bid -= 13440;
  {                                       // tip[b][k][n] = 0.125 * text[b,k]·ip[b,n]
    int b = bid / 77, k = bid % 77;
    int n = t >> 6, l = t & 63;
    const float* text = enc + ((size_t)b*81 + k)*2048;
    const float* ip   = enc + ((size_t)b*81 + 77 + n)*2048;
    float acc = 0.f;
    for (int c = l; c < 2048; c += 64) acc += text[c]*ip[c];
    #pragma unroll
    for (int off = 32; off > 0; off >>= 1) acc += __shfl_xor(acc, off);
    if (l == 0) tip[((size_t)b*77 + k)*4 + n] = acc * 0.125f;
  }
}

// ============ shared 128x128 GEMM body: BK=32, 3-buffer counted-vmcnt pipeline ============
template<int MODE>
__device__ __forceinline__ void gemm_body(
    ushort* As, ushort* Bs,
    const ushort* __restrict__ A, const ushort* __restrict__ Bt,
    int K, int lda, int ldb, int ldo,
    float* __restrict__ outF, ushort* __restrict__ outB,
    const float* __restrict__ bias, const float* __restrict__ resid,
    int mt, int nt)
{
  int t = threadIdx.x;
  int w = t >> 6, l = t & 63;
  int wr = w >> 1, wc = w & 1;
  int fr = l & 15, fq = l >> 4;

  int r0 = t >> 2, s0 = t & 3;
  int r1 = r0 + 64;
  int sc0 = ((s0 ^ ((r0 >> 1) & 3)) << 3);
  int sc1 = ((s0 ^ ((r1 >> 1) & 3)) << 3);
  const ushort* Ag0 = A  + (size_t)(mt*128 + r0)*lda + sc0;
  const ushort* Ag1 = A  + (size_t)(mt*128 + r1)*lda + sc1;
  const ushort* Bg0 = Bt + (size_t)(nt*128 + r0)*ldb + sc0;
  const ushort* Bg1 = Bt + (size_t)(nt*128 + r1)*ldb + sc1;

  f32x4 acc[4][4];
  #pragma unroll
  for (int m = 0; m < 4; ++m)
    #pragma unroll
    for (int n = 0; n < 4; ++n) acc[m][n] = (f32x4){0.f,0.f,0.f,0.f};

  auto stage = [&](int s, int kt){
    int ko = kt << 5;
    ushort* a = As + s*4096 + t*8;
    ushort* b = Bs + s*4096 + t*8;
    gload16(Ag0 + ko, a);
    gload16(Ag1 + ko, a + 2048);
    gload16(Bg0 + ko, b);
    gload16(Bg1 + ko, b + 2048);
  };
  auto compute = [&](int s){
    const ushort* Ab = As + s*4096;
    const ushort* Bb = Bs + s*4096;
    bf16x8 af[4], bf[4];
    #pragma unroll
    for (int m = 0; m < 4; ++m){
      int row = wr*64 + m*16 + fr;
      af[m] = *reinterpret_cast<const bf16x8*>(&Ab[row*32 + ((fq ^ ((row >> 1) & 3)) << 3)]);
    }
    #pragma unroll
    for (int n = 0; n < 4; ++n){
      int row = wc*64 + n*16 + fr;
      bf[n] = *reinterpret_cast<const bf16x8*>(&Bb[row*32 + ((fq ^ ((row >> 1) & 3)) << 3)]);
    }
    #pragma unroll
    for (int m = 0; m < 4; ++m)
      #pragma unroll
      for (int n = 0; n < 4; ++n)
        acc[m][n] = __builtin_amdgcn_mfma_f32_16x16x32_bf16(af[m], bf[n], acc[m][n], 0, 0, 0);
  };

  int nk = K >> 5;
  stage(0, 0);
  stage(1, 1);
  int kt = 0;
  for (; kt < nk - 1; ++kt){
    VMW(4);
    BARR;
    if (kt + 2 < nk) stage((kt + 2) % 3, kt + 2);
    compute(kt % 3);
  }
  VMW(0);
  BARR;
  compute(kt % 3);

  int fqb = fq << 2;
  #pragma unroll
  for (int m = 0; m < 4; ++m){
    #pragma unroll
    for (int n = 0; n < 4; ++n){
      #pragma unroll
      for (int r = 0; r < 4; ++r){
        int row = mt*128 + wr*64 + m*16 + fqb + r;
        int col = nt*128 + wc*64 + n*16 + fr;
        size_t oidx = (size_t)row*ldo + col;
        float v = acc[m][n][r];
        if (MODE == 0) outB[oidx] = f2b(v);
        else           outF[oidx] = v + bias[col] + resid[oidx];
      }
    }
  }
}

// q-proj (1280 blocks) + enc-proj (120 blocks) in one launch
__global__ __launch_bounds__(256) void gemm_dual_k(
    const ushort* __restrict__ A1, const ushort* __restrict__ B1, ushort* __restrict__ O1,
    const ushort* __restrict__ A2, const ushort* __restrict__ B2, ushort* __restrict__ O2)
{
  __shared__ ushort As[3*4096];
  __shared__ ushort Bs[3*4096];
  int nwg = gridDim.x;
  int bid = blockIdx.x;
  if ((nwg & 7) == 0){
    int cpx = nwg >> 3;
    bid = (bid & 7)*cpx + (bid >> 3);
  }
  if (bid < 1280){
    gemm_body<0>(As, Bs, A1, B1, 1280, 1280, 1280, 1280,
                 nullptr, O1, nullptr, nullptr, bid/10, bid%10);
  } else {
    int lb = bid - 1280;
    gemm_body<0>(As, Bs, A2, B2, 2048, 2048, 2048, 5120,
                 nullptr, O2, nullptr, nullptr, lb/40, lb%40);
  }
}

// out-proj: fp32 + bias + residual
__global__ __launch_bounds__(256) void gemm_out_k(
    const ushort* __restrict__ A, const ushort* __restrict__ Bt, float* __restrict__ outF,
    const float* __restrict__ bias, const float* __restrict__ resid)
{
  __shared__ ushort As[3*4096];
  __shared__ ushort Bs[3*4096];
  int nwg = gridDim.x;
  int bid = blockIdx.x;
  if ((nwg & 7) == 0){
    int cpx = nwg >> 3;
    bid = (bid & 7)*cpx + (bid >> 3);
  }
  gemm_body<1>(As, Bs, A, Bt, 1280, 1280, 1280, 1280,
               outF, nullptr, bias, resid, bid/10, bid%10);
}

// ============ fused logits + text-softmax + sem kernel ============
// block = (mt 0..63, z 0..3): 64 q-rows x 80 logit-cols (77 used), K=1280.
__global__ __launch_bounds__(256) void logits_sem_k(
    const ushort* __restrict__ q, const ushort* __restrict__ pall,
    const float* __restrict__ tip, float* __restrict__ sem)
{
  __shared__ ushort As[64][40];
  __shared__ ushort Bs[128][40];
  __shared__ float tipS[77][4];
  int mt = blockIdx.x;
  int z  = blockIdx.z;
  int t = threadIdx.x;
  const ushort* Ab = q + (size_t)z*4096*1280;
  const ushort* Bb = pall + (size_t)z*81*5120;
  for (int i = t; i < 308; i += 256) (&tipS[0][0])[i] = tip[(size_t)z*308 + i];

  int w = t >> 6, l = t & 63;
  int fr = l & 15, fq = l >> 4, fk = fq << 3;
  int alr = t >> 2, alc = (t & 3) << 3;

  const ushort* Aptr  = Ab + (size_t)(mt*64 + alr)*1280 + alc;
  const ushort* Bptr0 = Bb + (size_t)alr*5120 + alc;
  const ushort* Bptr1 = Bb + (size_t)(64 + alr)*5120 + alc;

  f32x4 acc[5];
  #pragma unroll
  for (int n = 0; n < 5; ++n) acc[n] = (f32x4){0.f,0.f,0.f,0.f};

  uint4 a0 = *reinterpret_cast<const uint4*>(Aptr);
  uint4 b0 = *reinterpret_cast<const uint4*>(Bptr0);
  uint4 b1 = *reinterpret_cast<const uint4*>(Bptr1);
  for (int k0 = 0; k0 < 1280; k0 += 32){
    __syncthreads();
    *reinterpret_cast<uint4*>(&As[alr][alc]) = a0;
    *reinterpret_cast<uint4*>(&Bs[alr][alc]) = b0;
    *reinterpret_cast<uint4*>(&Bs[64+alr][alc]) = b1;
    if (k0 + 32 < 1280){
      a0 = *reinterpret_cast<const uint4*>(Aptr + k0 + 32);
      b0 = *reinterpret_cast<const uint4*>(Bptr0 + k0 + 32);
      b1 = *reinterpret_cast<const uint4*>(Bptr1 + k0 + 32);
    }
    __syncthreads();
    bf16x8 af = *reinterpret_cast<const bf16x8*>(&As[w*16 + fr][fk]);
    #pragma unroll
    for (int n = 0; n < 5; ++n){
      bf16x8 bf = *reinterpret_cast<const bf16x8*>(&Bs[n*16 + fr][fk]);
      acc[n] = __builtin_amdgcn_mfma_f32_16x16x32_bf16(af, bf, acc[n], 0, 0, 0);
    }
  }

  bool v4 = (fr < 13);     // col 64+fr < 77
  #pragma unroll
  for (int r = 0; r < 4; ++r){
    float lg[5];
    #pragma unroll
    for (int n = 0; n < 5; ++n) lg[n] = acc[n][r]*0.125f;
    float m = fmaxf(fmaxf(lg[0],lg[1]), fmaxf(lg[2],lg[3]));
    if (v4) m = fmaxf(m, lg[4]);
    #pragma unroll
    for (int off = 1; off < 16; off <<= 1) m = fmaxf(m, __shfl_xor(m, off));
    float s = __expf(lg[0]-m) + __expf(lg[1]-m) + __expf(lg[2]-m) + __expf(lg[3]-m);
    if (v4) s += __expf(lg[4]-m);
    #pragma unroll
    for (int off = 1; off < 16; off <<= 1) s += __shfl_xor(s, off);
    float inv = 1.f / s;
    float a0s = 0.f, a1s = 0.f, a2s = 0.f, a3s = 0.f;
    #pragma unroll
    for (int n = 0; n < 5; ++n){
      int c = n*16 + fr;
      if (n < 4 || v4){
        float p = __expf(lg[n]-m) * inv;
        a0s += p*tipS[c][0]; a1s += p*tipS[c][1];
        a2s += p*tipS[c][2]; a3s += p*tipS[c][3];
      }
    }
    #pragma unroll
    for (int off = 1; off < 16; off <<= 1){
      a0s += __shfl_xor(a0s, off); a1s += __shfl_xor(a1s, off);
      a2s += __shfl_xor(a2s, off); a3s += __shfl_xor(a3s, off);
    }
    if (fr == 0){
      size_t row = (size_t)z*4096 + mt*64 + w*16 + fq*4 + r;
      f32x4 o = {a0s, a1s, a2s, a3s};
      *reinterpret_cast<f32x4*>(&sem[row*4]) = o;
    }
  }
}

// ============ MFMA fused text+ip attention ============
__global__ __launch_bounds__(256) void attn_mfma_k(
    const ushort* __restrict__ qb, const ushort* __restrict__ pall,
    const float* __restrict__ sem, const float* __restrict__ mask,
    ushort* __restrict__ hmid)
{
  int qt = blockIdx.x;   // 0..63
  int h  = blockIdx.y;   // 0..19
  int b  = blockIdx.z;   // 0..3
  __shared__ ushort Qs[64][72];
  __shared__ ushort Ks[96][72];
  __shared__ ushort Vt[64][104];  // V^T: [d][k]
  __shared__ ushort Ps[64][104];
  int t = threadIdx.x;
  int w = t >> 6, l = t & 63;
  const ushort* pb = pall + (size_t)b*81*5120 + h*64;

  {
    int base = b*4096 + qt*64;
    #pragma unroll
    for (int it = 0; it < 2; ++it){
      int chunk = t + it*256;
      int r = chunk >> 3, dp = (chunk & 7) << 3;
      uint4 v = *reinterpret_cast<const uint4*>(qb + (size_t)(base + r)*1280 + h*64 + dp);
      *reinterpret_cast<uint4*>(&Qs[r][dp]) = v;
    }
  }
  #pragma unroll
  for (int it = 0; it < 6; ++it){
    int chunk = t + it*256;
    int k = chunk >> 4, dp = (chunk & 15) << 2;
    ushort4 v = make_ushort4(0,0,0,0);
    if (k < 77)      v = *reinterpret_cast<const ushort4*>(pb + (size_t)k*5120 + dp);
    else if (k < 81) v = *reinterpret_cast<const ushort4*>(pb + (size_t)k*5120 + 2560 + dp);
    *reinterpret_cast<ushort4*>(&Ks[k][dp]) = v;
  }
  // V^T staging (ushort4): rows 81..95 are finite garbage x zero P cols
  #pragma unroll
  for (int it = 0; it < 6; ++it){
    int idx = t + it*256;
    int k = idx >> 4, d4 = (idx & 15) << 2;
    const ushort* src = (k < 77) ? pb + (size_t)k*5120 + 1280 + d4
                                 : pb + (size_t)k*5120 + 3840 + d4;
    ushort4 v = *reinterpret_cast<const ushort4*>(src);
    Vt[d4][k] = v.x; Vt[d4+1][k] = v.y; Vt[d4+2][k] = v.z; Vt[d4+3][k] = v.w;
  }
  __syncthreads();

  int fr = l & 15, fq = l >> 4, fkb = fq << 3;
  int c = fr;

  f32x4 s[6];
  #pragma unroll
  for (int n = 0; n < 6; ++n) s[n] = (f32x4){0.f,0.f,0.f,0.f};
  #pragma unroll
  for (int ks = 0; ks < 2; ++ks){
    bf16x8 aq = *reinterpret_cast<const bf16x8*>(&Qs[w*16 + fr][ks*32 + fkb]);
    #pragma unroll
    for (int n = 0; n < 6; ++n){
      bf16x8 bk = *reinterpret_cast<const bf16x8*>(&Ks[n*16 + fr][ks*32 + fkb]);
      s[n] = __builtin_amdgcn_mfma_f32_16x16x32_bf16(aq, bk, s[n], 0, 0, 0);
    }
  }

  int rowbase = qt*64 + w*16 + (fq << 2);
  #pragma unroll
  for (int r = 0; r < 4; ++r){
    float lg[6];
    #pragma unroll
    for (int n = 0; n < 6; ++n) lg[n] = s[n][r]*0.125f;

    float mt = fmaxf(fmaxf(lg[0],lg[1]), fmaxf(lg[2],lg[3]));
    if (c < 13) mt = fmaxf(mt, lg[4]);
    #pragma unroll
    for (int off = 1; off < 16; off <<= 1) mt = fmaxf(mt, __shfl_xor(mt, off));
    float st = __expf(lg[0]-mt) + __expf(lg[1]-mt) + __expf(lg[2]-mt) + __expf(lg[3]-mt);
    if (c < 13) st += __expf(lg[4]-mt);
    #pragma unroll
    for (int off = 1; off < 16; off <<= 1) st += __shfl_xor(st, off);
    float invst = 1.f/st;

    size_t qrow = (size_t)b*4096 + rowbase + r;
    float f4 = -1e30f, f5 = -1e30f;
    if (c >= 13) f4 = lg[4] + 0.5f*sem[qrow*4 + (c-13)];
    if (c == 0)  f5 = lg[5] + 0.5f*sem[qrow*4 + 3];
    float m2 = fmaxf(f4, f5);
    #pragma unroll
    for (int off = 1; off < 16; off <<= 1) m2 = fmaxf(m2, __shfl_xor(m2, off));
    float si = (c >= 13 ? __expf(f4-m2) : 0.f) + (c == 0 ? __expf(f5-m2) : 0.f);
    #pragma unroll
    for (int off = 1; off < 16; off <<= 1) si += __shfl_xor(si, off);
    float pmul = mask[rowbase + r] / si;

    int prow = w*16 + (fq << 2) + r;
    #pragma unroll
    for (int n = 0; n < 4; ++n) Ps[prow][n*16 + c] = f2b(__expf(lg[n]-mt)*invst);
    Ps[prow][64 + c] = f2b(c < 13 ? __expf(lg[4]-mt)*invst : __expf(f4-m2)*pmul);
    Ps[prow][80 + c] = f2b(c == 0 ? __expf(f5-m2)*pmul : 0.f);
  }
  __syncthreads();

  f32x4 o[4];
  #pragma unroll
  for (int df = 0; df < 4; ++df) o[df] = (f32x4){0.f,0.f,0.f,0.f};
  #pragma unroll
  for (int ks = 0; ks < 3; ++ks){
    bf16x8 ap = *reinterpret_cast<const bf16x8*>(&Ps[w*16 + fr][ks*32 + fkb]);
    #pragma unroll
    for (int df = 0; df < 4; ++df){
      bf16x8 bv = *reinterpret_cast<const bf16x8*>(&Vt[df*16 + fr][ks*32 + fkb]);
      o[df] = __builtin_amdgcn_mfma_f32_16x16x32_bf16(ap, bv, o[df], 0, 0, 0);
    }
  }
  #pragma unroll
  for (int df = 0; df < 4; ++df)
    #pragma unroll
    for (int r = 0; r < 4; ++r)
      hmid[((size_t)b*4096 + rowbase + r)*1280 + h*64 + df*16 + c] = f2b(o[df][r]);
}

extern "C" void kernel_launch(void* const* d_in, const int* in_sizes, int n_in,
                              void* d_out, int out_size, void* d_ws, size_t ws_size,
                              hipStream_t stream)
{
  (void)in_sizes; (void)n_in; (void)out_size; (void)ws_size;
  const float* hs   = (const float*)d_in[0];
  const float* enc  = (const float*)d_in[1];
  const float* mask = (const float*)d_in[2];
  const float* Wq   = (const float*)d_in[3];
  const float* Wk   = (const float*)d_in[4];
  const float* Wv   = (const float*)d_in[5];
  const float* Wkip = (const float*)d_in[6];
  const float* Wvip = (const float*)d_in[7];
  const float* Wout = (const float*)d_in[8];
  const float* bout = (const float*)d_in[9];
  float* out = (float*)d_out;
  char* ws = (char*)d_ws;

  size_t off = 0;
  auto alloc = [&](size_t bytes)->char*{
    char* p = ws + off; off += (bytes + 255) & ~(size_t)255; return p;
  };
  ushort* hs_bf   = (ushort*)alloc(16384ull*1280*2);   // reused as hmid
  ushort* q_bf    = (ushort*)alloc(16384ull*1280*2);
  ushort* enc_bf  = (ushort*)alloc(384ull*2048*2);
  ushort* wqt     = (ushort*)alloc(1280ull*1280*2);
  ushort* woutt   = (ushort*)alloc(1280ull*1280*2);
  ushort* wcat    = (ushort*)alloc(5120ull*2048*2);
  ushort* pall    = (ushort*)alloc(384ull*5120*2);
  float*  tip     = (float*)alloc(4ull*77*4*4);
  float*  semb    = (float*)alloc(16384ull*4*4);
  ushort* hmid_bf = hs_bf;

  // 1) all preprocessing in one launch
  prep_k<<<34996, 256, 0, stream>>>(hs, enc, Wq, Wout, Wk, Wv, Wkip, Wvip,
                                    hs_bf, enc_bf, wqt, woutt, wcat, tip);

  // 2) q-projection + encoder projections in one launch
  gemm_dual_k<<<1400, 256, 0, stream>>>(hs_bf, wqt, q_bf, enc_bf, wcat, pall);

  // 3) fused logits + text softmax + sem
  logits_sem_k<<<dim3(64,1,4), 256, 0, stream>>>(q_bf, pall, tip, semb);

  // 4) fused attention -> hmid (bf16)
  attn_mfma_k<<<dim3(64,20,4), 256, 0, stream>>>(q_bf, pall, semb, mask, hmid_bf);

  // 5) out = hmid @ Wout + bout + residual
  gemm_out_k<<<1280, 256, 0, stream>>>(hmid_bf, woutt, out, bout, hs);
}

// Round 10
// 349.912 us; speedup vs baseline: 1.1895x; 1.0098x over previous
//
#include <hip/hip_runtime.h>

typedef __bf16 bf16x8 __attribute__((ext_vector_type(8)));
typedef float f32x4 __attribute__((ext_vector_type(4)));

__device__ __forceinline__ ushort f2b(float f){
  union { float f; unsigned u; } v; v.f = f;
  unsigned r = v.u + 0x7FFFu + ((v.u >> 16) & 1u);
  return (ushort)(r >> 16);
}
__device__ __forceinline__ float b2f(ushort b){
  union { unsigned u; float f; } v; v.u = ((unsigned)b) << 16; return v.f;
}

__device__ __forceinline__ void gload16(const ushort* g, ushort* lds){
  __builtin_amdgcn_global_load_lds(
      (const __attribute__((address_space(1))) unsigned int*)(g),
      (__attribute__((address_space(3))) unsigned int*)(lds), 16, 0, 0);
}

#define VMW(n)  do { asm volatile("s_waitcnt vmcnt(" #n ")" ::: "memory"); __builtin_amdgcn_sched_barrier(0); } while(0)
#define BARR    do { __builtin_amdgcn_s_barrier(); __builtin_amdgcn_sched_barrier(0); } while(0)

// ============ prep mega-kernel: hs cvt | enc cvt | 6 weight transposes | T_ip ============
__global__ __launch_bounds__(256) void prep_k(
    const float* __restrict__ hs, const float* __restrict__ enc,
    const float* __restrict__ Wq, const float* __restrict__ Wout,
    const float* __restrict__ Wk, const float* __restrict__ Wv,
    const float* __restrict__ Wkip, const float* __restrict__ Wvip,
    ushort* __restrict__ hs_bf, ushort* __restrict__ enc_bf,
    ushort* __restrict__ wqt, ushort* __restrict__ woutt, ushort* __restrict__ wcat,
    float* __restrict__ tip)
{
  __shared__ float tile[32][33];
  int bid = blockIdx.x;
  int t = threadIdx.x;

  if (bid < 20480){                       // hs f32 -> bf16
    int i = bid*256 + t;
    f32x4 v = reinterpret_cast<const f32x4*>(hs)[i];
    ushort4 o = make_ushort4(f2b(v.x), f2b(v.y), f2b(v.z), f2b(v.w));
    reinterpret_cast<ushort4*>(hs_bf)[i] = o;
    return;
  }
  bid -= 20480;
  if (bid < 768){                         // enc f32 -> bf16 (pad to 384 rows)
    int i = bid*256 + t;
    f32x4 v = {0.f,0.f,0.f,0.f};
    if (i < 324*2048/4) v = reinterpret_cast<const f32x4*>(enc)[i];
    ushort4 o = make_ushort4(f2b(v.x), f2b(v.y), f2b(v.z), f2b(v.w));
    reinterpret_cast<ushort4*>(enc_bf)[i] = o;
    return;
  }
  bid -= 768;
  if (bid < 13440){                       // weight transposes
    const float* Wsrc; ushort* Wdst; int K;
    if (bid < 1600)      { Wsrc = Wq;   Wdst = wqt;                    K = 1280; }
    else if (bid < 3200) { bid -= 1600; Wsrc = Wout; Wdst = woutt;     K = 1280; }
    else if (bid < 5760) { bid -= 3200; Wsrc = Wk;   Wdst = wcat;      K = 2048; }
    else if (bid < 8320) { bid -= 5760; Wsrc = Wv;   Wdst = wcat + 1ull*1280*2048; K = 2048; }
    else if (bid < 10880){ bid -= 8320; Wsrc = Wkip; Wdst = wcat + 2ull*1280*2048; K = 2048; }
    else                 { bid -= 10880; Wsrc = Wvip; Wdst = wcat + 3ull*1280*2048; K = 2048; }
    int n0 = (bid % 40)*32, k0 = (bid / 40)*32;
    int tx = t & 31, ty = t >> 5;
    for (int i = ty; i < 32; i += 8) tile[i][tx] = Wsrc[(size_t)(k0+i)*1280 + n0+tx];
    __syncthreads();
    for (int i = ty; i < 32; i += 8) Wdst[(size_t)(n0+i)*K + k0+tx] = f2b(tile[tx][i]);
    return;
  }
  bid -= 13440;
  {                                       // tip[b][k][n] = 0.125 * text[b,k]·ip[b,n]
    int b = bid / 77, k = bid % 77;
    int n = t >> 6, l = t & 63;
    const float* text = enc + ((size_t)b*81 + k)*2048;
    const float* ip   = enc + ((size_t)b*81 + 77 + n)*2048;
    float acc = 0.f;
    for (int c = l; c < 2048; c += 64) acc += text[c]*ip[c];
    #pragma unroll
    for (int off = 32; off > 0; off >>= 1) acc += __shfl_xor(acc, off);
    if (l == 0) tip[((size_t)b*77 + k)*4 + n] = acc * 0.125f;
  }
}

// ============ shared 128x128 GEMM body: BK=32, 3-buffer counted-vmcnt pipeline ============
// __shared__ declared INSIDE (keeps addrspace(3) through inlining; one allocation per
// instantiation per kernel — both gemm_dual call sites share the same 48KB).
template<int MODE>
__device__ __forceinline__ void gemm_body(
    const ushort* __restrict__ A, const ushort* __restrict__ Bt,
    int K, int lda, int ldb, int ldo,
    float* __restrict__ outF, ushort* __restrict__ outB,
    const float* __restrict__ bias, const float* __restrict__ resid,
    int mt, int nt)
{
  __shared__ ushort As[3][128*32];
  __shared__ ushort Bs[3][128*32];
  int t = threadIdx.x;
  int w = t >> 6, l = t & 63;
  int wr = w >> 1, wc = w & 1;
  int fr = l & 15, fq = l >> 4;

  int r0 = t >> 2, s0 = t & 3;
  int r1 = r0 + 64;
  int sc0 = ((s0 ^ ((r0 >> 1) & 3)) << 3);
  int sc1 = ((s0 ^ ((r1 >> 1) & 3)) << 3);
  const ushort* Ag0 = A  + (size_t)(mt*128 + r0)*lda + sc0;
  const ushort* Ag1 = A  + (size_t)(mt*128 + r1)*lda + sc1;
  const ushort* Bg0 = Bt + (size_t)(nt*128 + r0)*ldb + sc0;
  const ushort* Bg1 = Bt + (size_t)(nt*128 + r1)*ldb + sc1;

  f32x4 acc[4][4];
  #pragma unroll
  for (int m = 0; m < 4; ++m)
    #pragma unroll
    for (int n = 0; n < 4; ++n) acc[m][n] = (f32x4){0.f,0.f,0.f,0.f};

  auto stage = [&](int s, int kt){
    int ko = kt << 5;
    ushort* a = &As[s][0] + t*8;
    ushort* b = &Bs[s][0] + t*8;
    gload16(Ag0 + ko, a);
    gload16(Ag1 + ko, a + 2048);
    gload16(Bg0 + ko, b);
    gload16(Bg1 + ko, b + 2048);
  };
  auto compute = [&](int s){
    bf16x8 af[4], bf[4];
    #pragma unroll
    for (int m = 0; m < 4; ++m){
      int row = wr*64 + m*16 + fr;
      af[m] = *reinterpret_cast<const bf16x8*>(&As[s][row*32 + ((fq ^ ((row >> 1) & 3)) << 3)]);
    }
    #pragma unroll
    for (int n = 0; n < 4; ++n){
      int row = wc*64 + n*16 + fr;
      bf[n] = *reinterpret_cast<const bf16x8*>(&Bs[s][row*32 + ((fq ^ ((row >> 1) & 3)) << 3)]);
    }
    #pragma unroll
    for (int m = 0; m < 4; ++m)
      #pragma unroll
      for (int n = 0; n < 4; ++n)
        acc[m][n] = __builtin_amdgcn_mfma_f32_16x16x32_bf16(af[m], bf[n], acc[m][n], 0, 0, 0);
  };

  int nk = K >> 5;
  stage(0, 0);
  stage(1, 1);
  int kt = 0;
  for (; kt < nk - 1; ++kt){
    VMW(4);
    BARR;
    if (kt + 2 < nk) stage((kt + 2) % 3, kt + 2);
    compute(kt % 3);
  }
  VMW(0);
  BARR;
  compute(kt % 3);

  int fqb = fq << 2;
  #pragma unroll
  for (int m = 0; m < 4; ++m){
    #pragma unroll
    for (int n = 0; n < 4; ++n){
      #pragma unroll
      for (int r = 0; r < 4; ++r){
        int row = mt*128 + wr*64 + m*16 + fqb + r;
        int col = nt*128 + wc*64 + n*16 + fr;
        size_t oidx = (size_t)row*ldo + col;
        float v = acc[m][n][r];
        if (MODE == 0) outB[oidx] = f2b(v);
        else           outF[oidx] = v + bias[col] + resid[oidx];
      }
    }
  }
}

// q-proj (1280 blocks) + enc-proj (120 blocks) in one launch
__global__ __launch_bounds__(256) void gemm_dual_k(
    const ushort* __restrict__ A1, const ushort* __restrict__ B1, ushort* __restrict__ O1,
    const ushort* __restrict__ A2, const ushort* __restrict__ B2, ushort* __restrict__ O2)
{
  int nwg = gridDim.x;
  int bid = blockIdx.x;
  if ((nwg & 7) == 0){
    int cpx = nwg >> 3;
    bid = (bid & 7)*cpx + (bid >> 3);
  }
  if (bid < 1280){
    gemm_body<0>(A1, B1, 1280, 1280, 1280, 1280,
                 nullptr, O1, nullptr, nullptr, bid/10, bid%10);
  } else {
    int lb = bid - 1280;
    gemm_body<0>(A2, B2, 2048, 2048, 2048, 5120,
                 nullptr, O2, nullptr, nullptr, lb/40, lb%40);
  }
}

// out-proj: fp32 + bias + residual
__global__ __launch_bounds__(256) void gemm_out_k(
    const ushort* __restrict__ A, const ushort* __restrict__ Bt, float* __restrict__ outF,
    const float* __restrict__ bias, const float* __restrict__ resid)
{
  int nwg = gridDim.x;
  int bid = blockIdx.x;
  if ((nwg & 7) == 0){
    int cpx = nwg >> 3;
    bid = (bid & 7)*cpx + (bid >> 3);
  }
  gemm_body<1>(A, Bt, 1280, 1280, 1280, 1280,
               outF, nullptr, bias, resid, bid/10, bid%10);
}

// ============ fused logits + text-softmax + sem kernel ============
__global__ __launch_bounds__(256) void logits_sem_k(
    const ushort* __restrict__ q, const ushort* __restrict__ pall,
    const float* __restrict__ tip, float* __restrict__ sem)
{
  __shared__ ushort As[64][40];
  __shared__ ushort Bs[128][40];
  __shared__ float tipS[77][4];
  int mt = blockIdx.x;
  int z  = blockIdx.z;
  int t = threadIdx.x;
  const ushort* Ab = q + (size_t)z*4096*1280;
  const ushort* Bb = pall + (size_t)z*81*5120;
  for (int i = t; i < 308; i += 256) (&tipS[0][0])[i] = tip[(size_t)z*308 + i];

  int w = t >> 6, l = t & 63;
  int fr = l & 15, fq = l >> 4, fk = fq << 3;
  int alr = t >> 2, alc = (t & 3) << 3;

  const ushort* Aptr  = Ab + (size_t)(mt*64 + alr)*1280 + alc;
  const ushort* Bptr0 = Bb + (size_t)alr*5120 + alc;
  const ushort* Bptr1 = Bb + (size_t)(64 + alr)*5120 + alc;

  f32x4 acc[5];
  #pragma unroll
  for (int n = 0; n < 5; ++n) acc[n] = (f32x4){0.f,0.f,0.f,0.f};

  uint4 a0 = *reinterpret_cast<const uint4*>(Aptr);
  uint4 b0 = *reinterpret_cast<const uint4*>(Bptr0);
  uint4 b1 = *reinterpret_cast<const uint4*>(Bptr1);
  for (int k0 = 0; k0 < 1280; k0 += 32){
    __syncthreads();
    *reinterpret_cast<uint4*>(&As[alr][alc]) = a0;
    *reinterpret_cast<uint4*>(&Bs[alr][alc]) = b0;
    *reinterpret_cast<uint4*>(&Bs[64+alr][alc]) = b1;
    if (k0 + 32 < 1280){
      a0 = *reinterpret_cast<const uint4*>(Aptr + k0 + 32);
      b0 = *reinterpret_cast<const uint4*>(Bptr0 + k0 + 32);
      b1 = *reinterpret_cast<const uint4*>(Bptr1 + k0 + 32);
    }
    __syncthreads();
    bf16x8 af = *reinterpret_cast<const bf16x8*>(&As[w*16 + fr][fk]);
    #pragma unroll
    for (int n = 0; n < 5; ++n){
      bf16x8 bf = *reinterpret_cast<const bf16x8*>(&Bs[n*16 + fr][fk]);
      acc[n] = __builtin_amdgcn_mfma_f32_16x16x32_bf16(af, bf, acc[n], 0, 0, 0);
    }
  }

  bool v4 = (fr < 13);     // col 64+fr < 77
  #pragma unroll
  for (int r = 0; r < 4; ++r){
    float lg[5];
    #pragma unroll
    for (int n = 0; n < 5; ++n) lg[n] = acc[n][r]*0.125f;
    float m = fmaxf(fmaxf(lg[0],lg[1]), fmaxf(lg[2],lg[3]));
    if (v4) m = fmaxf(m, lg[4]);
    #pragma unroll
    for (int off = 1; off < 16; off <<= 1) m = fmaxf(m, __shfl_xor(m, off));
    float s = __expf(lg[0]-m) + __expf(lg[1]-m) + __expf(lg[2]-m) + __expf(lg[3]-m);
    if (v4) s += __expf(lg[4]-m);
    #pragma unroll
    for (int off = 1; off < 16; off <<= 1) s += __shfl_xor(s, off);
    float inv = 1.f / s;
    float a0s = 0.f, a1s = 0.f, a2s = 0.f, a3s = 0.f;
    #pragma unroll
    for (int n = 0; n < 5; ++n){
      int c = n*16 + fr;
      if (n < 4 || v4){
        float p = __expf(lg[n]-m) * inv;
        a0s += p*tipS[c][0]; a1s += p*tipS[c][1];
        a2s += p*tipS[c][2]; a3s += p*tipS[c][3];
      }
    }
    #pragma unroll
    for (int off = 1; off < 16; off <<= 1){
      a0s += __shfl_xor(a0s, off); a1s += __shfl_xor(a1s, off);
      a2s += __shfl_xor(a2s, off); a3s += __shfl_xor(a3s, off);
    }
    if (fr == 0){
      size_t row = (size_t)z*4096 + mt*64 + w*16 + fq*4 + r;
      f32x4 o = {a0s, a1s, a2s, a3s};
      *reinterpret_cast<f32x4*>(&sem[row*4]) = o;
    }
  }
}

// ============ MFMA fused text+ip attention ============
__global__ __launch_bounds__(256) void attn_mfma_k(
    const ushort* __restrict__ qb, const ushort* __restrict__ pall,
    const float* __restrict__ sem, const float* __restrict__ mask,
    ushort* __restrict__ hmid)
{
  int qt = blockIdx.x;   // 0..63
  int h  = blockIdx.y;   // 0..19
  int b  = blockIdx.z;   // 0..3
  __shared__ ushort Qs[64][72];
  __shared__ ushort Ks[96][72];
  __shared__ ushort Vt[64][104];  // V^T: [d][k]
  __shared__ ushort Ps[64][104];
  int t = threadIdx.x;
  int w = t >> 6, l = t & 63;
  const ushort* pb = pall + (size_t)b*81*5120 + h*64;

  {
    int base = b*4096 + qt*64;
    #pragma unroll
    for (int it = 0; it < 2; ++it){
      int chunk = t + it*256;
      int r = chunk >> 3, dp = (chunk & 7) << 3;
      uint4 v = *reinterpret_cast<const uint4*>(qb + (size_t)(base + r)*1280 + h*64 + dp);
      *reinterpret_cast<uint4*>(&Qs[r][dp]) = v;
    }
  }
  #pragma unroll
  for (int it = 0; it < 6; ++it){
    int chunk = t + it*256;
    int k = chunk >> 4, dp = (chunk & 15) << 2;
    ushort4 v = make_ushort4(0,0,0,0);
    if (k < 77)      v = *reinterpret_cast<const ushort4*>(pb + (size_t)k*5120 + dp);
    else if (k < 81) v = *reinterpret_cast<const ushort4*>(pb + (size_t)k*5120 + 2560 + dp);
    *reinterpret_cast<ushort4*>(&Ks[k][dp]) = v;
  }
  // V^T staging (ushort4): rows 81..95 are finite garbage x zero P cols
  #pragma unroll
  for (int it = 0; it < 6; ++it){
    int idx = t + it*256;
    int k = idx >> 4, d4 = (idx & 15) << 2;
    const ushort* src = (k < 77) ? pb + (size_t)k*5120 + 1280 + d4
                                 : pb + (size_t)k*5120 + 3840 + d4;
    ushort4 v = *reinterpret_cast<const ushort4*>(src);
    Vt[d4][k] = v.x; Vt[d4+1][k] = v.y; Vt[d4+2][k] = v.z; Vt[d4+3][k] = v.w;
  }
  __syncthreads();

  int fr = l & 15, fq = l >> 4, fkb = fq << 3;
  int c = fr;

  f32x4 s[6];
  #pragma unroll
  for (int n = 0; n < 6; ++n) s[n] = (f32x4){0.f,0.f,0.f,0.f};
  #pragma unroll
  for (int ks = 0; ks < 2; ++ks){
    bf16x8 aq = *reinterpret_cast<const bf16x8*>(&Qs[w*16 + fr][ks*32 + fkb]);
    #pragma unroll
    for (int n = 0; n < 6; ++n){
      bf16x8 bk = *reinterpret_cast<const bf16x8*>(&Ks[n*16 + fr][ks*32 + fkb]);
      s[n] = __builtin_amdgcn_mfma_f32_16x16x32_bf16(aq, bk, s[n], 0, 0, 0);
    }
  }

  int rowbase = qt*64 + w*16 + (fq << 2);
  #pragma unroll
  for (int r = 0; r < 4; ++r){
    float lg[6];
    #pragma unroll
    for (int n = 0; n < 6; ++n) lg[n] = s[n][r]*0.125f;

    float mt = fmaxf(fmaxf(lg[0],lg[1]), fmaxf(lg[2],lg[3]));
    if (c < 13) mt = fmaxf(mt, lg[4]);
    #pragma unroll
    for (int off = 1; off < 16; off <<= 1) mt = fmaxf(mt, __shfl_xor(mt, off));
    float st = __expf(lg[0]-mt) + __expf(lg[1]-mt) + __expf(lg[2]-mt) + __expf(lg[3]-mt);
    if (c < 13) st += __expf(lg[4]-mt);
    #pragma unroll
    for (int off = 1; off < 16; off <<= 1) st += __shfl_xor(st, off);
    float invst = 1.f/st;

    size_t qrow = (size_t)b*4096 + rowbase + r;
    float f4 = -1e30f, f5 = -1e30f;
    if (c >= 13) f4 = lg[4] + 0.5f*sem[qrow*4 + (c-13)];
    if (c == 0)  f5 = lg[5] + 0.5f*sem[qrow*4 + 3];
    float m2 = fmaxf(f4, f5);
    #pragma unroll
    for (int off = 1; off < 16; off <<= 1) m2 = fmaxf(m2, __shfl_xor(m2, off));
    float si = (c >= 13 ? __expf(f4-m2) : 0.f) + (c == 0 ? __expf(f5-m2) : 0.f);
    #pragma unroll
    for (int off = 1; off < 16; off <<= 1) si += __shfl_xor(si, off);
    float pmul = mask[rowbase + r] / si;

    int prow = w*16 + (fq << 2) + r;
    #pragma unroll
    for (int n = 0; n < 4; ++n) Ps[prow][n*16 + c] = f2b(__expf(lg[n]-mt)*invst);
    Ps[prow][64 + c] = f2b(c < 13 ? __expf(lg[4]-mt)*invst : __expf(f4-m2)*pmul);
    Ps[prow][80 + c] = f2b(c == 0 ? __expf(f5-m2)*pmul : 0.f);
  }
  __syncthreads();

  f32x4 o[4];
  #pragma unroll
  for (int df = 0; df < 4; ++df) o[df] = (f32x4){0.f,0.f,0.f,0.f};
  #pragma unroll
  for (int ks = 0; ks < 3; ++ks){
    bf16x8 ap = *reinterpret_cast<const bf16x8*>(&Ps[w*16 + fr][ks*32 + fkb]);
    #pragma unroll
    for (int df = 0; df < 4; ++df){
      bf16x8 bv = *reinterpret_cast<const bf16x8*>(&Vt[df*16 + fr][ks*32 + fkb]);
      o[df] = __builtin_amdgcn_mfma_f32_16x16x32_bf16(ap, bv, o[df], 0, 0, 0);
    }
  }
  #pragma unroll
  for (int df = 0; df < 4; ++df)
    #pragma unroll
    for (int r = 0; r < 4; ++r)
      hmid[((size_t)b*4096 + rowbase + r)*1280 + h*64 + df*16 + c] = f2b(o[df][r]);
}

extern "C" void kernel_launch(void* const* d_in, const int* in_sizes, int n_in,
                              void* d_out, int out_size, void* d_ws, size_t ws_size,
                              hipStream_t stream)
{
  (void)in_sizes; (void)n_in; (void)out_size; (void)ws_size;
  const float* hs   = (const float*)d_in[0];
  const float* enc  = (const float*)d_in[1];
  const float* mask = (const float*)d_in[2];
  const float* Wq   = (const float*)d_in[3];
  const float* Wk   = (const float*)d_in[4];
  const float* Wv   = (const float*)d_in[5];
  const float* Wkip = (const float*)d_in[6];
  const float* Wvip = (const float*)d_in[7];
  const float* Wout = (const float*)d_in[8];
  const float* bout = (const float*)d_in[9];
  float* out = (float*)d_out;
  char* ws = (char*)d_ws;

  size_t off = 0;
  auto alloc = [&](size_t bytes)->char*{
    char* p = ws + off; off += (bytes + 255) & ~(size_t)255; return p;
  };
  ushort* hs_bf   = (ushort*)alloc(16384ull*1280*2);   // reused as hmid
  ushort* q_bf    = (ushort*)alloc(16384ull*1280*2);
  ushort* enc_bf  = (ushort*)alloc(384ull*2048*2);
  ushort* wqt     = (ushort*)alloc(1280ull*1280*2);
  ushort* woutt   = (ushort*)alloc(1280ull*1280*2);
  ushort* wcat    = (ushort*)alloc(5120ull*2048*2);
  ushort* pall    = (ushort*)alloc(384ull*5120*2);
  float*  tip     = (float*)alloc(4ull*77*4*4);
  float*  semb    = (float*)alloc(16384ull*4*4);
  ushort* hmid_bf = hs_bf;

  // 1) all preprocessing in one launch
  prep_k<<<34996, 256, 0, stream>>>(hs, enc, Wq, Wout, Wk, Wv, Wkip, Wvip,
                                    hs_bf, enc_bf, wqt, woutt, wcat, tip);

  // 2) q-projection + encoder projections in one launch
  gemm_dual_k<<<1400, 256, 0, stream>>>(hs_bf, wqt, q_bf, enc_bf, wcat, pall);

  // 3) fused logits + text softmax + sem
  logits_sem_k<<<dim3(64,1,4), 256, 0, stream>>>(q_bf, pall, tip, semb);

  // 4) fused attention -> hmid (bf16)
  attn_mfma_k<<<dim3(64,20,4), 256, 0, stream>>>(q_bf, pall, semb, mask, hmid_bf);

  // 5) out = hmid @ Wout + bout + residual
  gemm_out_k<<<1280, 256, 0, stream>>>(hmid_bf, woutt, out, bout, hs);
}

// Round 11
// 329.507 us; speedup vs baseline: 1.2632x; 1.0619x over previous
//
#include <hip/hip_runtime.h>

typedef __bf16 bf16x8 __attribute__((ext_vector_type(8)));
typedef float f32x4 __attribute__((ext_vector_type(4)));

__device__ __forceinline__ ushort f2b(float f){
  union { float f; unsigned u; } v; v.f = f;
  unsigned r = v.u + 0x7FFFu + ((v.u >> 16) & 1u);
  return (ushort)(r >> 16);
}
__device__ __forceinline__ float b2f(ushort b){
  union { unsigned u; float f; } v; v.u = ((unsigned)b) << 16; return v.f;
}

__device__ __forceinline__ void gload16(const ushort* g, ushort* lds){
  __builtin_amdgcn_global_load_lds(
      (const __attribute__((address_space(1))) unsigned int*)(g),
      (__attribute__((address_space(3))) unsigned int*)(lds), 16, 0, 0);
}

#define VMW(n)  do { asm volatile("s_waitcnt vmcnt(" #n ")" ::: "memory"); __builtin_amdgcn_sched_barrier(0); } while(0)
#define BARR    do { __builtin_amdgcn_s_barrier(); __builtin_amdgcn_sched_barrier(0); } while(0)

// ============ prep mega-kernel: hs cvt | enc cvt | 6 weight transposes | T_ip ============
__global__ __launch_bounds__(256) void prep_k(
    const float* __restrict__ hs, const float* __restrict__ enc,
    const float* __restrict__ Wq, const float* __restrict__ Wout,
    const float* __restrict__ Wk, const float* __restrict__ Wv,
    const float* __restrict__ Wkip, const float* __restrict__ Wvip,
    ushort* __restrict__ hs_bf, ushort* __restrict__ enc_bf,
    ushort* __restrict__ wqt, ushort* __restrict__ woutt, ushort* __restrict__ wcat,
    float* __restrict__ tip)
{
  __shared__ float tile[32][33];
  int bid = blockIdx.x;
  int t = threadIdx.x;

  if (bid < 20480){                       // hs f32 -> bf16
    int i = bid*256 + t;
    f32x4 v = reinterpret_cast<const f32x4*>(hs)[i];
    ushort4 o = make_ushort4(f2b(v.x), f2b(v.y), f2b(v.z), f2b(v.w));
    reinterpret_cast<ushort4*>(hs_bf)[i] = o;
    return;
  }
  bid -= 20480;
  if (bid < 768){                         // enc f32 -> bf16 (pad to 384 rows)
    int i = bid*256 + t;
    f32x4 v = {0.f,0.f,0.f,0.f};
    if (i < 324*2048/4) v = reinterpret_cast<const f32x4*>(enc)[i];
    ushort4 o = make_ushort4(f2b(v.x), f2b(v.y), f2b(v.z), f2b(v.w));
    reinterpret_cast<ushort4*>(enc_bf)[i] = o;
    return;
  }
  bid -= 768;
  if (bid < 13440){                       // weight transposes
    const float* Wsrc; ushort* Wdst; int K;
    if (bid < 1600)      { Wsrc = Wq;   Wdst = wqt;                    K = 1280; }
    else if (bid < 3200) { bid -= 1600; Wsrc = Wout; Wdst = woutt;     K = 1280; }
    else if (bid < 5760) { bid -= 3200; Wsrc = Wk;   Wdst = wcat;      K = 2048; }
    else if (bid < 8320) { bid -= 5760; Wsrc = Wv;   Wdst = wcat + 1ull*1280*2048; K = 2048; }
    else if (bid < 10880){ bid -= 8320; Wsrc = Wkip; Wdst = wcat + 2ull*1280*2048; K = 2048; }
    else                 { bid -= 10880; Wsrc = Wvip; Wdst = wcat + 3ull*1280*2048; K = 2048; }
    int n0 = (bid % 40)*32, k0 = (bid / 40)*32;
    int tx = t & 31, ty = t >> 5;
    for (int i = ty; i < 32; i += 8) tile[i][tx] = Wsrc[(size_t)(k0+i)*1280 + n0+tx];
    __syncthreads();
    for (int i = ty; i < 32; i += 8) Wdst[(size_t)(n0+i)*K + k0+tx] = f2b(tile[tx][i]);
    return;
  }
  bid -= 13440;
  {                                       // tip[b][k][n] = 0.125 * text[b,k]·ip[b,n]
    int b = bid / 77, k = bid % 77;
    int n = t >> 6, l = t & 63;
    const float* text = enc + ((size_t)b*81 + k)*2048;
    const float* ip   = enc + ((size_t)b*81 + 77 + n)*2048;
    float acc = 0.f;
    for (int c = l; c < 2048; c += 64) acc += text[c]*ip[c];
    #pragma unroll
    for (int off = 32; off > 0; off >>= 1) acc += __shfl_xor(acc, off);
    if (l == 0) tip[((size_t)b*77 + k)*4 + n] = acc * 0.125f;
  }
}

// ============ shared 128x128 GEMM body: BK=32, 3-buffer counted-vmcnt pipeline ============
// NOTE: K reaches here as a compile-time constant; WITHOUT `#pragma unroll 1` the
// compiler fully unrolls the 39/63-iteration pipeline loop (+24 VGPR, icache bloat,
// 108->129us regression seen in R9/R10). Keep the loop rolled.
template<int MODE>
__device__ __forceinline__ void gemm_body(
    const ushort* __restrict__ A, const ushort* __restrict__ Bt,
    int K, int lda, int ldb, int ldo,
    float* __restrict__ outF, ushort* __restrict__ outB,
    const float* __restrict__ bias, const float* __restrict__ resid,
    int mt, int nt)
{
  __shared__ ushort As[3][128*32];
  __shared__ ushort Bs[3][128*32];
  int t = threadIdx.x;
  int w = t >> 6, l = t & 63;
  int wr = w >> 1, wc = w & 1;
  int fr = l & 15, fq = l >> 4;

  int r0 = t >> 2, s0 = t & 3;
  int r1 = r0 + 64;
  int sc0 = ((s0 ^ ((r0 >> 1) & 3)) << 3);
  int sc1 = ((s0 ^ ((r1 >> 1) & 3)) << 3);
  const ushort* Ag0 = A  + (size_t)(mt*128 + r0)*lda + sc0;
  const ushort* Ag1 = A  + (size_t)(mt*128 + r1)*lda + sc1;
  const ushort* Bg0 = Bt + (size_t)(nt*128 + r0)*ldb + sc0;
  const ushort* Bg1 = Bt + (size_t)(nt*128 + r1)*ldb + sc1;

  f32x4 acc[4][4];
  #pragma unroll
  for (int m = 0; m < 4; ++m)
    #pragma unroll
    for (int n = 0; n < 4; ++n) acc[m][n] = (f32x4){0.f,0.f,0.f,0.f};

  auto stage = [&](int s, int kt){
    int ko = kt << 5;
    ushort* a = &As[s][0] + t*8;
    ushort* b = &Bs[s][0] + t*8;
    gload16(Ag0 + ko, a);
    gload16(Ag1 + ko, a + 2048);
    gload16(Bg0 + ko, b);
    gload16(Bg1 + ko, b + 2048);
  };
  auto compute = [&](int s){
    bf16x8 af[4], bf[4];
    #pragma unroll
    for (int m = 0; m < 4; ++m){
      int row = wr*64 + m*16 + fr;
      af[m] = *reinterpret_cast<const bf16x8*>(&As[s][row*32 + ((fq ^ ((row >> 1) & 3)) << 3)]);
    }
    #pragma unroll
    for (int n = 0; n < 4; ++n){
      int row = wc*64 + n*16 + fr;
      bf[n] = *reinterpret_cast<const bf16x8*>(&Bs[s][row*32 + ((fq ^ ((row >> 1) & 3)) << 3)]);
    }
    #pragma unroll
    for (int m = 0; m < 4; ++m)
      #pragma unroll
      for (int n = 0; n < 4; ++n)
        acc[m][n] = __builtin_amdgcn_mfma_f32_16x16x32_bf16(af[m], bf[n], acc[m][n], 0, 0, 0);
  };

  int nk = K >> 5;
  stage(0, 0);
  stage(1, 1);
  int kt = 0;
  #pragma unroll 1
  for (; kt < nk - 1; ++kt){
    VMW(4);
    BARR;
    if (kt + 2 < nk) stage((kt + 2) % 3, kt + 2);
    compute(kt % 3);
  }
  VMW(0);
  BARR;
  compute(kt % 3);

  int fqb = fq << 2;
  #pragma unroll
  for (int m = 0; m < 4; ++m){
    #pragma unroll
    for (int n = 0; n < 4; ++n){
      #pragma unroll
      for (int r = 0; r < 4; ++r){
        int row = mt*128 + wr*64 + m*16 + fqb + r;
        int col = nt*128 + wc*64 + n*16 + fr;
        size_t oidx = (size_t)row*ldo + col;
        float v = acc[m][n][r];
        if (MODE == 0) outB[oidx] = f2b(v);
        else           outF[oidx] = v + bias[col] + resid[oidx];
      }
    }
  }
}

// q-proj (1280 blocks) + enc-proj (120 blocks) in one launch
__global__ __launch_bounds__(256) void gemm_dual_k(
    const ushort* __restrict__ A1, const ushort* __restrict__ B1, ushort* __restrict__ O1,
    const ushort* __restrict__ A2, const ushort* __restrict__ B2, ushort* __restrict__ O2)
{
  int nwg = gridDim.x;
  int bid = blockIdx.x;
  if ((nwg & 7) == 0){
    int cpx = nwg >> 3;
    bid = (bid & 7)*cpx + (bid >> 3);
  }
  if (bid < 1280){
    gemm_body<0>(A1, B1, 1280, 1280, 1280, 1280,
                 nullptr, O1, nullptr, nullptr, bid/10, bid%10);
  } else {
    int lb = bid - 1280;
    gemm_body<0>(A2, B2, 2048, 2048, 2048, 5120,
                 nullptr, O2, nullptr, nullptr, lb/40, lb%40);
  }
}

// out-proj: fp32 + bias + residual
__global__ __launch_bounds__(256) void gemm_out_k(
    const ushort* __restrict__ A, const ushort* __restrict__ Bt, float* __restrict__ outF,
    const float* __restrict__ bias, const float* __restrict__ resid)
{
  int nwg = gridDim.x;
  int bid = blockIdx.x;
  if ((nwg & 7) == 0){
    int cpx = nwg >> 3;
    bid = (bid & 7)*cpx + (bid >> 3);
  }
  gemm_body<1>(A, Bt, 1280, 1280, 1280, 1280,
               outF, nullptr, bias, resid, bid/10, bid%10);
}

// ============ fused logits + text-softmax + sem kernel ============
__global__ __launch_bounds__(256) void logits_sem_k(
    const ushort* __restrict__ q, const ushort* __restrict__ pall,
    const float* __restrict__ tip, float* __restrict__ sem)
{
  __shared__ ushort As[64][40];
  __shared__ ushort Bs[128][40];
  __shared__ float tipS[77][4];
  int mt = blockIdx.x;
  int z  = blockIdx.z;
  int t = threadIdx.x;
  const ushort* Ab = q + (size_t)z*4096*1280;
  const ushort* Bb = pall + (size_t)z*81*5120;
  for (int i = t; i < 308; i += 256) (&tipS[0][0])[i] = tip[(size_t)z*308 + i];

  int w = t >> 6, l = t & 63;
  int fr = l & 15, fq = l >> 4, fk = fq << 3;
  int alr = t >> 2, alc = (t & 3) << 3;

  const ushort* Aptr  = Ab + (size_t)(mt*64 + alr)*1280 + alc;
  const ushort* Bptr0 = Bb + (size_t)alr*5120 + alc;
  const ushort* Bptr1 = Bb + (size_t)(64 + alr)*5120 + alc;

  f32x4 acc[5];
  #pragma unroll
  for (int n = 0; n < 5; ++n) acc[n] = (f32x4){0.f,0.f,0.f,0.f};

  uint4 a0 = *reinterpret_cast<const uint4*>(Aptr);
  uint4 b0 = *reinterpret_cast<const uint4*>(Bptr0);
  uint4 b1 = *reinterpret_cast<const uint4*>(Bptr1);
  #pragma unroll 1
  for (int k0 = 0; k0 < 1280; k0 += 32){
    __syncthreads();
    *reinterpret_cast<uint4*>(&As[alr][alc]) = a0;
    *reinterpret_cast<uint4*>(&Bs[alr][alc]) = b0;
    *reinterpret_cast<uint4*>(&Bs[64+alr][alc]) = b1;
    if (k0 + 32 < 1280){
      a0 = *reinterpret_cast<const uint4*>(Aptr + k0 + 32);
      b0 = *reinterpret_cast<const uint4*>(Bptr0 + k0 + 32);
      b1 = *reinterpret_cast<const uint4*>(Bptr1 + k0 + 32);
    }
    __syncthreads();
    bf16x8 af = *reinterpret_cast<const bf16x8*>(&As[w*16 + fr][fk]);
    #pragma unroll
    for (int n = 0; n < 5; ++n){
      bf16x8 bf = *reinterpret_cast<const bf16x8*>(&Bs[n*16 + fr][fk]);
      acc[n] = __builtin_amdgcn_mfma_f32_16x16x32_bf16(af, bf, acc[n], 0, 0, 0);
    }
  }

  bool v4 = (fr < 13);     // col 64+fr < 77
  #pragma unroll
  for (int r = 0; r < 4; ++r){
    float lg[5];
    #pragma unroll
    for (int n = 0; n < 5; ++n) lg[n] = acc[n][r]*0.125f;
    float m = fmaxf(fmaxf(lg[0],lg[1]), fmaxf(lg[2],lg[3]));
    if (v4) m = fmaxf(m, lg[4]);
    #pragma unroll
    for (int off = 1; off < 16; off <<= 1) m = fmaxf(m, __shfl_xor(m, off));
    float s = __expf(lg[0]-m) + __expf(lg[1]-m) + __expf(lg[2]-m) + __expf(lg[3]-m);
    if (v4) s += __expf(lg[4]-m);
    #pragma unroll
    for (int off = 1; off < 16; off <<= 1) s += __shfl_xor(s, off);
    float inv = 1.f / s;
    float a0s = 0.f, a1s = 0.f, a2s = 0.f, a3s = 0.f;
    #pragma unroll
    for (int n = 0; n < 5; ++n){
      int c = n*16 + fr;
      if (n < 4 || v4){
        float p = __expf(lg[n]-m) * inv;
        a0s += p*tipS[c][0]; a1s += p*tipS[c][1];
        a2s += p*tipS[c][2]; a3s += p*tipS[c][3];
      }
    }
    #pragma unroll
    for (int off = 1; off < 16; off <<= 1){
      a0s += __shfl_xor(a0s, off); a1s += __shfl_xor(a1s, off);
      a2s += __shfl_xor(a2s, off); a3s += __shfl_xor(a3s, off);
    }
    if (fr == 0){
      size_t row = (size_t)z*4096 + mt*64 + w*16 + fq*4 + r;
      f32x4 o = {a0s, a1s, a2s, a3s};
      *reinterpret_cast<f32x4*>(&sem[row*4]) = o;
    }
  }
}

// ============ MFMA fused text+ip attention ============
__global__ __launch_bounds__(256) void attn_mfma_k(
    const ushort* __restrict__ qb, const ushort* __restrict__ pall,
    const float* __restrict__ sem, const float* __restrict__ mask,
    ushort* __restrict__ hmid)
{
  int qt = blockIdx.x;   // 0..63
  int h  = blockIdx.y;   // 0..19
  int b  = blockIdx.z;   // 0..3
  __shared__ ushort Qs[64][72];
  __shared__ ushort Ks[96][72];
  __shared__ ushort Vt[64][104];  // V^T: [d][k]
  __shared__ ushort Ps[64][104];
  int t = threadIdx.x;
  int w = t >> 6, l = t & 63;
  const ushort* pb = pall + (size_t)b*81*5120 + h*64;

  {
    int base = b*4096 + qt*64;
    #pragma unroll
    for (int it = 0; it < 2; ++it){
      int chunk = t + it*256;
      int r = chunk >> 3, dp = (chunk & 7) << 3;
      uint4 v = *reinterpret_cast<const uint4*>(qb + (size_t)(base + r)*1280 + h*64 + dp);
      *reinterpret_cast<uint4*>(&Qs[r][dp]) = v;
    }
  }
  #pragma unroll
  for (int it = 0; it < 6; ++it){
    int chunk = t + it*256;
    int k = chunk >> 4, dp = (chunk & 15) << 2;
    ushort4 v = make_ushort4(0,0,0,0);
    if (k < 77)      v = *reinterpret_cast<const ushort4*>(pb + (size_t)k*5120 + dp);
    else if (k < 81) v = *reinterpret_cast<const ushort4*>(pb + (size_t)k*5120 + 2560 + dp);
    *reinterpret_cast<ushort4*>(&Ks[k][dp]) = v;
  }
  // V^T staging (ushort4): rows 81..95 are finite garbage x zero P cols
  #pragma unroll
  for (int it = 0; it < 6; ++it){
    int idx = t + it*256;
    int k = idx >> 4, d4 = (idx & 15) << 2;
    const ushort* src = (k < 77) ? pb + (size_t)k*5120 + 1280 + d4
                                 : pb + (size_t)k*5120 + 3840 + d4;
    ushort4 v = *reinterpret_cast<const ushort4*>(src);
    Vt[d4][k] = v.x; Vt[d4+1][k] = v.y; Vt[d4+2][k] = v.z; Vt[d4+3][k] = v.w;
  }
  __syncthreads();

  int fr = l & 15, fq = l >> 4, fkb = fq << 3;
  int c = fr;

  f32x4 s[6];
  #pragma unroll
  for (int n = 0; n < 6; ++n) s[n] = (f32x4){0.f,0.f,0.f,0.f};
  #pragma unroll
  for (int ks = 0; ks < 2; ++ks){
    bf16x8 aq = *reinterpret_cast<const bf16x8*>(&Qs[w*16 + fr][ks*32 + fkb]);
    #pragma unroll
    for (int n = 0; n < 6; ++n){
      bf16x8 bk = *reinterpret_cast<const bf16x8*>(&Ks[n*16 + fr][ks*32 + fkb]);
      s[n] = __builtin_amdgcn_mfma_f32_16x16x32_bf16(aq, bk, s[n], 0, 0, 0);
    }
  }

  int rowbase = qt*64 + w*16 + (fq << 2);
  #pragma unroll
  for (int r = 0; r < 4; ++r){
    float lg[6];
    #pragma unroll
    for (int n = 0; n < 6; ++n) lg[n] = s[n][r]*0.125f;

    float mt = fmaxf(fmaxf(lg[0],lg[1]), fmaxf(lg[2],lg[3]));
    if (c < 13) mt = fmaxf(mt, lg[4]);
    #pragma unroll
    for (int off = 1; off < 16; off <<= 1) mt = fmaxf(mt, __shfl_xor(mt, off));
    float st = __expf(lg[0]-mt) + __expf(lg[1]-mt) + __expf(lg[2]-mt) + __expf(lg[3]-mt);
    if (c < 13) st += __expf(lg[4]-mt);
    #pragma unroll
    for (int off = 1; off < 16; off <<= 1) st += __shfl_xor(st, off);
    float invst = 1.f/st;

    size_t qrow = (size_t)b*4096 + rowbase + r;
    float f4 = -1e30f, f5 = -1e30f;
    if (c >= 13) f4 = lg[4] + 0.5f*sem[qrow*4 + (c-13)];
    if (c == 0)  f5 = lg[5] + 0.5f*sem[qrow*4 + 3];
    float m2 = fmaxf(f4, f5);
    #pragma unroll
    for (int off = 1; off < 16; off <<= 1) m2 = fmaxf(m2, __shfl_xor(m2, off));
    float si = (c >= 13 ? __expf(f4-m2) : 0.f) + (c == 0 ? __expf(f5-m2) : 0.f);
    #pragma unroll
    for (int off = 1; off < 16; off <<= 1) si += __shfl_xor(si, off);
    float pmul = mask[rowbase + r] / si;

    int prow = w*16 + (fq << 2) + r;
    #pragma unroll
    for (int n = 0; n < 4; ++n) Ps[prow][n*16 + c] = f2b(__expf(lg[n]-mt)*invst);
    Ps[prow][64 + c] = f2b(c < 13 ? __expf(lg[4]-mt)*invst : __expf(f4-m2)*pmul);
    Ps[prow][80 + c] = f2b(c == 0 ? __expf(f5-m2)*pmul : 0.f);
  }
  __syncthreads();

  f32x4 o[4];
  #pragma unroll
  for (int df = 0; df < 4; ++df) o[df] = (f32x4){0.f,0.f,0.f,0.f};
  #pragma unroll
  for (int ks = 0; ks < 3; ++ks){
    bf16x8 ap = *reinterpret_cast<const bf16x8*>(&Ps[w*16 + fr][ks*32 + fkb]);
    #pragma unroll
    for (int df = 0; df < 4; ++df){
      bf16x8 bv = *reinterpret_cast<const bf16x8*>(&Vt[df*16 + fr][ks*32 + fkb]);
      o[df] = __builtin_amdgcn_mfma_f32_16x16x32_bf16(ap, bv, o[df], 0, 0, 0);
    }
  }
  #pragma unroll
  for (int df = 0; df < 4; ++df)
    #pragma unroll
    for (int r = 0; r < 4; ++r)
      hmid[((size_t)b*4096 + rowbase + r)*1280 + h*64 + df*16 + c] = f2b(o[df][r]);
}

extern "C" void kernel_launch(void* const* d_in, const int* in_sizes, int n_in,
                              void* d_out, int out_size, void* d_ws, size_t ws_size,
                              hipStream_t stream)
{
  (void)in_sizes; (void)n_in; (void)out_size; (void)ws_size;
  const float* hs   = (const float*)d_in[0];
  const float* enc  = (const float*)d_in[1];
  const float* mask = (const float*)d_in[2];
  const float* Wq   = (const float*)d_in[3];
  const float* Wk   = (const float*)d_in[4];
  const float* Wv   = (const float*)d_in[5];
  const float* Wkip = (const float*)d_in[6];
  const float* Wvip = (const float*)d_in[7];
  const float* Wout = (const float*)d_in[8];
  const float* bout = (const float*)d_in[9];
  float* out = (float*)d_out;
  char* ws = (char*)d_ws;

  size_t off = 0;
  auto alloc = [&](size_t bytes)->char*{
    char* p = ws + off; off += (bytes + 255) & ~(size_t)255; return p;
  };
  ushort* hs_bf   = (ushort*)alloc(16384ull*1280*2);   // reused as hmid
  ushort* q_bf    = (ushort*)alloc(16384ull*1280*2);
  ushort* enc_bf  = (ushort*)alloc(384ull*2048*2);
  ushort* wqt     = (ushort*)alloc(1280ull*1280*2);
  ushort* woutt   = (ushort*)alloc(1280ull*1280*2);
  ushort* wcat    = (ushort*)alloc(5120ull*2048*2);
  ushort* pall    = (ushort*)alloc(384ull*5120*2);
  float*  tip     = (float*)alloc(4ull*77*4*4);
  float*  semb    = (float*)alloc(16384ull*4*4);
  ushort* hmid_bf = hs_bf;

  // 1) all preprocessing in one launch
  prep_k<<<34996, 256, 0, stream>>>(hs, enc, Wq, Wout, Wk, Wv, Wkip, Wvip,
                                    hs_bf, enc_bf, wqt, woutt, wcat, tip);

  // 2) q-projection + encoder projections in one launch
  gemm_dual_k<<<1400, 256, 0, stream>>>(hs_bf, wqt, q_bf, enc_bf, wcat, pall);

  // 3) fused logits + text softmax + sem
  logits_sem_k<<<dim3(64,1,4), 256, 0, stream>>>(q_bf, pall, tip, semb);

  // 4) fused attention -> hmid (bf16)
  attn_mfma_k<<<dim3(64,20,4), 256, 0, stream>>>(q_bf, pall, semb, mask, hmid_bf);

  // 5) out = hmid @ Wout + bout + residual
  gemm_out_k<<<1280, 256, 0, stream>>>(hmid_bf, woutt, out, bout, hs);
}

// Round 12
// 309.940 us; speedup vs baseline: 1.3430x; 1.0631x over previous
//
#include <hip/hip_runtime.h>

typedef __bf16 bf16x8 __attribute__((ext_vector_type(8)));
typedef float f32x4 __attribute__((ext_vector_type(4)));

__device__ __forceinline__ ushort f2b(float f){
  union { float f; unsigned u; } v; v.f = f;
  unsigned r = v.u + 0x7FFFu + ((v.u >> 16) & 1u);
  return (ushort)(r >> 16);
}
__device__ __forceinline__ float b2f(ushort b){
  union { unsigned u; float f; } v; v.u = ((unsigned)b) << 16; return v.f;
}

__device__ __forceinline__ void gload16(const ushort* g, ushort* lds){
  __builtin_amdgcn_global_load_lds(
      (const __attribute__((address_space(1))) unsigned int*)(g),
      (__attribute__((address_space(3))) unsigned int*)(lds), 16, 0, 0);
}

#define VMW(n)  do { asm volatile("s_waitcnt vmcnt(" #n ")" ::: "memory"); __builtin_amdgcn_sched_barrier(0); } while(0)
#define BARR    do { __builtin_amdgcn_s_barrier(); __builtin_amdgcn_sched_barrier(0); } while(0)

// ============ prep mega-kernel: hs cvt | enc cvt | 6 weight transposes | T_ip ============
__global__ __launch_bounds__(256) void prep_k(
    const float* __restrict__ hs, const float* __restrict__ enc,
    const float* __restrict__ Wq, const float* __restrict__ Wout,
    const float* __restrict__ Wk, const float* __restrict__ Wv,
    const float* __restrict__ Wkip, const float* __restrict__ Wvip,
    ushort* __restrict__ hs_bf, ushort* __restrict__ enc_bf,
    ushort* __restrict__ wqt, ushort* __restrict__ woutt, ushort* __restrict__ wcat,
    float* __restrict__ tip)
{
  __shared__ float tile[32][33];
  int bid = blockIdx.x;
  int t = threadIdx.x;

  if (bid < 20480){                       // hs f32 -> bf16
    int i = bid*256 + t;
    f32x4 v = reinterpret_cast<const f32x4*>(hs)[i];
    ushort4 o = make_ushort4(f2b(v.x), f2b(v.y), f2b(v.z), f2b(v.w));
    reinterpret_cast<ushort4*>(hs_bf)[i] = o;
    return;
  }
  bid -= 20480;
  if (bid < 768){                         // enc f32 -> bf16 (pad to 384 rows)
    int i = bid*256 + t;
    f32x4 v = {0.f,0.f,0.f,0.f};
    if (i < 324*2048/4) v = reinterpret_cast<const f32x4*>(enc)[i];
    ushort4 o = make_ushort4(f2b(v.x), f2b(v.y), f2b(v.z), f2b(v.w));
    reinterpret_cast<ushort4*>(enc_bf)[i] = o;
    return;
  }
  bid -= 768;
  if (bid < 13440){                       // weight transposes
    const float* Wsrc; ushort* Wdst; int K;
    if (bid < 1600)      { Wsrc = Wq;   Wdst = wqt;                    K = 1280; }
    else if (bid < 3200) { bid -= 1600; Wsrc = Wout; Wdst = woutt;     K = 1280; }
    else if (bid < 5760) { bid -= 3200; Wsrc = Wk;   Wdst = wcat;      K = 2048; }
    else if (bid < 8320) { bid -= 5760; Wsrc = Wv;   Wdst = wcat + 1ull*1280*2048; K = 2048; }
    else if (bid < 10880){ bid -= 8320; Wsrc = Wkip; Wdst = wcat + 2ull*1280*2048; K = 2048; }
    else                 { bid -= 10880; Wsrc = Wvip; Wdst = wcat + 3ull*1280*2048; K = 2048; }
    int n0 = (bid % 40)*32, k0 = (bid / 40)*32;
    int tx = t & 31, ty = t >> 5;
    for (int i = ty; i < 32; i += 8) tile[i][tx] = Wsrc[(size_t)(k0+i)*1280 + n0+tx];
    __syncthreads();
    for (int i = ty; i < 32; i += 8) Wdst[(size_t)(n0+i)*K + k0+tx] = f2b(tile[tx][i]);
    return;
  }
  bid -= 13440;
  {                                       // tip[b][k][n] = 0.125 * text[b,k]·ip[b,n]
    int b = bid / 77, k = bid % 77;
    int n = t >> 6, l = t & 63;
    const float* text = enc + ((size_t)b*81 + k)*2048;
    const float* ip   = enc + ((size_t)b*81 + 77 + n)*2048;
    float acc = 0.f;
    for (int c = l; c < 2048; c += 64) acc += text[c]*ip[c];
    #pragma unroll
    for (int off = 32; off > 0; off >>= 1) acc += __shfl_xor(acc, off);
    if (l == 0) tip[((size_t)b*77 + k)*4 + n] = acc * 0.125f;
  }
}

// ============ shared 128x128 GEMM body: BK=32, 2-buffer counted-vmcnt pipeline ============
// 32KB LDS -> 5 blocks/CU (20 waves). Per K-step: BARR1 (buffer-overwrite safety);
// stage(kt+1); VMW(4) = "stage(kt) retired" (in-order vmcnt); BARR2 (collective);
// ds_read frags; 16 MFMA/wave. Last iter VMW(0) (VMW(4) would be a no-op).
// `#pragma unroll 1` — K is compile-time const; full unroll costs +24 VGPR (R9/R10).
template<int MODE>
__device__ __forceinline__ void gemm_body(
    const ushort* __restrict__ A, const ushort* __restrict__ Bt,
    int K, int lda, int ldb, int ldo,
    float* __restrict__ outF, ushort* __restrict__ outB,
    const float* __restrict__ bias, const float* __restrict__ resid,
    int mt, int nt)
{
  __shared__ ushort As[2][128*32];
  __shared__ ushort Bs[2][128*32];
  int t = threadIdx.x;
  int w = t >> 6, l = t & 63;
  int wr = w >> 1, wc = w & 1;
  int fr = l & 15, fq = l >> 4;

  int r0 = t >> 2, s0 = t & 3;
  int r1 = r0 + 64;
  int sc0 = ((s0 ^ ((r0 >> 1) & 3)) << 3);
  int sc1 = ((s0 ^ ((r1 >> 1) & 3)) << 3);
  const ushort* Ag0 = A  + (size_t)(mt*128 + r0)*lda + sc0;
  const ushort* Ag1 = A  + (size_t)(mt*128 + r1)*lda + sc1;
  const ushort* Bg0 = Bt + (size_t)(nt*128 + r0)*ldb + sc0;
  const ushort* Bg1 = Bt + (size_t)(nt*128 + r1)*ldb + sc1;

  f32x4 acc[4][4];
  #pragma unroll
  for (int m = 0; m < 4; ++m)
    #pragma unroll
    for (int n = 0; n < 4; ++n) acc[m][n] = (f32x4){0.f,0.f,0.f,0.f};

  auto stage = [&](int s, int kt){
    int ko = kt << 5;
    ushort* a = &As[s][0] + t*8;
    ushort* b = &Bs[s][0] + t*8;
    gload16(Ag0 + ko, a);
    gload16(Ag1 + ko, a + 2048);
    gload16(Bg0 + ko, b);
    gload16(Bg1 + ko, b + 2048);
  };
  auto compute = [&](int s){
    bf16x8 af[4], bf[4];
    #pragma unroll
    for (int m = 0; m < 4; ++m){
      int row = wr*64 + m*16 + fr;
      af[m] = *reinterpret_cast<const bf16x8*>(&As[s][row*32 + ((fq ^ ((row >> 1) & 3)) << 3)]);
    }
    #pragma unroll
    for (int n = 0; n < 4; ++n){
      int row = wc*64 + n*16 + fr;
      bf[n] = *reinterpret_cast<const bf16x8*>(&Bs[s][row*32 + ((fq ^ ((row >> 1) & 3)) << 3)]);
    }
    #pragma unroll
    for (int m = 0; m < 4; ++m)
      #pragma unroll
      for (int n = 0; n < 4; ++n)
        acc[m][n] = __builtin_amdgcn_mfma_f32_16x16x32_bf16(af[m], bf[n], acc[m][n], 0, 0, 0);
  };

  int nk = K >> 5;
  stage(0, 0);
  #pragma unroll 1
  for (int kt = 0; kt < nk; ++kt){
    BARR;                                 // all waves done reading buf[(kt+1)&1]
    if (kt + 1 < nk){ stage((kt + 1) & 1, kt + 1); VMW(4); }
    else            { VMW(0); }
    BARR;                                 // collective: tile kt fully in LDS
    compute(kt & 1);
  }

  int fqb = fq << 2;
  #pragma unroll
  for (int m = 0; m < 4; ++m){
    #pragma unroll
    for (int n = 0; n < 4; ++n){
      #pragma unroll
      for (int r = 0; r < 4; ++r){
        int row = mt*128 + wr*64 + m*16 + fqb + r;
        int col = nt*128 + wc*64 + n*16 + fr;
        size_t oidx = (size_t)row*ldo + col;
        float v = acc[m][n][r];
        if (MODE == 0) outB[oidx] = f2b(v);
        else           outF[oidx] = v + bias[col] + resid[oidx];
      }
    }
  }
}

// enc-proj (K=2048, longer blocks) on blockIdx 0..119 so they launch FIRST and run
// in q-proj's shadow; q-proj swizzled bijectively over its own 1280 range.
__global__ __launch_bounds__(256) void gemm_dual_k(
    const ushort* __restrict__ A1, const ushort* __restrict__ B1, ushort* __restrict__ O1,
    const ushort* __restrict__ A2, const ushort* __restrict__ B2, ushort* __restrict__ O2)
{
  int bid = blockIdx.x;
  if (bid < 120){
    gemm_body<0>(A2, B2, 2048, 2048, 2048, 5120,
                 nullptr, O2, nullptr, nullptr, bid/40, bid%40);
  } else {
    int qb = bid - 120;
    qb = (qb & 7)*160 + (qb >> 3);        // 1280/8 = 160, bijective
    gemm_body<0>(A1, B1, 1280, 1280, 1280, 1280,
                 nullptr, O1, nullptr, nullptr, qb/10, qb%10);
  }
}

// out-proj: fp32 + bias + residual
__global__ __launch_bounds__(256) void gemm_out_k(
    const ushort* __restrict__ A, const ushort* __restrict__ Bt, float* __restrict__ outF,
    const float* __restrict__ bias, const float* __restrict__ resid)
{
  int nwg = gridDim.x;
  int bid = blockIdx.x;
  if ((nwg & 7) == 0){
    int cpx = nwg >> 3;
    bid = (bid & 7)*cpx + (bid >> 3);
  }
  gemm_body<1>(A, Bt, 1280, 1280, 1280, 1280,
               outF, nullptr, bias, resid, bid/10, bid%10);
}

// ============ fused logits + text-softmax + sem kernel ============
__global__ __launch_bounds__(256) void logits_sem_k(
    const ushort* __restrict__ q, const ushort* __restrict__ pall,
    const float* __restrict__ tip, float* __restrict__ sem)
{
  __shared__ ushort As[64][40];
  __shared__ ushort Bs[128][40];
  __shared__ float tipS[77][4];
  int mt = blockIdx.x;
  int z  = blockIdx.z;
  int t = threadIdx.x;
  const ushort* Ab = q + (size_t)z*4096*1280;
  const ushort* Bb = pall + (size_t)z*81*5120;
  for (int i = t; i < 308; i += 256) (&tipS[0][0])[i] = tip[(size_t)z*308 + i];

  int w = t >> 6, l = t & 63;
  int fr = l & 15, fq = l >> 4, fk = fq << 3;
  int alr = t >> 2, alc = (t & 3) << 3;

  const ushort* Aptr  = Ab + (size_t)(mt*64 + alr)*1280 + alc;
  const ushort* Bptr0 = Bb + (size_t)alr*5120 + alc;
  const ushort* Bptr1 = Bb + (size_t)(64 + alr)*5120 + alc;

  f32x4 acc[5];
  #pragma unroll
  for (int n = 0; n < 5; ++n) acc[n] = (f32x4){0.f,0.f,0.f,0.f};

  uint4 a0 = *reinterpret_cast<const uint4*>(Aptr);
  uint4 b0 = *reinterpret_cast<const uint4*>(Bptr0);
  uint4 b1 = *reinterpret_cast<const uint4*>(Bptr1);
  #pragma unroll 1
  for (int k0 = 0; k0 < 1280; k0 += 32){
    __syncthreads();
    *reinterpret_cast<uint4*>(&As[alr][alc]) = a0;
    *reinterpret_cast<uint4*>(&Bs[alr][alc]) = b0;
    *reinterpret_cast<uint4*>(&Bs[64+alr][alc]) = b1;
    if (k0 + 32 < 1280){
      a0 = *reinterpret_cast<const uint4*>(Aptr + k0 + 32);
      b0 = *reinterpret_cast<const uint4*>(Bptr0 + k0 + 32);
      b1 = *reinterpret_cast<const uint4*>(Bptr1 + k0 + 32);
    }
    __syncthreads();
    bf16x8 af = *reinterpret_cast<const bf16x8*>(&As[w*16 + fr][fk]);
    #pragma unroll
    for (int n = 0; n < 5; ++n){
      bf16x8 bf = *reinterpret_cast<const bf16x8*>(&Bs[n*16 + fr][fk]);
      acc[n] = __builtin_amdgcn_mfma_f32_16x16x32_bf16(af, bf, acc[n], 0, 0, 0);
    }
  }

  bool v4 = (fr < 13);     // col 64+fr < 77
  #pragma unroll
  for (int r = 0; r < 4; ++r){
    float lg[5];
    #pragma unroll
    for (int n = 0; n < 5; ++n) lg[n] = acc[n][r]*0.125f;
    float m = fmaxf(fmaxf(lg[0],lg[1]), fmaxf(lg[2],lg[3]));
    if (v4) m = fmaxf(m, lg[4]);
    #pragma unroll
    for (int off = 1; off < 16; off <<= 1) m = fmaxf(m, __shfl_xor(m, off));
    float s = __expf(lg[0]-m) + __expf(lg[1]-m) + __expf(lg[2]-m) + __expf(lg[3]-m);
    if (v4) s += __expf(lg[4]-m);
    #pragma unroll
    for (int off = 1; off < 16; off <<= 1) s += __shfl_xor(s, off);
    float inv = 1.f / s;
    float a0s = 0.f, a1s = 0.f, a2s = 0.f, a3s = 0.f;
    #pragma unroll
    for (int n = 0; n < 5; ++n){
      int c = n*16 + fr;
      if (n < 4 || v4){
        float p = __expf(lg[n]-m) * inv;
        a0s += p*tipS[c][0]; a1s += p*tipS[c][1];
        a2s += p*tipS[c][2]; a3s += p*tipS[c][3];
      }
    }
    #pragma unroll
    for (int off = 1; off < 16; off <<= 1){
      a0s += __shfl_xor(a0s, off); a1s += __shfl_xor(a1s, off);
      a2s += __shfl_xor(a2s, off); a3s += __shfl_xor(a3s, off);
    }
    if (fr == 0){
      size_t row = (size_t)z*4096 + mt*64 + w*16 + fq*4 + r;
      f32x4 o = {a0s, a1s, a2s, a3s};
      *reinterpret_cast<f32x4*>(&sem[row*4]) = o;
    }
  }
}

// ============ MFMA fused text+ip attention ============
__global__ __launch_bounds__(256) void attn_mfma_k(
    const ushort* __restrict__ qb, const ushort* __restrict__ pall,
    const float* __restrict__ sem, const float* __restrict__ mask,
    ushort* __restrict__ hmid)
{
  int qt = blockIdx.x;   // 0..63
  int h  = blockIdx.y;   // 0..19
  int b  = blockIdx.z;   // 0..3
  __shared__ ushort Qs[64][72];
  __shared__ ushort Ks[96][72];
  __shared__ ushort Vt[64][104];  // V^T: [d][k]
  __shared__ ushort Ps[64][104];
  int t = threadIdx.x;
  int w = t >> 6, l = t & 63;
  const ushort* pb = pall + (size_t)b*81*5120 + h*64;

  {
    int base = b*4096 + qt*64;
    #pragma unroll
    for (int it = 0; it < 2; ++it){
      int chunk = t + it*256;
      int r = chunk >> 3, dp = (chunk & 7) << 3;
      uint4 v = *reinterpret_cast<const uint4*>(qb + (size_t)(base + r)*1280 + h*64 + dp);
      *reinterpret_cast<uint4*>(&Qs[r][dp]) = v;
    }
  }
  #pragma unroll
  for (int it = 0; it < 6; ++it){
    int chunk = t + it*256;
    int k = chunk >> 4, dp = (chunk & 15) << 2;
    ushort4 v = make_ushort4(0,0,0,0);
    if (k < 77)      v = *reinterpret_cast<const ushort4*>(pb + (size_t)k*5120 + dp);
    else if (k < 81) v = *reinterpret_cast<const ushort4*>(pb + (size_t)k*5120 + 2560 + dp);
    *reinterpret_cast<ushort4*>(&Ks[k][dp]) = v;
  }
  // V^T staging (ushort4): rows 81..95 are finite garbage x zero P cols
  #pragma unroll
  for (int it = 0; it < 6; ++it){
    int idx = t + it*256;
    int k = idx >> 4, d4 = (idx & 15) << 2;
    const ushort* src = (k < 77) ? pb + (size_t)k*5120 + 1280 + d4
                                 : pb + (size_t)k*5120 + 3840 + d4;
    ushort4 v = *reinterpret_cast<const ushort4*>(src);
    Vt[d4][k] = v.x; Vt[d4+1][k] = v.y; Vt[d4+2][k] = v.z; Vt[d4+3][k] = v.w;
  }
  __syncthreads();

  int fr = l & 15, fq = l >> 4, fkb = fq << 3;
  int c = fr;

  f32x4 s[6];
  #pragma unroll
  for (int n = 0; n < 6; ++n) s[n] = (f32x4){0.f,0.f,0.f,0.f};
  #pragma unroll
  for (int ks = 0; ks < 2; ++ks){
    bf16x8 aq = *reinterpret_cast<const bf16x8*>(&Qs[w*16 + fr][ks*32 + fkb]);
    #pragma unroll
    for (int n = 0; n < 6; ++n){
      bf16x8 bk = *reinterpret_cast<const bf16x8*>(&Ks[n*16 + fr][ks*32 + fkb]);
      s[n] = __builtin_amdgcn_mfma_f32_16x16x32_bf16(aq, bk, s[n], 0, 0, 0);
    }
  }

  int rowbase = qt*64 + w*16 + (fq << 2);
  #pragma unroll
  for (int r = 0; r < 4; ++r){
    float lg[6];
    #pragma unroll
    for (int n = 0; n < 6; ++n) lg[n] = s[n][r]*0.125f;

    float mt = fmaxf(fmaxf(lg[0],lg[1]), fmaxf(lg[2],lg[3]));
    if (c < 13) mt = fmaxf(mt, lg[4]);
    #pragma unroll
    for (int off = 1; off < 16; off <<= 1) mt = fmaxf(mt, __shfl_xor(mt, off));
    float st = __expf(lg[0]-mt) + __expf(lg[1]-mt) + __expf(lg[2]-mt) + __expf(lg[3]-mt);
    if (c < 13) st += __expf(lg[4]-mt);
    #pragma unroll
    for (int off = 1; off < 16; off <<= 1) st += __shfl_xor(st, off);
    float invst = 1.f/st;

    size_t qrow = (size_t)b*4096 + rowbase + r;
    float f4 = -1e30f, f5 = -1e30f;
    if (c >= 13) f4 = lg[4] + 0.5f*sem[qrow*4 + (c-13)];
    if (c == 0)  f5 = lg[5] + 0.5f*sem[qrow*4 + 3];
    float m2 = fmaxf(f4, f5);
    #pragma unroll
    for (int off = 1; off < 16; off <<= 1) m2 = fmaxf(m2, __shfl_xor(m2, off));
    float si = (c >= 13 ? __expf(f4-m2) : 0.f) + (c == 0 ? __expf(f5-m2) : 0.f);
    #pragma unroll
    for (int off = 1; off < 16; off <<= 1) si += __shfl_xor(si, off);
    float pmul = mask[rowbase + r] / si;

    int prow = w*16 + (fq << 2) + r;
    #pragma unroll
    for (int n = 0; n < 4; ++n) Ps[prow][n*16 + c] = f2b(__expf(lg[n]-mt)*invst);
    Ps[prow][64 + c] = f2b(c < 13 ? __expf(lg[4]-mt)*invst : __expf(f4-m2)*pmul);
    Ps[prow][80 + c] = f2b(c == 0 ? __expf(f5-m2)*pmul : 0.f);
  }
  __syncthreads();

  f32x4 o[4];
  #pragma unroll
  for (int df = 0; df < 4; ++df) o[df] = (f32x4){0.f,0.f,0.f,0.f};
  #pragma unroll
  for (int ks = 0; ks < 3; ++ks){
    bf16x8 ap = *reinterpret_cast<const bf16x8*>(&Ps[w*16 + fr][ks*32 + fkb]);
    #pragma unroll
    for (int df = 0; df < 4; ++df){
      bf16x8 bv = *reinterpret_cast<const bf16x8*>(&Vt[df*16 + fr][ks*32 + fkb]);
      o[df] = __builtin_amdgcn_mfma_f32_16x16x32_bf16(ap, bv, o[df], 0, 0, 0);
    }
  }
  #pragma unroll
  for (int df = 0; df < 4; ++df)
    #pragma unroll
    for (int r = 0; r < 4; ++r)
      hmid[((size_t)b*4096 + rowbase + r)*1280 + h*64 + df*16 + c] = f2b(o[df][r]);
}

extern "C" void kernel_launch(void* const* d_in, const int* in_sizes, int n_in,
                              void* d_out, int out_size, void* d_ws, size_t ws_size,
                              hipStream_t stream)
{
  (void)in_sizes; (void)n_in; (void)out_size; (void)ws_size;
  const float* hs   = (const float*)d_in[0];
  const float* enc  = (const float*)d_in[1];
  const float* mask = (const float*)d_in[2];
  const float* Wq   = (const float*)d_in[3];
  const float* Wk   = (const float*)d_in[4];
  const float* Wv   = (const float*)d_in[5];
  const float* Wkip = (const float*)d_in[6];
  const float* Wvip = (const float*)d_in[7];
  const float* Wout = (const float*)d_in[8];
  const float* bout = (const float*)d_in[9];
  float* out = (float*)d_out;
  char* ws = (char*)d_ws;

  size_t off = 0;
  auto alloc = [&](size_t bytes)->char*{
    char* p = ws + off; off += (bytes + 255) & ~(size_t)255; return p;
  };
  ushort* hs_bf   = (ushort*)alloc(16384ull*1280*2);   // reused as hmid
  ushort* q_bf    = (ushort*)alloc(16384ull*1280*2);
  ushort* enc_bf  = (ushort*)alloc(384ull*2048*2);
  ushort* wqt     = (ushort*)alloc(1280ull*1280*2);
  ushort* woutt   = (ushort*)alloc(1280ull*1280*2);
  ushort* wcat    = (ushort*)alloc(5120ull*2048*2);
  ushort* pall    = (ushort*)alloc(384ull*5120*2);
  float*  tip     = (float*)alloc(4ull*77*4*4);
  float*  semb    = (float*)alloc(16384ull*4*4);
  ushort* hmid_bf = hs_bf;

  // 1) all preprocessing in one launch
  prep_k<<<34996, 256, 0, stream>>>(hs, enc, Wq, Wout, Wk, Wv, Wkip, Wvip,
                                    hs_bf, enc_bf, wqt, woutt, wcat, tip);

  // 2) q-projection + encoder projections in one launch (enc first)
  gemm_dual_k<<<1400, 256, 0, stream>>>(hs_bf, wqt, q_bf, enc_bf, wcat, pall);

  // 3) fused logits + text softmax + sem
  logits_sem_k<<<dim3(64,1,4), 256, 0, stream>>>(q_bf, pall, tip, semb);

  // 4) fused attention -> hmid (bf16)
  attn_mfma_k<<<dim3(64,20,4), 256, 0, stream>>>(q_bf, pall, semb, mask, hmid_bf);

  // 5) out = hmid @ Wout + bout + residual
  gemm_out_k<<<1280, 256, 0, stream>>>(hmid_bf, woutt, out, bout, hs);
}

// Round 13
// 297.561 us; speedup vs baseline: 1.3988x; 1.0416x over previous
//
#include <hip/hip_runtime.h>

typedef __bf16 bf16x8 __attribute__((ext_vector_type(8)));
typedef float f32x4 __attribute__((ext_vector_type(4)));

__device__ __forceinline__ ushort f2b(float f){
  union { float f; unsigned u; } v; v.f = f;
  unsigned r = v.u + 0x7FFFu + ((v.u >> 16) & 1u);
  return (ushort)(r >> 16);
}
__device__ __forceinline__ float b2f(ushort b){
  union { unsigned u; float f; } v; v.u = ((unsigned)b) << 16; return v.f;
}

__device__ __forceinline__ void gload16(const ushort* g, ushort* lds){
  __builtin_amdgcn_global_load_lds(
      (const __attribute__((address_space(1))) unsigned int*)(g),
      (__attribute__((address_space(3))) unsigned int*)(lds), 16, 0, 0);
}

#define VMW(n)  do { asm volatile("s_waitcnt vmcnt(" #n ")" ::: "memory"); __builtin_amdgcn_sched_barrier(0); } while(0)
#define BARR    do { __builtin_amdgcn_s_barrier(); __builtin_amdgcn_sched_barrier(0); } while(0)

// ============ prep mega-kernel: hs cvt | enc cvt | 6 weight transposes | T_ip ============
__global__ __launch_bounds__(256) void prep_k(
    const float* __restrict__ hs, const float* __restrict__ enc,
    const float* __restrict__ Wq, const float* __restrict__ Wout,
    const float* __restrict__ Wk, const float* __restrict__ Wv,
    const float* __restrict__ Wkip, const float* __restrict__ Wvip,
    ushort* __restrict__ hs_bf, ushort* __restrict__ enc_bf,
    ushort* __restrict__ wqt, ushort* __restrict__ woutt, ushort* __restrict__ wcat,
    float* __restrict__ tip)
{
  __shared__ float tile[32][33];
  int bid = blockIdx.x;
  int t = threadIdx.x;

  if (bid < 20480){                       // hs f32 -> bf16
    int i = bid*256 + t;
    f32x4 v = reinterpret_cast<const f32x4*>(hs)[i];
    ushort4 o = make_ushort4(f2b(v.x), f2b(v.y), f2b(v.z), f2b(v.w));
    reinterpret_cast<ushort4*>(hs_bf)[i] = o;
    return;
  }
  bid -= 20480;
  if (bid < 768){                         // enc f32 -> bf16 (pad to 384 rows)
    int i = bid*256 + t;
    f32x4 v = {0.f,0.f,0.f,0.f};
    if (i < 324*2048/4) v = reinterpret_cast<const f32x4*>(enc)[i];
    ushort4 o = make_ushort4(f2b(v.x), f2b(v.y), f2b(v.z), f2b(v.w));
    reinterpret_cast<ushort4*>(enc_bf)[i] = o;
    return;
  }
  bid -= 768;
  if (bid < 13440){                       // weight transposes
    const float* Wsrc; ushort* Wdst; int K;
    if (bid < 1600)      { Wsrc = Wq;   Wdst = wqt;                    K = 1280; }
    else if (bid < 3200) { bid -= 1600; Wsrc = Wout; Wdst = woutt;     K = 1280; }
    else if (bid < 5760) { bid -= 3200; Wsrc = Wk;   Wdst = wcat;      K = 2048; }
    else if (bid < 8320) { bid -= 5760; Wsrc = Wv;   Wdst = wcat + 1ull*1280*2048; K = 2048; }
    else if (bid < 10880){ bid -= 8320; Wsrc = Wkip; Wdst = wcat + 2ull*1280*2048; K = 2048; }
    else                 { bid -= 10880; Wsrc = Wvip; Wdst = wcat + 3ull*1280*2048; K = 2048; }
    int n0 = (bid % 40)*32, k0 = (bid / 40)*32;
    int tx = t & 31, ty = t >> 5;
    for (int i = ty; i < 32; i += 8) tile[i][tx] = Wsrc[(size_t)(k0+i)*1280 + n0+tx];
    __syncthreads();
    for (int i = ty; i < 32; i += 8) Wdst[(size_t)(n0+i)*K + k0+tx] = f2b(tile[tx][i]);
    return;
  }
  bid -= 13440;
  {                                       // tip[b][k][n] = 0.125 * text[b,k]·ip[b,n]
    int b = bid / 77, k = bid % 77;
    int n = t >> 6, l = t & 63;
    const float* text = enc + ((size_t)b*81 + k)*2048;
    const float* ip   = enc + ((size_t)b*81 + 77 + n)*2048;
    float acc = 0.f;
    for (int c = l; c < 2048; c += 64) acc += text[c]*ip[c];
    #pragma unroll
    for (int off = 32; off > 0; off >>= 1) acc += __shfl_xor(acc, off);
    if (l == 0) tip[((size_t)b*77 + k)*4 + n] = acc * 0.125f;
  }
}

// ============ shared 128x128 GEMM body: BK=32, 3-buffer counted-vmcnt pipeline ============
// R7's 68-VGPR variant: per K-step = VMW(4); barrier; stage(kt+2); ds_read; 16 MFMA/wave.
// Loads stay in flight across barriers. 48KB LDS -> 3 blocks/CU.
// `#pragma unroll 1` — K is compile-time const here; full unroll costs +24 VGPR (R9/R10).
template<int MODE>
__device__ __forceinline__ void gemm_body(
    const ushort* __restrict__ A, const ushort* __restrict__ Bt,
    int K, int lda, int ldb, int ldo,
    float* __restrict__ outF, ushort* __restrict__ outB,
    const float* __restrict__ bias, const float* __restrict__ resid,
    int mt, int nt)
{
  __shared__ ushort As[3][128*32];
  __shared__ ushort Bs[3][128*32];
  int t = threadIdx.x;
  int w = t >> 6, l = t & 63;
  int wr = w >> 1, wc = w & 1;
  int fr = l & 15, fq = l >> 4;

  int r0 = t >> 2, s0 = t & 3;
  int r1 = r0 + 64;
  int sc0 = ((s0 ^ ((r0 >> 1) & 3)) << 3);
  int sc1 = ((s0 ^ ((r1 >> 1) & 3)) << 3);
  const ushort* Ag0 = A  + (size_t)(mt*128 + r0)*lda + sc0;
  const ushort* Ag1 = A  + (size_t)(mt*128 + r1)*lda + sc1;
  const ushort* Bg0 = Bt + (size_t)(nt*128 + r0)*ldb + sc0;
  const ushort* Bg1 = Bt + (size_t)(nt*128 + r1)*ldb + sc1;

  f32x4 acc[4][4];
  #pragma unroll
  for (int m = 0; m < 4; ++m)
    #pragma unroll
    for (int n = 0; n < 4; ++n) acc[m][n] = (f32x4){0.f,0.f,0.f,0.f};

  auto stage = [&](int s, int kt){
    int ko = kt << 5;
    ushort* a = &As[s][0] + t*8;
    ushort* b = &Bs[s][0] + t*8;
    gload16(Ag0 + ko, a);
    gload16(Ag1 + ko, a + 2048);
    gload16(Bg0 + ko, b);
    gload16(Bg1 + ko, b + 2048);
  };
  auto compute = [&](int s){
    bf16x8 af[4], bf[4];
    #pragma unroll
    for (int m = 0; m < 4; ++m){
      int row = wr*64 + m*16 + fr;
      af[m] = *reinterpret_cast<const bf16x8*>(&As[s][row*32 + ((fq ^ ((row >> 1) & 3)) << 3)]);
    }
    #pragma unroll
    for (int n = 0; n < 4; ++n){
      int row = wc*64 + n*16 + fr;
      bf[n] = *reinterpret_cast<const bf16x8*>(&Bs[s][row*32 + ((fq ^ ((row >> 1) & 3)) << 3)]);
    }
    #pragma unroll
    for (int m = 0; m < 4; ++m)
      #pragma unroll
      for (int n = 0; n < 4; ++n)
        acc[m][n] = __builtin_amdgcn_mfma_f32_16x16x32_bf16(af[m], bf[n], acc[m][n], 0, 0, 0);
  };

  int nk = K >> 5;
  stage(0, 0);
  stage(1, 1);
  int kt = 0;
  #pragma unroll 1
  for (; kt < nk - 1; ++kt){
    VMW(4);                 // tile kt landed (only stage(kt+1) may be in flight)
    BARR;
    if (kt + 2 < nk) stage((kt + 2) % 3, kt + 2);
    compute(kt % 3);
  }
  VMW(0);
  BARR;
  compute(kt % 3);

  int fqb = fq << 2;
  #pragma unroll
  for (int m = 0; m < 4; ++m){
    #pragma unroll
    for (int n = 0; n < 4; ++n){
      #pragma unroll
      for (int r = 0; r < 4; ++r){
        int row = mt*128 + wr*64 + m*16 + fqb + r;
        int col = nt*128 + wc*64 + n*16 + fr;
        size_t oidx = (size_t)row*ldo + col;
        float v = acc[m][n][r];
        if (MODE == 0) outB[oidx] = f2b(v);
        else           outF[oidx] = v + bias[col] + resid[oidx];
      }
    }
  }
}

// enc-proj (K=2048, longer blocks) on blockIdx 0..119 so they launch FIRST and run
// in q-proj's shadow; q-proj swizzled bijectively over its own 1280 range.
__global__ __launch_bounds__(256) void gemm_dual_k(
    const ushort* __restrict__ A1, const ushort* __restrict__ B1, ushort* __restrict__ O1,
    const ushort* __restrict__ A2, const ushort* __restrict__ B2, ushort* __restrict__ O2)
{
  int bid = blockIdx.x;
  if (bid < 120){
    gemm_body<0>(A2, B2, 2048, 2048, 2048, 5120,
                 nullptr, O2, nullptr, nullptr, bid/40, bid%40);
  } else {
    int qb = bid - 120;
    qb = (qb & 7)*160 + (qb >> 3);        // 1280/8 = 160, bijective
    gemm_body<0>(A1, B1, 1280, 1280, 1280, 1280,
                 nullptr, O1, nullptr, nullptr, qb/10, qb%10);
  }
}

// out-proj: fp32 + bias + residual
__global__ __launch_bounds__(256) void gemm_out_k(
    const ushort* __restrict__ A, const ushort* __restrict__ Bt, float* __restrict__ outF,
    const float* __restrict__ bias, const float* __restrict__ resid)
{
  int nwg = gridDim.x;
  int bid = blockIdx.x;
  if ((nwg & 7) == 0){
    int cpx = nwg >> 3;
    bid = (bid & 7)*cpx + (bid >> 3);
  }
  gemm_body<1>(A, Bt, 1280, 1280, 1280, 1280,
               outF, nullptr, bias, resid, bid/10, bid%10);
}

// ============ fused logits + text-softmax + sem kernel ============
__global__ __launch_bounds__(256) void logits_sem_k(
    const ushort* __restrict__ q, const ushort* __restrict__ pall,
    const float* __restrict__ tip, float* __restrict__ sem)
{
  __shared__ ushort As[64][40];
  __shared__ ushort Bs[128][40];
  __shared__ float tipS[77][4];
  int mt = blockIdx.x;
  int z  = blockIdx.z;
  int t = threadIdx.x;
  const ushort* Ab = q + (size_t)z*4096*1280;
  const ushort* Bb = pall + (size_t)z*81*5120;
  for (int i = t; i < 308; i += 256) (&tipS[0][0])[i] = tip[(size_t)z*308 + i];

  int w = t >> 6, l = t & 63;
  int fr = l & 15, fq = l >> 4, fk = fq << 3;
  int alr = t >> 2, alc = (t & 3) << 3;

  const ushort* Aptr  = Ab + (size_t)(mt*64 + alr)*1280 + alc;
  const ushort* Bptr0 = Bb + (size_t)alr*5120 + alc;
  const ushort* Bptr1 = Bb + (size_t)(64 + alr)*5120 + alc;

  f32x4 acc[5];
  #pragma unroll
  for (int n = 0; n < 5; ++n) acc[n] = (f32x4){0.f,0.f,0.f,0.f};

  uint4 a0 = *reinterpret_cast<const uint4*>(Aptr);
  uint4 b0 = *reinterpret_cast<const uint4*>(Bptr0);
  uint4 b1 = *reinterpret_cast<const uint4*>(Bptr1);
  #pragma unroll 1
  for (int k0 = 0; k0 < 1280; k0 += 32){
    __syncthreads();
    *reinterpret_cast<uint4*>(&As[alr][alc]) = a0;
    *reinterpret_cast<uint4*>(&Bs[alr][alc]) = b0;
    *reinterpret_cast<uint4*>(&Bs[64+alr][alc]) = b1;
    if (k0 + 32 < 1280){
      a0 = *reinterpret_cast<const uint4*>(Aptr + k0 + 32);
      b0 = *reinterpret_cast<const uint4*>(Bptr0 + k0 + 32);
      b1 = *reinterpret_cast<const uint4*>(Bptr1 + k0 + 32);
    }
    __syncthreads();
    bf16x8 af = *reinterpret_cast<const bf16x8*>(&As[w*16 + fr][fk]);
    #pragma unroll
    for (int n = 0; n < 5; ++n){
      bf16x8 bf = *reinterpret_cast<const bf16x8*>(&Bs[n*16 + fr][fk]);
      acc[n] = __builtin_amdgcn_mfma_f32_16x16x32_bf16(af, bf, acc[n], 0, 0, 0);
    }
  }

  bool v4 = (fr < 13);     // col 64+fr < 77
  #pragma unroll
  for (int r = 0; r < 4; ++r){
    float lg[5];
    #pragma unroll
    for (int n = 0; n < 5; ++n) lg[n] = acc[n][r]*0.125f;
    float m = fmaxf(fmaxf(lg[0],lg[1]), fmaxf(lg[2],lg[3]));
    if (v4) m = fmaxf(m, lg[4]);
    #pragma unroll
    for (int off = 1; off < 16; off <<= 1) m = fmaxf(m, __shfl_xor(m, off));
    float s = __expf(lg[0]-m) + __expf(lg[1]-m) + __expf(lg[2]-m) + __expf(lg[3]-m);
    if (v4) s += __expf(lg[4]-m);
    #pragma unroll
    for (int off = 1; off < 16; off <<= 1) s += __shfl_xor(s, off);
    float inv = 1.f / s;
    float a0s = 0.f, a1s = 0.f, a2s = 0.f, a3s = 0.f;
    #pragma unroll
    for (int n = 0; n < 5; ++n){
      int c = n*16 + fr;
      if (n < 4 || v4){
        float p = __expf(lg[n]-m) * inv;
        a0s += p*tipS[c][0]; a1s += p*tipS[c][1];
        a2s += p*tipS[c][2]; a3s += p*tipS[c][3];
      }
    }
    #pragma unroll
    for (int off = 1; off < 16; off <<= 1){
      a0s += __shfl_xor(a0s, off); a1s += __shfl_xor(a1s, off);
      a2s += __shfl_xor(a2s, off); a3s += __shfl_xor(a3s, off);
    }
    if (fr == 0){
      size_t row = (size_t)z*4096 + mt*64 + w*16 + fq*4 + r;
      f32x4 o = {a0s, a1s, a2s, a3s};
      *reinterpret_cast<f32x4*>(&sem[row*4]) = o;
    }
  }
}

// ============ MFMA fused text+ip attention: 2 q-tiles per block ============
// K/V/Vt staged once, amortized over two 64-row Q-tiles.
__global__ __launch_bounds__(256) void attn_mfma_k(
    const ushort* __restrict__ qb, const ushort* __restrict__ pall,
    const float* __restrict__ sem, const float* __restrict__ mask,
    ushort* __restrict__ hmid)
{
  int qp = blockIdx.x;   // 0..31 (pair of q-tiles)
  int h  = blockIdx.y;   // 0..19
  int b  = blockIdx.z;   // 0..3
  __shared__ ushort Qs[64][72];
  __shared__ ushort Ks[96][72];
  __shared__ ushort Vt[64][104];  // V^T: [d][k]
  __shared__ ushort Ps[64][104];
  int t = threadIdx.x;
  int w = t >> 6, l = t & 63;
  const ushort* pb = pall + (size_t)b*81*5120 + h*64;

  // stage K rows (text 0..76, ip 77..80, zero 81..95)
  #pragma unroll
  for (int it = 0; it < 6; ++it){
    int chunk = t + it*256;
    int k = chunk >> 4, dp = (chunk & 15) << 2;
    ushort4 v = make_ushort4(0,0,0,0);
    if (k < 77)      v = *reinterpret_cast<const ushort4*>(pb + (size_t)k*5120 + dp);
    else if (k < 81) v = *reinterpret_cast<const ushort4*>(pb + (size_t)k*5120 + 2560 + dp);
    *reinterpret_cast<ushort4*>(&Ks[k][dp]) = v;
  }
  // V^T staging (ushort4): rows 81..95 are finite garbage x zero P cols
  #pragma unroll
  for (int it = 0; it < 6; ++it){
    int idx = t + it*256;
    int k = idx >> 4, d4 = (idx & 15) << 2;
    const ushort* src = (k < 77) ? pb + (size_t)k*5120 + 1280 + d4
                                 : pb + (size_t)k*5120 + 3840 + d4;
    ushort4 v = *reinterpret_cast<const ushort4*>(src);
    Vt[d4][k] = v.x; Vt[d4+1][k] = v.y; Vt[d4+2][k] = v.z; Vt[d4+3][k] = v.w;
  }

  int fr = l & 15, fq = l >> 4, fkb = fq << 3;
  int c = fr;

  #pragma unroll 1
  for (int half = 0; half < 2; ++half){
    int qt = qp*2 + half;
    // stage Q for this tile (safe: prior QK^T reads of Qs finished before the
    // pre-PV barrier of the previous half)
    {
      int base = b*4096 + qt*64;
      #pragma unroll
      for (int it = 0; it < 2; ++it){
        int chunk = t + it*256;
        int r = chunk >> 3, dp = (chunk & 7) << 3;
        uint4 v = *reinterpret_cast<const uint4*>(qb + (size_t)(base + r)*1280 + h*64 + dp);
        *reinterpret_cast<uint4*>(&Qs[r][dp]) = v;
      }
    }
    __syncthreads();   // Q (and on half 0: K/V) staged; also guards prev-half PV reads of Ps

    f32x4 s[6];
    #pragma unroll
    for (int n = 0; n < 6; ++n) s[n] = (f32x4){0.f,0.f,0.f,0.f};
    #pragma unroll
    for (int ks = 0; ks < 2; ++ks){
      bf16x8 aq = *reinterpret_cast<const bf16x8*>(&Qs[w*16 + fr][ks*32 + fkb]);
      #pragma unroll
      for (int n = 0; n < 6; ++n){
        bf16x8 bk = *reinterpret_cast<const bf16x8*>(&Ks[n*16 + fr][ks*32 + fkb]);
        s[n] = __builtin_amdgcn_mfma_f32_16x16x32_bf16(aq, bk, s[n], 0, 0, 0);
      }
    }

    int rowbase = qt*64 + w*16 + (fq << 2);
    #pragma unroll
    for (int r = 0; r < 4; ++r){
      float lg[6];
      #pragma unroll
      for (int n = 0; n < 6; ++n) lg[n] = s[n][r]*0.125f;

      float mt = fmaxf(fmaxf(lg[0],lg[1]), fmaxf(lg[2],lg[3]));
      if (c < 13) mt = fmaxf(mt, lg[4]);
      #pragma unroll
      for (int off = 1; off < 16; off <<= 1) mt = fmaxf(mt, __shfl_xor(mt, off));
      float st = __expf(lg[0]-mt) + __expf(lg[1]-mt) + __expf(lg[2]-mt) + __expf(lg[3]-mt);
      if (c < 13) st += __expf(lg[4]-mt);
      #pragma unroll
      for (int off = 1; off < 16; off <<= 1) st += __shfl_xor(st, off);
      float invst = 1.f/st;

      size_t qrow = (size_t)b*4096 + rowbase + r;
      float f4 = -1e30f, f5 = -1e30f;
      if (c >= 13) f4 = lg[4] + 0.5f*sem[qrow*4 + (c-13)];
      if (c == 0)  f5 = lg[5] + 0.5f*sem[qrow*4 + 3];
      float m2 = fmaxf(f4, f5);
      #pragma unroll
      for (int off = 1; off < 16; off <<= 1) m2 = fmaxf(m2, __shfl_xor(m2, off));
      float si = (c >= 13 ? __expf(f4-m2) : 0.f) + (c == 0 ? __expf(f5-m2) : 0.f);
      #pragma unroll
      for (int off = 1; off < 16; off <<= 1) si += __shfl_xor(si, off);
      float pmul = mask[rowbase + r] / si;

      int prow = w*16 + (fq << 2) + r;
      #pragma unroll
      for (int n = 0; n < 4; ++n) Ps[prow][n*16 + c] = f2b(__expf(lg[n]-mt)*invst);
      Ps[prow][64 + c] = f2b(c < 13 ? __expf(lg[4]-mt)*invst : __expf(f4-m2)*pmul);
      Ps[prow][80 + c] = f2b(c == 0 ? __expf(f5-m2)*pmul : 0.f);
    }
    __syncthreads();   // Ps complete before PV

    f32x4 o[4];
    #pragma unroll
    for (int df = 0; df < 4; ++df) o[df] = (f32x4){0.f,0.f,0.f,0.f};
    #pragma unroll
    for (int ks = 0; ks < 3; ++ks){
      bf16x8 ap = *reinterpret_cast<const bf16x8*>(&Ps[w*16 + fr][ks*32 + fkb]);
      #pragma unroll
      for (int df = 0; df < 4; ++df){
        bf16x8 bv = *reinterpret_cast<const bf16x8*>(&Vt[df*16 + fr][ks*32 + fkb]);
        o[df] = __builtin_amdgcn_mfma_f32_16x16x32_bf16(ap, bv, o[df], 0, 0, 0);
      }
    }
    #pragma unroll
    for (int df = 0; df < 4; ++df)
      #pragma unroll
      for (int r = 0; r < 4; ++r)
        hmid[((size_t)b*4096 + rowbase + r)*1280 + h*64 + df*16 + c] = f2b(o[df][r]);
  }
}

extern "C" void kernel_launch(void* const* d_in, const int* in_sizes, int n_in,
                              void* d_out, int out_size, void* d_ws, size_t ws_size,
                              hipStream_t stream)
{
  (void)in_sizes; (void)n_in; (void)out_size; (void)ws_size;
  const float* hs   = (const float*)d_in[0];
  const float* enc  = (const float*)d_in[1];
  const float* mask = (const float*)d_in[2];
  const float* Wq   = (const float*)d_in[3];
  const float* Wk   = (const float*)d_in[4];
  const float* Wv   = (const float*)d_in[5];
  const float* Wkip = (const float*)d_in[6];
  const float* Wvip = (const float*)d_in[7];
  const float* Wout = (const float*)d_in[8];
  const float* bout = (const float*)d_in[9];
  float* out = (float*)d_out;
  char* ws = (char*)d_ws;

  size_t off = 0;
  auto alloc = [&](size_t bytes)->char*{
    char* p = ws + off; off += (bytes + 255) & ~(size_t)255; return p;
  };
  ushort* hs_bf   = (ushort*)alloc(16384ull*1280*2);   // reused as hmid
  ushort* q_bf    = (ushort*)alloc(16384ull*1280*2);
  ushort* enc_bf  = (ushort*)alloc(384ull*2048*2);
  ushort* wqt     = (ushort*)alloc(1280ull*1280*2);
  ushort* woutt   = (ushort*)alloc(1280ull*1280*2);
  ushort* wcat    = (ushort*)alloc(5120ull*2048*2);
  ushort* pall    = (ushort*)alloc(384ull*5120*2);
  float*  tip     = (float*)alloc(4ull*77*4*4);
  float*  semb    = (float*)alloc(16384ull*4*4);
  ushort* hmid_bf = hs_bf;

  // 1) all preprocessing in one launch
  prep_k<<<34996, 256, 0, stream>>>(hs, enc, Wq, Wout, Wk, Wv, Wkip, Wvip,
                                    hs_bf, enc_bf, wqt, woutt, wcat, tip);

  // 2) q-projection + encoder projections in one launch (enc first)
  gemm_dual_k<<<1400, 256, 0, stream>>>(hs_bf, wqt, q_bf, enc_bf, wcat, pall);

  // 3) fused logits + text softmax + sem
  logits_sem_k<<<dim3(64,1,4), 256, 0, stream>>>(q_bf, pall, tip, semb);

  // 4) fused attention -> hmid (bf16)
  attn_mfma_k<<<dim3(32,20,4), 256, 0, stream>>>(q_bf, pall, semb, mask, hmid_bf);

  // 5) out = hmid @ Wout + bout + residual
  gemm_out_k<<<1280, 256, 0, stream>>>(hmid_bf, woutt, out, bout, hs);
}